// Round 1
// baseline (1219.710 us; speedup 1.0000x reference)
//
#include <hip/hip_runtime.h>
#include <math.h>

// GAT, 4 layers: N=50000 nodes, E=800000 edges, IN=128, HID=64, H=4, C=2.
// Pipeline per call:
//   CSR build (dst-sorted) once: hist -> exclusive scan -> scatter
//   L1..L3: gemm (feat = h @ W^T), el/er reduce, per-dst-wave softmax-aggregate (+res+bias+elu)
//   L4: per-node wave projection (W4, resW4, el4, er4), aggregate + per-head softmax + head-mean

#define LEAKY_SLOPE 0.2f

__device__ __forceinline__ float leaky(float x) { return x > 0.f ? x : LEAKY_SLOPE * x; }
__device__ __forceinline__ float eluf(float x)  { return x > 0.f ? x : expm1f(x); }

__device__ __forceinline__ float wsum(float v) {
#pragma unroll
  for (int o = 32; o; o >>= 1) v += __shfl_xor(v, o);
  return v;
}
__device__ __forceinline__ float wmax(float v) {
#pragma unroll
  for (int o = 32; o; o >>= 1) v = fmaxf(v, __shfl_xor(v, o));
  return v;
}

// ---------------- CSR build ----------------
__global__ void hist_k(const int* __restrict__ dst, int* __restrict__ deg, int e) {
  int i = blockIdx.x * 256 + threadIdx.x;
  if (i < e) atomicAdd(&deg[dst[i]], 1);
}

__global__ __launch_bounds__(1024) void exscan_k(const int* __restrict__ deg,
                                                 int* __restrict__ rowp, int n) {
  __shared__ int sd[1024];
  __shared__ int carry;
  int tid = threadIdx.x;
  if (tid == 0) carry = 0;
  __syncthreads();
  for (int base = 0; base < n; base += 1024) {
    int i = base + tid;
    int v = (i < n) ? deg[i] : 0;
    int x = v;
    sd[tid] = x;
    __syncthreads();
    for (int off = 1; off < 1024; off <<= 1) {
      int t = (tid >= off) ? sd[tid - off] : 0;
      __syncthreads();
      x += t;
      sd[tid] = x;
      __syncthreads();
    }
    int c = carry;
    if (i < n) rowp[i] = c + x - v;  // exclusive
    int tot = sd[1023];
    __syncthreads();
    if (tid == 0) carry = c + tot;
    __syncthreads();
  }
  if (tid == 0) rowp[n] = carry;
}

__global__ void scatter_k(const int* __restrict__ src, const int* __restrict__ dst,
                          const int* __restrict__ rowp, int* __restrict__ cur,
                          int* __restrict__ csrc, int e) {
  int i = blockIdx.x * 256 + threadIdx.x;
  if (i < e) {
    int d = dst[i];
    int p = atomicAdd(&cur[d], 1);
    csrc[rowp[d] + p] = src[i];
  }
}

// ---------------- GEMM: Out[n][256] = A[n][K] @ B[256][K]^T ----------------
template <int K>
__global__ __launch_bounds__(256) void gemm_nt(const float* __restrict__ A,
                                               const float* __restrict__ B,
                                               float* __restrict__ Cout, int n) {
  __shared__ float As[16][132];
  __shared__ float Bs[16][132];
  const int tid = threadIdx.x;
  const int tx = tid & 15, ty = tid >> 4;
  const int r0 = blockIdx.x * 128, c0 = blockIdx.y * 128;
  const int lrow = tid >> 1, lk8 = (tid & 1) * 8;
  float acc[8][8] = {};
  for (int kk = 0; kk < K; kk += 16) {
    float4 a0 = {0, 0, 0, 0}, a1 = {0, 0, 0, 0};
    int ar = r0 + lrow;
    if (ar < n) {
      const float* p = A + (size_t)ar * K + kk + lk8;
      a0 = *(const float4*)p;
      a1 = *(const float4*)(p + 4);
    }
    const float* q = B + (size_t)(c0 + lrow) * K + kk + lk8;
    float4 b0 = *(const float4*)q;
    float4 b1 = *(const float4*)(q + 4);
    __syncthreads();
    As[lk8 + 0][lrow] = a0.x; As[lk8 + 1][lrow] = a0.y;
    As[lk8 + 2][lrow] = a0.z; As[lk8 + 3][lrow] = a0.w;
    As[lk8 + 4][lrow] = a1.x; As[lk8 + 5][lrow] = a1.y;
    As[lk8 + 6][lrow] = a1.z; As[lk8 + 7][lrow] = a1.w;
    Bs[lk8 + 0][lrow] = b0.x; Bs[lk8 + 1][lrow] = b0.y;
    Bs[lk8 + 2][lrow] = b0.z; Bs[lk8 + 3][lrow] = b0.w;
    Bs[lk8 + 4][lrow] = b1.x; Bs[lk8 + 5][lrow] = b1.y;
    Bs[lk8 + 6][lrow] = b1.z; Bs[lk8 + 7][lrow] = b1.w;
    __syncthreads();
#pragma unroll
    for (int kt = 0; kt < 16; ++kt) {
      float a[8], b[8];
      *(float4*)&a[0] = *(const float4*)&As[kt][ty * 8];
      *(float4*)&a[4] = *(const float4*)&As[kt][ty * 8 + 4];
      *(float4*)&b[0] = *(const float4*)&Bs[kt][tx * 8];
      *(float4*)&b[4] = *(const float4*)&Bs[kt][tx * 8 + 4];
#pragma unroll
      for (int i = 0; i < 8; i++)
#pragma unroll
        for (int j = 0; j < 8; j++) acc[i][j] = fmaf(a[i], b[j], acc[i][j]);
    }
  }
#pragma unroll
  for (int i = 0; i < 8; i++) {
    int r = r0 + ty * 8 + i;
    if (r < n) {
      float* o = Cout + (size_t)r * 256 + c0 + tx * 8;
      float4 v0 = {acc[i][0], acc[i][1], acc[i][2], acc[i][3]};
      float4 v1 = {acc[i][4], acc[i][5], acc[i][6], acc[i][7]};
      *(float4*)o = v0;
      *(float4*)(o + 4) = v1;
    }
  }
}

// ---------------- el/er: el[n][h] = sum_o feat[n][h][o]*al[h][o] ----------------
__global__ __launch_bounds__(256) void eler_k(const float* __restrict__ feat,
                                              const float* __restrict__ al,
                                              const float* __restrict__ ar,
                                              float* __restrict__ el, float* __restrict__ er,
                                              int n) {
  int node = blockIdx.x * 4 + (threadIdx.x >> 6);
  int lane = threadIdx.x & 63;
  if (node >= n) return;
  const float* f = feat + (size_t)node * 256;
#pragma unroll
  for (int h = 0; h < 4; ++h) {
    float v = f[h * 64 + lane];
    float sl = wsum(v * al[h * 64 + lane]);
    float sr = wsum(v * ar[h * 64 + lane]);
    if (lane == 0) {
      el[node * 4 + h] = sl;
      er[node * 4 + h] = sr;
    }
  }
}

// ---------------- aggregate, OUT=64 (layers 1-3): one wave per dst node ----------------
template <int RES>  // 0: none, 1: identity residual
__global__ __launch_bounds__(256) void agg64_k(const float* __restrict__ feat,
                                               const float* __restrict__ el,
                                               const float* __restrict__ er,
                                               const int* __restrict__ rowp,
                                               const int* __restrict__ csrc,
                                               const float* __restrict__ hin,
                                               const float* __restrict__ bias,
                                               float* __restrict__ hout, int n) {
  int node = blockIdx.x * 4 + (threadIdx.x >> 6);
  int lane = threadIdx.x & 63;
  if (node >= n) return;
  int s0 = rowp[node], s1 = rowp[node + 1];
  float4 erv = *(const float4*)(er + (size_t)node * 4);

  // pass 1: per-head max
  float m0 = -INFINITY, m1 = -INFINITY, m2 = -INFINITY, m3 = -INFINITY;
  for (int k = s0 + lane; k < s1; k += 64) {
    int s = csrc[k];
    float4 e = *(const float4*)(el + (size_t)s * 4);
    m0 = fmaxf(m0, leaky(e.x + erv.x));
    m1 = fmaxf(m1, leaky(e.y + erv.y));
    m2 = fmaxf(m2, leaky(e.z + erv.z));
    m3 = fmaxf(m3, leaky(e.w + erv.w));
  }
  m0 = wmax(m0); m1 = wmax(m1); m2 = wmax(m2); m3 = wmax(m3);

  // pass 2: per-head sum of exp
  float d0 = 0, d1 = 0, d2 = 0, d3 = 0;
  for (int k = s0 + lane; k < s1; k += 64) {
    int s = csrc[k];
    float4 e = *(const float4*)(el + (size_t)s * 4);
    d0 += __expf(leaky(e.x + erv.x) - m0);
    d1 += __expf(leaky(e.y + erv.y) - m1);
    d2 += __expf(leaky(e.z + erv.z) - m2);
    d3 += __expf(leaky(e.w + erv.w) - m3);
  }
  d0 = wsum(d0); d1 = wsum(d1); d2 = wsum(d2); d3 = wsum(d3);
  float i0 = d0 > 0.f ? 1.f / d0 : 0.f;
  float i1 = d1 > 0.f ? 1.f / d1 : 0.f;
  float i2 = d2 > 0.f ? 1.f / d2 : 0.f;
  float i3 = d3 > 0.f ? 1.f / d3 : 0.f;

  // pass 3: weighted accumulate; lane owns output column o=lane for each head
  float a0 = 0, a1 = 0, a2 = 0, a3 = 0;
  for (int k = s0; k < s1; ++k) {
    int s = csrc[k];
    float4 e = *(const float4*)(el + (size_t)s * 4);
    float w0 = __expf(leaky(e.x + erv.x) - m0) * i0;
    float w1 = __expf(leaky(e.y + erv.y) - m1) * i1;
    float w2 = __expf(leaky(e.z + erv.z) - m2) * i2;
    float w3 = __expf(leaky(e.w + erv.w) - m3) * i3;
    const float* fr = feat + (size_t)s * 256;
    a0 = fmaf(w0, fr[lane], a0);
    a1 = fmaf(w1, fr[64 + lane], a1);
    a2 = fmaf(w2, fr[128 + lane], a2);
    a3 = fmaf(w3, fr[192 + lane], a3);
  }

  size_t base = (size_t)node * 256;
  float v0 = a0 + bias[lane];
  float v1 = a1 + bias[64 + lane];
  float v2 = a2 + bias[128 + lane];
  float v3 = a3 + bias[192 + lane];
  if (RES) {
    v0 += hin[base + lane];
    v1 += hin[base + 64 + lane];
    v2 += hin[base + 128 + lane];
    v3 += hin[base + 192 + lane];
  }
  hout[base + lane]       = eluf(v0);
  hout[base + 64 + lane]  = eluf(v1);
  hout[base + 128 + lane] = eluf(v2);
  hout[base + 192 + lane] = eluf(v3);
}

// ---------------- layer 4 projection: feat4/res4 [n][8], el4/er4 [n][4] ----------------
__global__ __launch_bounds__(256) void l4_proj_k(const float* __restrict__ h,
                                                 const float* __restrict__ W4,
                                                 const float* __restrict__ rW4,
                                                 const float* __restrict__ al4,
                                                 const float* __restrict__ ar4,
                                                 float* __restrict__ feat4,
                                                 float* __restrict__ res4,
                                                 float* __restrict__ el4,
                                                 float* __restrict__ er4, int n) {
  int node = blockIdx.x * 4 + (threadIdx.x >> 6);
  int lane = threadIdx.x & 63;
  if (node >= n) return;
  float4 hv = *(const float4*)(h + (size_t)node * 256 + lane * 4);
  float fo[8], ro[8];
#pragma unroll
  for (int m = 0; m < 8; ++m) {
    float4 wv = *(const float4*)(W4 + m * 256 + lane * 4);
    fo[m] = wsum(fmaf(hv.x, wv.x, fmaf(hv.y, wv.y, fmaf(hv.z, wv.z, hv.w * wv.w))));
    float4 rv = *(const float4*)(rW4 + m * 256 + lane * 4);
    ro[m] = wsum(fmaf(hv.x, rv.x, fmaf(hv.y, rv.y, fmaf(hv.z, rv.z, hv.w * rv.w))));
  }
  if (lane == 0) {
#pragma unroll
    for (int m = 0; m < 8; ++m) {
      feat4[(size_t)node * 8 + m] = fo[m];
      res4[(size_t)node * 8 + m] = ro[m];
    }
#pragma unroll
    for (int hh = 0; hh < 4; ++hh) {
      el4[(size_t)node * 4 + hh] = fo[2 * hh] * al4[2 * hh] + fo[2 * hh + 1] * al4[2 * hh + 1];
      er4[(size_t)node * 4 + hh] = fo[2 * hh] * ar4[2 * hh] + fo[2 * hh + 1] * ar4[2 * hh + 1];
    }
  }
}

// ---------------- layer 4 aggregate + per-head softmax + head mean ----------------
__global__ __launch_bounds__(256) void agg4_k(const float* __restrict__ feat4,
                                              const float* __restrict__ el4,
                                              const float* __restrict__ er4,
                                              const int* __restrict__ rowp,
                                              const int* __restrict__ csrc,
                                              const float* __restrict__ res4,
                                              const float* __restrict__ b4,
                                              float* __restrict__ out, int n) {
  int node = blockIdx.x * 4 + (threadIdx.x >> 6);
  int lane = threadIdx.x & 63;
  if (node >= n) return;
  int s0 = rowp[node], s1 = rowp[node + 1];
  float4 erv = *(const float4*)(er4 + (size_t)node * 4);

  float m0 = -INFINITY, m1 = -INFINITY, m2 = -INFINITY, m3 = -INFINITY;
  for (int k = s0 + lane; k < s1; k += 64) {
    int s = csrc[k];
    float4 e = *(const float4*)(el4 + (size_t)s * 4);
    m0 = fmaxf(m0, leaky(e.x + erv.x));
    m1 = fmaxf(m1, leaky(e.y + erv.y));
    m2 = fmaxf(m2, leaky(e.z + erv.z));
    m3 = fmaxf(m3, leaky(e.w + erv.w));
  }
  m0 = wmax(m0); m1 = wmax(m1); m2 = wmax(m2); m3 = wmax(m3);

  float d0 = 0, d1 = 0, d2 = 0, d3 = 0;
  for (int k = s0 + lane; k < s1; k += 64) {
    int s = csrc[k];
    float4 e = *(const float4*)(el4 + (size_t)s * 4);
    d0 += __expf(leaky(e.x + erv.x) - m0);
    d1 += __expf(leaky(e.y + erv.y) - m1);
    d2 += __expf(leaky(e.z + erv.z) - m2);
    d3 += __expf(leaky(e.w + erv.w) - m3);
  }
  d0 = wsum(d0); d1 = wsum(d1); d2 = wsum(d2); d3 = wsum(d3);
  float i0 = d0 > 0.f ? 1.f / d0 : 0.f;
  float i1 = d1 > 0.f ? 1.f / d1 : 0.f;
  float i2 = d2 > 0.f ? 1.f / d2 : 0.f;
  float i3 = d3 > 0.f ? 1.f / d3 : 0.f;

  // lane = h*2 + c for lane < 8
  int hh = (lane < 8) ? (lane >> 1) : 0;
  float acc = 0.f;
  for (int k = s0; k < s1; ++k) {
    int s = csrc[k];
    float4 e = *(const float4*)(el4 + (size_t)s * 4);
    float w0 = __expf(leaky(e.x + erv.x) - m0) * i0;
    float w1 = __expf(leaky(e.y + erv.y) - m1) * i1;
    float w2 = __expf(leaky(e.z + erv.z) - m2) * i2;
    float w3 = __expf(leaky(e.w + erv.w) - m3) * i3;
    float wv = (hh == 0) ? w0 : (hh == 1) ? w1 : (hh == 2) ? w2 : w3;
    float fv = (lane < 8) ? feat4[(size_t)s * 8 + lane] : 0.f;
    acc = fmaf(wv, fv, acc);
  }

  float v = 0.f;
  if (lane < 8) v = acc + res4[(size_t)node * 8 + lane] + b4[lane];
  // softmax over c (partner = lane ^ 1)
  float pv = __shfl_xor(v, 1);
  float mx = fmaxf(v, pv);
  float ex = __expf(v - mx);
  float sm = ex + __shfl_xor(ex, 1);
  float pr = ex / sm;
  // mean over heads: lanes {c, 2+c, 4+c, 6+c}
  float t = pr + __shfl_xor(pr, 2);
  t += __shfl_xor(t, 4);
  if (lane < 2) out[(size_t)node * 2 + lane] = t * 0.25f;
}

extern "C" void kernel_launch(void* const* d_in, const int* in_sizes, int n_in,
                              void* d_out, int out_size, void* d_ws, size_t ws_size,
                              hipStream_t stream) {
  const float* x   = (const float*)d_in[0];
  const int* src   = (const int*)d_in[1];
  const int* dst   = (const int*)d_in[2];
  const float* W1  = (const float*)d_in[3];
  const float* al1 = (const float*)d_in[4];
  const float* ar1 = (const float*)d_in[5];
  const float* b1  = (const float*)d_in[6];
  const float* W2  = (const float*)d_in[7];
  const float* al2 = (const float*)d_in[8];
  const float* ar2 = (const float*)d_in[9];
  const float* b2  = (const float*)d_in[10];
  const float* W3  = (const float*)d_in[11];
  const float* al3 = (const float*)d_in[12];
  const float* ar3 = (const float*)d_in[13];
  const float* b3  = (const float*)d_in[14];
  const float* W4  = (const float*)d_in[15];
  const float* al4 = (const float*)d_in[16];
  const float* ar4 = (const float*)d_in[17];
  const float* b4  = (const float*)d_in[18];
  const float* rW4 = (const float*)d_in[19];
  float* out = (float*)d_out;

  const int n = in_sizes[0] / 128;  // 50000
  const int e = in_sizes[1];        // 800000

  char* ws = (char*)d_ws;
  auto alloc = [&](size_t bytes) -> char* {
    char* p = ws;
    ws += (bytes + 255) & ~(size_t)255;
    return p;
  };
  float* hA    = (float*)alloc((size_t)n * 256 * 4);
  float* hB    = (float*)alloc((size_t)n * 256 * 4);
  float* feat  = (float*)alloc((size_t)n * 256 * 4);
  float* el    = (float*)alloc((size_t)n * 4 * 4);
  float* er    = (float*)alloc((size_t)n * 4 * 4);
  float* feat4 = (float*)alloc((size_t)n * 8 * 4);
  float* res4  = (float*)alloc((size_t)n * 8 * 4);
  float* el4   = (float*)alloc((size_t)n * 4 * 4);
  float* er4   = (float*)alloc((size_t)n * 4 * 4);
  int* deg     = (int*)alloc((size_t)n * 4);
  int* cur     = (int*)alloc((size_t)n * 4);
  int* rowp    = (int*)alloc((size_t)(n + 1) * 4);
  int* csrc    = (int*)alloc((size_t)e * 4);

  // CSR build (src/dst shared by all 4 layers)
  hipMemsetAsync(deg, 0, (size_t)n * 4, stream);
  hipMemsetAsync(cur, 0, (size_t)n * 4, stream);
  hist_k<<<(e + 255) / 256, 256, 0, stream>>>(dst, deg, e);
  exscan_k<<<1, 1024, 0, stream>>>(deg, rowp, n);
  scatter_k<<<(e + 255) / 256, 256, 0, stream>>>(src, dst, rowp, cur, csrc, e);

  dim3 ggrid((n + 127) / 128, 2);
  int nb4 = (n + 3) / 4;

  // layer 1: IN=128 -> [H,64], no residual, elu
  gemm_nt<128><<<ggrid, 256, 0, stream>>>(x, W1, feat, n);
  eler_k<<<nb4, 256, 0, stream>>>(feat, al1, ar1, el, er, n);
  agg64_k<0><<<nb4, 256, 0, stream>>>(feat, el, er, rowp, csrc, nullptr, b1, hA, n);

  // layer 2: 256 -> [H,64], id residual, elu
  gemm_nt<256><<<ggrid, 256, 0, stream>>>(hA, W2, feat, n);
  eler_k<<<nb4, 256, 0, stream>>>(feat, al2, ar2, el, er, n);
  agg64_k<1><<<nb4, 256, 0, stream>>>(feat, el, er, rowp, csrc, hA, b2, hB, n);

  // layer 3: 256 -> [H,64], id residual, elu
  gemm_nt<256><<<ggrid, 256, 0, stream>>>(hB, W3, feat, n);
  eler_k<<<nb4, 256, 0, stream>>>(feat, al3, ar3, el, er, n);
  agg64_k<1><<<nb4, 256, 0, stream>>>(feat, el, er, rowp, csrc, hB, b3, hA, n);

  // layer 4: 256 -> [H,2], fc residual, per-head softmax, mean over heads
  l4_proj_k<<<nb4, 256, 0, stream>>>(hA, W4, rW4, al4, ar4, feat4, res4, el4, er4, n);
  agg4_k<<<nb4, 256, 0, stream>>>(feat4, el4, er4, rowp, csrc, res4, b4, out, n);
}

// Round 2
// 875.060 us; speedup vs baseline: 1.3939x; 1.3939x over previous
//
#include <hip/hip_runtime.h>
#include <hip/hip_bf16.h>
#include <math.h>

// GAT, 4 layers: N=50000, E=800000, IN=128, HID=64, H=4, C=2.
// R2: register-resident softmax weights in agg (deg<=64 fast path), bf16
// interleaved feature copy for the pass-3 gather, hierarchical scan,
// parallelized agg4 accumulation.

#define LEAKY_SLOPE 0.2f

__device__ __forceinline__ float leaky(float x) { return x > 0.f ? x : LEAKY_SLOPE * x; }
__device__ __forceinline__ float eluf(float x)  { return x > 0.f ? x : expm1f(x); }

__device__ __forceinline__ float wsum(float v) {
#pragma unroll
  for (int o = 32; o; o >>= 1) v += __shfl_xor(v, o);
  return v;
}
__device__ __forceinline__ float wmax(float v) {
#pragma unroll
  for (int o = 32; o; o >>= 1) v = fmaxf(v, __shfl_xor(v, o));
  return v;
}

// ---------------- CSR build ----------------
__global__ void hist_k(const int* __restrict__ dst, int* __restrict__ deg, int e) {
  int i = blockIdx.x * 256 + threadIdx.x;
  if (i < e) atomicAdd(&deg[dst[i]], 1);
}

// block-local exclusive scan (1024/block) + block sums
__global__ __launch_bounds__(1024) void scan1_k(const int* __restrict__ deg,
                                                int* __restrict__ rowp,
                                                int* __restrict__ bsum, int n) {
  __shared__ int sd[1024];
  int tid = threadIdx.x;
  int i = blockIdx.x * 1024 + tid;
  int v = (i < n) ? deg[i] : 0;
  int x = v;
  sd[tid] = x;
  __syncthreads();
  for (int off = 1; off < 1024; off <<= 1) {
    int t = (tid >= off) ? sd[tid - off] : 0;
    __syncthreads();
    x += t;
    sd[tid] = x;
    __syncthreads();
  }
  if (i < n) rowp[i] = x - v;  // block-local exclusive
  if (tid == 1023) bsum[blockIdx.x] = x;
}

// scan of block sums (single wave; nb<=64 fast path, serial fallback)
__global__ __launch_bounds__(64) void scan2_k(int* __restrict__ bsum, int nb) {
  int lane = threadIdx.x;
  if (nb <= 64) {
    int v = (lane < nb) ? bsum[lane] : 0;
    int x = v;
#pragma unroll
    for (int off = 1; off < 64; off <<= 1) {
      int t = __shfl_up(x, off);
      if (lane >= off) x += t;
    }
    if (lane < nb) bsum[lane] = x - v;  // exclusive
    if (lane == 63) bsum[nb] = x;       // total
  } else if (lane == 0) {
    int run = 0;
    for (int i = 0; i < nb; ++i) { int t = bsum[i]; bsum[i] = run; run += t; }
    bsum[nb] = run;
  }
}

__global__ void scan3_k(const int* __restrict__ bsum, int* __restrict__ rowp, int n, int nb) {
  int i = blockIdx.x * 256 + threadIdx.x;
  if (i < n) rowp[i] += bsum[i >> 10];
  if (i == n) rowp[n] = bsum[nb];
}

__global__ void scatter_k(const int* __restrict__ src, const int* __restrict__ dst,
                          const int* __restrict__ rowp, int* __restrict__ cur,
                          int* __restrict__ csrc, int e) {
  int i = blockIdx.x * 256 + threadIdx.x;
  if (i < e) {
    int d = dst[i];
    int p = atomicAdd(&cur[d], 1);
    csrc[rowp[d] + p] = src[i];
  }
}

// ---------------- GEMM: Out[n][256] = A[n][K] @ B[256][K]^T ----------------
template <int K>
__global__ __launch_bounds__(256) void gemm_nt(const float* __restrict__ A,
                                               const float* __restrict__ B,
                                               float* __restrict__ Cout, int n) {
  __shared__ float As[16][132];
  __shared__ float Bs[16][132];
  const int tid = threadIdx.x;
  const int tx = tid & 15, ty = tid >> 4;
  const int r0 = blockIdx.x * 128, c0 = blockIdx.y * 128;
  const int lrow = tid >> 1, lk8 = (tid & 1) * 8;
  float acc[8][8] = {};
  for (int kk = 0; kk < K; kk += 16) {
    float4 a0 = {0, 0, 0, 0}, a1 = {0, 0, 0, 0};
    int ar = r0 + lrow;
    if (ar < n) {
      const float* p = A + (size_t)ar * K + kk + lk8;
      a0 = *(const float4*)p;
      a1 = *(const float4*)(p + 4);
    }
    const float* q = B + (size_t)(c0 + lrow) * K + kk + lk8;
    float4 b0 = *(const float4*)q;
    float4 b1 = *(const float4*)(q + 4);
    __syncthreads();
    As[lk8 + 0][lrow] = a0.x; As[lk8 + 1][lrow] = a0.y;
    As[lk8 + 2][lrow] = a0.z; As[lk8 + 3][lrow] = a0.w;
    As[lk8 + 4][lrow] = a1.x; As[lk8 + 5][lrow] = a1.y;
    As[lk8 + 6][lrow] = a1.z; As[lk8 + 7][lrow] = a1.w;
    Bs[lk8 + 0][lrow] = b0.x; Bs[lk8 + 1][lrow] = b0.y;
    Bs[lk8 + 2][lrow] = b0.z; Bs[lk8 + 3][lrow] = b0.w;
    Bs[lk8 + 4][lrow] = b1.x; Bs[lk8 + 5][lrow] = b1.y;
    Bs[lk8 + 6][lrow] = b1.z; Bs[lk8 + 7][lrow] = b1.w;
    __syncthreads();
#pragma unroll
    for (int kt = 0; kt < 16; ++kt) {
      float a[8], b[8];
      *(float4*)&a[0] = *(const float4*)&As[kt][ty * 8];
      *(float4*)&a[4] = *(const float4*)&As[kt][ty * 8 + 4];
      *(float4*)&b[0] = *(const float4*)&Bs[kt][tx * 8];
      *(float4*)&b[4] = *(const float4*)&Bs[kt][tx * 8 + 4];
#pragma unroll
      for (int i = 0; i < 8; i++)
#pragma unroll
        for (int j = 0; j < 8; j++) acc[i][j] = fmaf(a[i], b[j], acc[i][j]);
    }
  }
#pragma unroll
  for (int i = 0; i < 8; i++) {
    int r = r0 + ty * 8 + i;
    if (r < n) {
      float* o = Cout + (size_t)r * 256 + c0 + tx * 8;
      float4 v0 = {acc[i][0], acc[i][1], acc[i][2], acc[i][3]};
      float4 v1 = {acc[i][4], acc[i][5], acc[i][6], acc[i][7]};
      *(float4*)o = v0;
      *(float4*)(o + 4) = v1;
    }
  }
}

// ---------------- el/er + bf16 interleaved feature copy ----------------
// featb layout: [n][o=64][h=4] bf16 -> lane reads uint2 (4 heads of its column)
__global__ __launch_bounds__(256) void eler_k(const float* __restrict__ feat,
                                              const float* __restrict__ al,
                                              const float* __restrict__ ar,
                                              float* __restrict__ el, float* __restrict__ er,
                                              __hip_bfloat16* __restrict__ featb, int n) {
  int node = blockIdx.x * 4 + (threadIdx.x >> 6);
  int lane = threadIdx.x & 63;
  if (node >= n) return;
  const float* f = feat + (size_t)node * 256;
  __hip_bfloat16* fb = featb + (size_t)node * 256;
#pragma unroll
  for (int h = 0; h < 4; ++h) {
    float v = f[h * 64 + lane];
    fb[lane * 4 + h] = __float2bfloat16(v);
    float sl = wsum(v * al[h * 64 + lane]);
    float sr = wsum(v * ar[h * 64 + lane]);
    if (lane == 0) {
      el[node * 4 + h] = sl;
      er[node * 4 + h] = sr;
    }
  }
}

// ---------------- aggregate, OUT=64 (layers 1-3): one wave per dst node ----------------
template <int RES>
__global__ __launch_bounds__(256) void agg64_k(const __hip_bfloat16* __restrict__ featb,
                                               const float* __restrict__ el,
                                               const float* __restrict__ er,
                                               const int* __restrict__ rowp,
                                               const int* __restrict__ csrc,
                                               const float* __restrict__ hin,
                                               const float* __restrict__ bias,
                                               float* __restrict__ hout, int n) {
  int node = blockIdx.x * 4 + (threadIdx.x >> 6);
  int lane = threadIdx.x & 63;
  if (node >= n) return;
  int s0 = rowp[node], s1 = rowp[node + 1];
  int deg = s1 - s0;
  float4 erv = *(const float4*)(er + (size_t)node * 4);
  float a0 = 0, a1 = 0, a2 = 0, a3 = 0;

  if (deg <= 64) {
    // --- fast path: lane owns edge `lane`; weights live in registers ---
    int sown = 0;
    float e0 = -INFINITY, e1 = -INFINITY, e2 = -INFINITY, e3 = -INFINITY;
    if (lane < deg) {
      sown = csrc[s0 + lane];
      float4 e = *(const float4*)(el + (size_t)sown * 4);
      e0 = leaky(e.x + erv.x);
      e1 = leaky(e.y + erv.y);
      e2 = leaky(e.z + erv.z);
      e3 = leaky(e.w + erv.w);
    }
    float m0 = wmax(e0), m1 = wmax(e1), m2 = wmax(e2), m3 = wmax(e3);
    float x0 = (lane < deg) ? __expf(e0 - m0) : 0.f;
    float x1 = (lane < deg) ? __expf(e1 - m1) : 0.f;
    float x2 = (lane < deg) ? __expf(e2 - m2) : 0.f;
    float x3 = (lane < deg) ? __expf(e3 - m3) : 0.f;
    float d0 = wsum(x0), d1 = wsum(x1), d2 = wsum(x2), d3 = wsum(x3);
    float w0 = x0 * (d0 > 0.f ? 1.f / d0 : 0.f);
    float w1 = x1 * (d1 > 0.f ? 1.f / d1 : 0.f);
    float w2 = x2 * (d2 > 0.f ? 1.f / d2 : 0.f);
    float w3 = x3 * (d3 > 0.f ? 1.f / d3 : 0.f);
#pragma unroll 2
    for (int k = 0; k < deg; ++k) {
      int sk = __shfl(sown, k);
      float w0k = __shfl(w0, k), w1k = __shfl(w1, k);
      float w2k = __shfl(w2, k), w3k = __shfl(w3, k);
      const uint2* fp = (const uint2*)(featb + ((size_t)sk << 8));
      uint2 u = fp[lane];
      float f0 = __uint_as_float(u.x << 16);
      float f1 = __uint_as_float(u.x & 0xffff0000u);
      float f2 = __uint_as_float(u.y << 16);
      float f3 = __uint_as_float(u.y & 0xffff0000u);
      a0 = fmaf(w0k, f0, a0);
      a1 = fmaf(w1k, f1, a1);
      a2 = fmaf(w2k, f2, a2);
      a3 = fmaf(w3k, f3, a3);
    }
  } else {
    // --- fallback: 3-pass gather (rare) ---
    float m0 = -INFINITY, m1 = -INFINITY, m2 = -INFINITY, m3 = -INFINITY;
    for (int k = s0 + lane; k < s1; k += 64) {
      int s = csrc[k];
      float4 e = *(const float4*)(el + (size_t)s * 4);
      m0 = fmaxf(m0, leaky(e.x + erv.x));
      m1 = fmaxf(m1, leaky(e.y + erv.y));
      m2 = fmaxf(m2, leaky(e.z + erv.z));
      m3 = fmaxf(m3, leaky(e.w + erv.w));
    }
    m0 = wmax(m0); m1 = wmax(m1); m2 = wmax(m2); m3 = wmax(m3);
    float d0 = 0, d1 = 0, d2 = 0, d3 = 0;
    for (int k = s0 + lane; k < s1; k += 64) {
      int s = csrc[k];
      float4 e = *(const float4*)(el + (size_t)s * 4);
      d0 += __expf(leaky(e.x + erv.x) - m0);
      d1 += __expf(leaky(e.y + erv.y) - m1);
      d2 += __expf(leaky(e.z + erv.z) - m2);
      d3 += __expf(leaky(e.w + erv.w) - m3);
    }
    d0 = wsum(d0); d1 = wsum(d1); d2 = wsum(d2); d3 = wsum(d3);
    float i0 = d0 > 0.f ? 1.f / d0 : 0.f;
    float i1 = d1 > 0.f ? 1.f / d1 : 0.f;
    float i2 = d2 > 0.f ? 1.f / d2 : 0.f;
    float i3 = d3 > 0.f ? 1.f / d3 : 0.f;
    for (int k = s0; k < s1; ++k) {
      int s = csrc[k];
      float4 e = *(const float4*)(el + (size_t)s * 4);
      float w0 = __expf(leaky(e.x + erv.x) - m0) * i0;
      float w1 = __expf(leaky(e.y + erv.y) - m1) * i1;
      float w2 = __expf(leaky(e.z + erv.z) - m2) * i2;
      float w3 = __expf(leaky(e.w + erv.w) - m3) * i3;
      const uint2* fp = (const uint2*)(featb + ((size_t)s << 8));
      uint2 u = fp[lane];
      a0 = fmaf(w0, __uint_as_float(u.x << 16), a0);
      a1 = fmaf(w1, __uint_as_float(u.x & 0xffff0000u), a1);
      a2 = fmaf(w2, __uint_as_float(u.y << 16), a2);
      a3 = fmaf(w3, __uint_as_float(u.y & 0xffff0000u), a3);
    }
  }

  size_t base = (size_t)node * 256;
  float v0 = a0 + bias[lane];
  float v1 = a1 + bias[64 + lane];
  float v2 = a2 + bias[128 + lane];
  float v3 = a3 + bias[192 + lane];
  if (RES) {
    v0 += hin[base + lane];
    v1 += hin[base + 64 + lane];
    v2 += hin[base + 128 + lane];
    v3 += hin[base + 192 + lane];
  }
  hout[base + lane]       = eluf(v0);
  hout[base + 64 + lane]  = eluf(v1);
  hout[base + 128 + lane] = eluf(v2);
  hout[base + 192 + lane] = eluf(v3);
}

// ---------------- layer 4 projection ----------------
__global__ __launch_bounds__(256) void l4_proj_k(const float* __restrict__ h,
                                                 const float* __restrict__ W4,
                                                 const float* __restrict__ rW4,
                                                 const float* __restrict__ al4,
                                                 const float* __restrict__ ar4,
                                                 float* __restrict__ feat4,
                                                 float* __restrict__ res4,
                                                 float* __restrict__ el4,
                                                 float* __restrict__ er4, int n) {
  int node = blockIdx.x * 4 + (threadIdx.x >> 6);
  int lane = threadIdx.x & 63;
  if (node >= n) return;
  float4 hv = *(const float4*)(h + (size_t)node * 256 + lane * 4);
  float fo[8], ro[8];
#pragma unroll
  for (int m = 0; m < 8; ++m) {
    float4 wv = *(const float4*)(W4 + m * 256 + lane * 4);
    fo[m] = wsum(fmaf(hv.x, wv.x, fmaf(hv.y, wv.y, fmaf(hv.z, wv.z, hv.w * wv.w))));
    float4 rv = *(const float4*)(rW4 + m * 256 + lane * 4);
    ro[m] = wsum(fmaf(hv.x, rv.x, fmaf(hv.y, rv.y, fmaf(hv.z, rv.z, hv.w * rv.w))));
  }
  if (lane == 0) {
#pragma unroll
    for (int m = 0; m < 8; ++m) {
      feat4[(size_t)node * 8 + m] = fo[m];
      res4[(size_t)node * 8 + m] = ro[m];
    }
#pragma unroll
    for (int hh = 0; hh < 4; ++hh) {
      el4[(size_t)node * 4 + hh] = fo[2 * hh] * al4[2 * hh] + fo[2 * hh + 1] * al4[2 * hh + 1];
      er4[(size_t)node * 4 + hh] = fo[2 * hh] * ar4[2 * hh] + fo[2 * hh + 1] * ar4[2 * hh + 1];
    }
  }
}

// ---------------- layer 4 aggregate + per-head softmax + head mean ----------------
__global__ __launch_bounds__(256) void agg4_k(const float* __restrict__ feat4,
                                              const float* __restrict__ el4,
                                              const float* __restrict__ er4,
                                              const int* __restrict__ rowp,
                                              const int* __restrict__ csrc,
                                              const float* __restrict__ res4,
                                              const float* __restrict__ b4,
                                              float* __restrict__ out, int n) {
  int node = blockIdx.x * 4 + (threadIdx.x >> 6);
  int lane = threadIdx.x & 63;
  if (node >= n) return;
  int s0 = rowp[node], s1 = rowp[node + 1];
  int deg = s1 - s0;
  float4 erv = *(const float4*)(er4 + (size_t)node * 4);
  float acc = 0.f;
  int p = lane & 7, hh = p >> 1;

  if (deg <= 64) {
    int sown = 0;
    float e0 = -INFINITY, e1 = -INFINITY, e2 = -INFINITY, e3 = -INFINITY;
    if (lane < deg) {
      sown = csrc[s0 + lane];
      float4 e = *(const float4*)(el4 + (size_t)sown * 4);
      e0 = leaky(e.x + erv.x);
      e1 = leaky(e.y + erv.y);
      e2 = leaky(e.z + erv.z);
      e3 = leaky(e.w + erv.w);
    }
    float m0 = wmax(e0), m1 = wmax(e1), m2 = wmax(e2), m3 = wmax(e3);
    float x0 = (lane < deg) ? __expf(e0 - m0) : 0.f;
    float x1 = (lane < deg) ? __expf(e1 - m1) : 0.f;
    float x2 = (lane < deg) ? __expf(e2 - m2) : 0.f;
    float x3 = (lane < deg) ? __expf(e3 - m3) : 0.f;
    float d0 = wsum(x0), d1 = wsum(x1), d2 = wsum(x2), d3 = wsum(x3);
    float w0 = x0 * (d0 > 0.f ? 1.f / d0 : 0.f);
    float w1 = x1 * (d1 > 0.f ? 1.f / d1 : 0.f);
    float w2 = x2 * (d2 > 0.f ? 1.f / d2 : 0.f);
    float w3 = x3 * (d3 > 0.f ? 1.f / d3 : 0.f);
    // 8 edge-groups x 8 output lanes
    int g = lane >> 3;
    int nt = (deg + 7) >> 3;
    for (int t = 0; t < nt; ++t) {
      int k = g + t * 8;
      bool ok = k < deg;
      int kk = k & 63;
      int sk = __shfl(sown, kk);
      float w0k = __shfl(w0, kk), w1k = __shfl(w1, kk);
      float w2k = __shfl(w2, kk), w3k = __shfl(w3, kk);
      float wk = (hh == 0) ? w0k : (hh == 1) ? w1k : (hh == 2) ? w2k : w3k;
      if (ok) acc = fmaf(wk, feat4[(size_t)sk * 8 + p], acc);
    }
    acc += __shfl_xor(acc, 8);
    acc += __shfl_xor(acc, 16);
    acc += __shfl_xor(acc, 32);
  } else {
    float m0 = -INFINITY, m1 = -INFINITY, m2 = -INFINITY, m3 = -INFINITY;
    for (int k = s0 + lane; k < s1; k += 64) {
      int s = csrc[k];
      float4 e = *(const float4*)(el4 + (size_t)s * 4);
      m0 = fmaxf(m0, leaky(e.x + erv.x));
      m1 = fmaxf(m1, leaky(e.y + erv.y));
      m2 = fmaxf(m2, leaky(e.z + erv.z));
      m3 = fmaxf(m3, leaky(e.w + erv.w));
    }
    m0 = wmax(m0); m1 = wmax(m1); m2 = wmax(m2); m3 = wmax(m3);
    float d0 = 0, d1 = 0, d2 = 0, d3 = 0;
    for (int k = s0 + lane; k < s1; k += 64) {
      int s = csrc[k];
      float4 e = *(const float4*)(el4 + (size_t)s * 4);
      d0 += __expf(leaky(e.x + erv.x) - m0);
      d1 += __expf(leaky(e.y + erv.y) - m1);
      d2 += __expf(leaky(e.z + erv.z) - m2);
      d3 += __expf(leaky(e.w + erv.w) - m3);
    }
    d0 = wsum(d0); d1 = wsum(d1); d2 = wsum(d2); d3 = wsum(d3);
    float i0 = d0 > 0.f ? 1.f / d0 : 0.f;
    float i1 = d1 > 0.f ? 1.f / d1 : 0.f;
    float i2 = d2 > 0.f ? 1.f / d2 : 0.f;
    float i3 = d3 > 0.f ? 1.f / d3 : 0.f;
    for (int k = s0; k < s1; ++k) {
      int s = csrc[k];
      float4 e = *(const float4*)(el4 + (size_t)s * 4);
      float w0 = __expf(leaky(e.x + erv.x) - m0) * i0;
      float w1 = __expf(leaky(e.y + erv.y) - m1) * i1;
      float w2 = __expf(leaky(e.z + erv.z) - m2) * i2;
      float w3 = __expf(leaky(e.w + erv.w) - m3) * i3;
      float wk = (hh == 0) ? w0 : (hh == 1) ? w1 : (hh == 2) ? w2 : w3;
      if (lane < 8) acc = fmaf(wk, feat4[(size_t)s * 8 + p], acc);
    }
  }

  float v = 0.f;
  if (lane < 8) v = acc + res4[(size_t)node * 8 + lane] + b4[lane];
  float pv = __shfl_xor(v, 1);
  float mx = fmaxf(v, pv);
  float ex = __expf(v - mx);
  float sm = ex + __shfl_xor(ex, 1);
  float pr = ex / sm;
  float t = pr + __shfl_xor(pr, 2);
  t += __shfl_xor(t, 4);
  if (lane < 2) out[(size_t)node * 2 + lane] = t * 0.25f;
}

extern "C" void kernel_launch(void* const* d_in, const int* in_sizes, int n_in,
                              void* d_out, int out_size, void* d_ws, size_t ws_size,
                              hipStream_t stream) {
  const float* x   = (const float*)d_in[0];
  const int* src   = (const int*)d_in[1];
  const int* dst   = (const int*)d_in[2];
  const float* W1  = (const float*)d_in[3];
  const float* al1 = (const float*)d_in[4];
  const float* ar1 = (const float*)d_in[5];
  const float* b1  = (const float*)d_in[6];
  const float* W2  = (const float*)d_in[7];
  const float* al2 = (const float*)d_in[8];
  const float* ar2 = (const float*)d_in[9];
  const float* b2  = (const float*)d_in[10];
  const float* W3  = (const float*)d_in[11];
  const float* al3 = (const float*)d_in[12];
  const float* ar3 = (const float*)d_in[13];
  const float* b3  = (const float*)d_in[14];
  const float* W4  = (const float*)d_in[15];
  const float* al4 = (const float*)d_in[16];
  const float* ar4 = (const float*)d_in[17];
  const float* b4  = (const float*)d_in[18];
  const float* rW4 = (const float*)d_in[19];
  float* out = (float*)d_out;

  const int n = in_sizes[0] / 128;  // 50000
  const int e = in_sizes[1];        // 800000

  char* ws = (char*)d_ws;
  auto alloc = [&](size_t bytes) -> char* {
    char* p = ws;
    ws += (bytes + 255) & ~(size_t)255;
    return p;
  };
  float* hA    = (float*)alloc((size_t)n * 256 * 4);
  float* hB    = (float*)alloc((size_t)n * 256 * 4);
  float* feat  = (float*)alloc((size_t)n * 256 * 4);
  __hip_bfloat16* featb = (__hip_bfloat16*)alloc((size_t)n * 256 * 2);
  float* el    = (float*)alloc((size_t)n * 4 * 4);
  float* er    = (float*)alloc((size_t)n * 4 * 4);
  float* feat4 = (float*)alloc((size_t)n * 8 * 4);
  float* res4  = (float*)alloc((size_t)n * 8 * 4);
  float* el4   = (float*)alloc((size_t)n * 4 * 4);
  float* er4   = (float*)alloc((size_t)n * 4 * 4);
  int* deg     = (int*)alloc((size_t)n * 4);
  int* cur     = (int*)alloc((size_t)n * 4);
  int* rowp    = (int*)alloc((size_t)(n + 1) * 4);
  int* csrc    = (int*)alloc((size_t)e * 4);
  int nb_scan  = (n + 1023) / 1024;
  int* bsum    = (int*)alloc((size_t)(nb_scan + 1) * 4);

  // CSR build (src/dst shared by all 4 layers)
  hipMemsetAsync(deg, 0, (size_t)n * 4, stream);
  hipMemsetAsync(cur, 0, (size_t)n * 4, stream);
  hist_k<<<(e + 255) / 256, 256, 0, stream>>>(dst, deg, e);
  scan1_k<<<nb_scan, 1024, 0, stream>>>(deg, rowp, bsum, n);
  scan2_k<<<1, 64, 0, stream>>>(bsum, nb_scan);
  scan3_k<<<(n + 256) / 256, 256, 0, stream>>>(bsum, rowp, n, nb_scan);
  scatter_k<<<(e + 255) / 256, 256, 0, stream>>>(src, dst, rowp, cur, csrc, e);

  dim3 ggrid((n + 127) / 128, 2);
  int nb4 = (n + 3) / 4;

  // layer 1
  gemm_nt<128><<<ggrid, 256, 0, stream>>>(x, W1, feat, n);
  eler_k<<<nb4, 256, 0, stream>>>(feat, al1, ar1, el, er, featb, n);
  agg64_k<0><<<nb4, 256, 0, stream>>>(featb, el, er, rowp, csrc, nullptr, b1, hA, n);

  // layer 2
  gemm_nt<256><<<ggrid, 256, 0, stream>>>(hA, W2, feat, n);
  eler_k<<<nb4, 256, 0, stream>>>(feat, al2, ar2, el, er, featb, n);
  agg64_k<1><<<nb4, 256, 0, stream>>>(featb, el, er, rowp, csrc, hA, b2, hB, n);

  // layer 3
  gemm_nt<256><<<ggrid, 256, 0, stream>>>(hB, W3, feat, n);
  eler_k<<<nb4, 256, 0, stream>>>(feat, al3, ar3, el, er, featb, n);
  agg64_k<1><<<nb4, 256, 0, stream>>>(featb, el, er, rowp, csrc, hB, b3, hA, n);

  // layer 4
  l4_proj_k<<<nb4, 256, 0, stream>>>(hA, W4, rW4, al4, ar4, feat4, res4, el4, er4, n);
  agg4_k<<<nb4, 256, 0, stream>>>(feat4, el4, er4, rowp, csrc, res4, b4, out, n);
}

// Round 3
// 712.462 us; speedup vs baseline: 1.7120x; 1.2282x over previous
//
#include <hip/hip_runtime.h>
#include <hip/hip_bf16.h>
#include <math.h>

// GAT, 4 layers: N=50000, E=800000, IN=128, HID=64, H=4, C=2.
// R3: bf16 MFMA GEMM (16x16x32, 128x128 tile) writing interleaved bf16 featb
// directly; el/er kept fp32 via Wal = W^T @ al projection (fused into agg64
// epilogue for layers 2/3); eler_k and fp32 feat buffer eliminated.

#define LEAKY_SLOPE 0.2f

typedef __bf16 bf16x8_t __attribute__((ext_vector_type(8)));
typedef float f32x4_t __attribute__((ext_vector_type(4)));

__device__ __forceinline__ float leaky(float x) { return x > 0.f ? x : LEAKY_SLOPE * x; }
__device__ __forceinline__ float eluf(float x)  { return x > 0.f ? x : expm1f(x); }

__device__ __forceinline__ float wsum(float v) {
#pragma unroll
  for (int o = 32; o; o >>= 1) v += __shfl_xor(v, o);
  return v;
}
__device__ __forceinline__ float wmax(float v) {
#pragma unroll
  for (int o = 32; o; o >>= 1) v = fmaxf(v, __shfl_xor(v, o));
  return v;
}

// ---------------- CSR build ----------------
__global__ void hist_k(const int* __restrict__ dst, int* __restrict__ deg, int e) {
  int i = blockIdx.x * 256 + threadIdx.x;
  if (i < e) atomicAdd(&deg[dst[i]], 1);
}

__global__ __launch_bounds__(1024) void scan1_k(const int* __restrict__ deg,
                                                int* __restrict__ rowp,
                                                int* __restrict__ bsum, int n) {
  __shared__ int sd[1024];
  int tid = threadIdx.x;
  int i = blockIdx.x * 1024 + tid;
  int v = (i < n) ? deg[i] : 0;
  int x = v;
  sd[tid] = x;
  __syncthreads();
  for (int off = 1; off < 1024; off <<= 1) {
    int t = (tid >= off) ? sd[tid - off] : 0;
    __syncthreads();
    x += t;
    sd[tid] = x;
    __syncthreads();
  }
  if (i < n) rowp[i] = x - v;
  if (tid == 1023) bsum[blockIdx.x] = x;
}

__global__ __launch_bounds__(64) void scan2_k(int* __restrict__ bsum, int nb) {
  int lane = threadIdx.x;
  if (nb <= 64) {
    int v = (lane < nb) ? bsum[lane] : 0;
    int x = v;
#pragma unroll
    for (int off = 1; off < 64; off <<= 1) {
      int t = __shfl_up(x, off);
      if (lane >= off) x += t;
    }
    if (lane < nb) bsum[lane] = x - v;
    if (lane == 63) bsum[nb] = x;
  } else if (lane == 0) {
    int run = 0;
    for (int i = 0; i < nb; ++i) { int t = bsum[i]; bsum[i] = run; run += t; }
    bsum[nb] = run;
  }
}

__global__ void scan3_k(const int* __restrict__ bsum, int* __restrict__ rowp, int n, int nb) {
  int i = blockIdx.x * 256 + threadIdx.x;
  if (i < n) rowp[i] += bsum[i >> 10];
  if (i == n) rowp[n] = bsum[nb];
}

__global__ void scatter_k(const int* __restrict__ src, const int* __restrict__ dst,
                          const int* __restrict__ rowp, int* __restrict__ cur,
                          int* __restrict__ csrc, int e) {
  int i = blockIdx.x * 256 + threadIdx.x;
  if (i < e) {
    int d = dst[i];
    int p = atomicAdd(&cur[d], 1);
    csrc[rowp[d] + p] = src[i];
  }
}

// ---------------- small converters / projections ----------------
__global__ void cvt_k(const float* __restrict__ a, __hip_bfloat16* __restrict__ b, int cnt) {
  int i = blockIdx.x * 256 + threadIdx.x;
  if (i < cnt) b[i] = __float2bfloat16(a[i]);
}

// Wal[hh][col] = sum_o al[hh*64+o] * W[(hh*64+o)*K + col]   (fp32, tiny)
__global__ void wa_k(const float* __restrict__ W, const float* __restrict__ al,
                     const float* __restrict__ ar, float* __restrict__ Wal,
                     float* __restrict__ War, int K) {
  int i = blockIdx.x * 256 + threadIdx.x;
  if (i >= 4 * K) return;
  int hh = i / K, col = i - hh * K;
  float sl = 0.f, sr = 0.f;
  const float* wp = W + (size_t)(hh * 64) * K + col;
#pragma unroll 4
  for (int o = 0; o < 64; ++o) {
    float wv = wp[(size_t)o * K];
    sl = fmaf(al[hh * 64 + o], wv, sl);
    sr = fmaf(ar[hh * 64 + o], wv, sr);
  }
  Wal[i] = sl;
  War[i] = sr;
}

// layer-1 el/er from fp32 x (K=128): one wave per node
__global__ __launch_bounds__(256) void elproj_k(const float* __restrict__ x,
                                                const float* __restrict__ Wal,
                                                const float* __restrict__ War,
                                                float* __restrict__ el,
                                                float* __restrict__ er, int n) {
  int node = blockIdx.x * 4 + (threadIdx.x >> 6);
  int lane = threadIdx.x & 63;
  if (node >= n) return;
  float2 xv = *(const float2*)(x + (size_t)node * 128 + lane * 2);
#pragma unroll
  for (int hh = 0; hh < 4; ++hh) {
    float sl = xv.x * Wal[hh * 128 + 2 * lane] + xv.y * Wal[hh * 128 + 2 * lane + 1];
    float sr = xv.x * War[hh * 128 + 2 * lane] + xv.y * War[hh * 128 + 2 * lane + 1];
    sl = wsum(sl);
    sr = wsum(sr);
    if (lane == 0) {
      el[node * 4 + hh] = sl;
      er[node * 4 + hh] = sr;
    }
  }
}

// ---------------- MFMA GEMM: featb[n][o=64][h=4](bf16) = A[n][K] @ B[256][K]^T ----------------
// 128x128 tile, 4 waves of 64x64, mfma_f32_16x16x32_bf16. LDS rows padded to
// 40 bf16 (20 words: frag ds_read_b128 is 2-way -> conflict-free).
template <int K>
__global__ __launch_bounds__(256) void gemm_mfma(const __hip_bfloat16* __restrict__ A,
                                                 const __hip_bfloat16* __restrict__ B,
                                                 __hip_bfloat16* __restrict__ featb, int n) {
  __shared__ __bf16 As[128 * 40];
  __shared__ __bf16 Bs[128 * 40];
  const int tid = threadIdx.x;
  const int lane = tid & 63, w = tid >> 6;
  const int tm = lane & 15, tq = lane >> 4;
  const int wm = (w & 1) * 64, wn = (w >> 1) * 64;
  const int r0 = blockIdx.x * 128, c0 = blockIdx.y * 128;
  const int srow = tid >> 1, sko = (tid & 1) * 16;

  f32x4_t acc[4][4];
#pragma unroll
  for (int i = 0; i < 4; ++i)
#pragma unroll
    for (int j = 0; j < 4; ++j) acc[i][j] = 0.f;

  for (int kk = 0; kk < K; kk += 32) {
    uint4 av0 = {0, 0, 0, 0}, av1 = {0, 0, 0, 0};
    int arw = r0 + srow;
    if (arw < n) {
      const uint4* p = (const uint4*)(A + (size_t)arw * K + kk + sko);
      av0 = p[0];
      av1 = p[1];
    }
    const uint4* q = (const uint4*)(B + (size_t)(c0 + srow) * K + kk + sko);
    uint4 bv0 = q[0], bv1 = q[1];
    __syncthreads();
    *(uint4*)&As[srow * 40 + sko] = av0;
    *(uint4*)&As[srow * 40 + sko + 8] = av1;
    *(uint4*)&Bs[srow * 40 + sko] = bv0;
    *(uint4*)&Bs[srow * 40 + sko + 8] = bv1;
    __syncthreads();
    bf16x8_t af[4], bfr[4];
#pragma unroll
    for (int i = 0; i < 4; ++i) af[i] = *(const bf16x8_t*)&As[(wm + i * 16 + tm) * 40 + tq * 8];
#pragma unroll
    for (int j = 0; j < 4; ++j) bfr[j] = *(const bf16x8_t*)&Bs[(wn + j * 16 + tm) * 40 + tq * 8];
#pragma unroll
    for (int i = 0; i < 4; ++i)
#pragma unroll
      for (int j = 0; j < 4; ++j)
        acc[i][j] = __builtin_amdgcn_mfma_f32_16x16x32_bf16(af[i], bfr[j], acc[i][j], 0, 0, 0);
  }

  // featb interleaved [row][o=64][hh=4]; col block (c0+wn) fixes hh per wave
#pragma unroll
  for (int i = 0; i < 4; ++i) {
#pragma unroll
    for (int j = 0; j < 4; ++j) {
      int col = c0 + wn + j * 16 + tm;
      int hh = col >> 6, oo = col & 63;
#pragma unroll
      for (int rr = 0; rr < 4; ++rr) {
        int row = r0 + wm + i * 16 + tq * 4 + rr;
        if (row < n) featb[(size_t)row * 256 + oo * 4 + hh] = __float2bfloat16(acc[i][j][rr]);
      }
    }
  }
}

// ---------------- aggregate layers 1-3: one wave per dst node ----------------
// NEXT: also emit bf16 row-major h (next GEMM A) + fp32 el/er for next layer.
template <int RES, int NEXT>
__global__ __launch_bounds__(256) void agg64_k(const __hip_bfloat16* __restrict__ featb,
                                               const float* __restrict__ el,
                                               const float* __restrict__ er,
                                               const int* __restrict__ rowp,
                                               const int* __restrict__ csrc,
                                               const float* __restrict__ hin,
                                               const float* __restrict__ bias,
                                               float* __restrict__ hout,
                                               __hip_bfloat16* __restrict__ houtb,
                                               const float* __restrict__ Waln,
                                               const float* __restrict__ Warn,
                                               float* __restrict__ eln,
                                               float* __restrict__ ern, int n) {
  int node = blockIdx.x * 4 + (threadIdx.x >> 6);
  int lane = threadIdx.x & 63;
  if (node >= n) return;
  int s0 = rowp[node], s1 = rowp[node + 1];
  int deg = s1 - s0;
  float4 erv = *(const float4*)(er + (size_t)node * 4);
  float a0 = 0, a1 = 0, a2 = 0, a3 = 0;

  if (deg <= 64) {
    int sown = 0;
    float e0 = -INFINITY, e1 = -INFINITY, e2 = -INFINITY, e3 = -INFINITY;
    if (lane < deg) {
      sown = csrc[s0 + lane];
      float4 e = *(const float4*)(el + (size_t)sown * 4);
      e0 = leaky(e.x + erv.x);
      e1 = leaky(e.y + erv.y);
      e2 = leaky(e.z + erv.z);
      e3 = leaky(e.w + erv.w);
    }
    float m0 = wmax(e0), m1 = wmax(e1), m2 = wmax(e2), m3 = wmax(e3);
    float x0 = (lane < deg) ? __expf(e0 - m0) : 0.f;
    float x1 = (lane < deg) ? __expf(e1 - m1) : 0.f;
    float x2 = (lane < deg) ? __expf(e2 - m2) : 0.f;
    float x3 = (lane < deg) ? __expf(e3 - m3) : 0.f;
    float d0 = wsum(x0), d1 = wsum(x1), d2 = wsum(x2), d3 = wsum(x3);
    float w0 = x0 * (d0 > 0.f ? 1.f / d0 : 0.f);
    float w1 = x1 * (d1 > 0.f ? 1.f / d1 : 0.f);
    float w2 = x2 * (d2 > 0.f ? 1.f / d2 : 0.f);
    float w3 = x3 * (d3 > 0.f ? 1.f / d3 : 0.f);
#pragma unroll 2
    for (int k = 0; k < deg; ++k) {
      int sk = __shfl(sown, k);
      float w0k = __shfl(w0, k), w1k = __shfl(w1, k);
      float w2k = __shfl(w2, k), w3k = __shfl(w3, k);
      const uint2* fp = (const uint2*)(featb + ((size_t)sk << 8));
      uint2 u = fp[lane];
      a0 = fmaf(w0k, __uint_as_float(u.x << 16), a0);
      a1 = fmaf(w1k, __uint_as_float(u.x & 0xffff0000u), a1);
      a2 = fmaf(w2k, __uint_as_float(u.y << 16), a2);
      a3 = fmaf(w3k, __uint_as_float(u.y & 0xffff0000u), a3);
    }
  } else {
    float m0 = -INFINITY, m1 = -INFINITY, m2 = -INFINITY, m3 = -INFINITY;
    for (int k = s0 + lane; k < s1; k += 64) {
      int s = csrc[k];
      float4 e = *(const float4*)(el + (size_t)s * 4);
      m0 = fmaxf(m0, leaky(e.x + erv.x));
      m1 = fmaxf(m1, leaky(e.y + erv.y));
      m2 = fmaxf(m2, leaky(e.z + erv.z));
      m3 = fmaxf(m3, leaky(e.w + erv.w));
    }
    m0 = wmax(m0); m1 = wmax(m1); m2 = wmax(m2); m3 = wmax(m3);
    float d0 = 0, d1 = 0, d2 = 0, d3 = 0;
    for (int k = s0 + lane; k < s1; k += 64) {
      int s = csrc[k];
      float4 e = *(const float4*)(el + (size_t)s * 4);
      d0 += __expf(leaky(e.x + erv.x) - m0);
      d1 += __expf(leaky(e.y + erv.y) - m1);
      d2 += __expf(leaky(e.z + erv.z) - m2);
      d3 += __expf(leaky(e.w + erv.w) - m3);
    }
    d0 = wsum(d0); d1 = wsum(d1); d2 = wsum(d2); d3 = wsum(d3);
    float i0 = d0 > 0.f ? 1.f / d0 : 0.f;
    float i1 = d1 > 0.f ? 1.f / d1 : 0.f;
    float i2 = d2 > 0.f ? 1.f / d2 : 0.f;
    float i3 = d3 > 0.f ? 1.f / d3 : 0.f;
    for (int k = s0; k < s1; ++k) {
      int s = csrc[k];
      float4 e = *(const float4*)(el + (size_t)s * 4);
      float w0 = __expf(leaky(e.x + erv.x) - m0) * i0;
      float w1 = __expf(leaky(e.y + erv.y) - m1) * i1;
      float w2 = __expf(leaky(e.z + erv.z) - m2) * i2;
      float w3 = __expf(leaky(e.w + erv.w) - m3) * i3;
      const uint2* fp = (const uint2*)(featb + ((size_t)s << 8));
      uint2 u = fp[lane];
      a0 = fmaf(w0, __uint_as_float(u.x << 16), a0);
      a1 = fmaf(w1, __uint_as_float(u.x & 0xffff0000u), a1);
      a2 = fmaf(w2, __uint_as_float(u.y << 16), a2);
      a3 = fmaf(w3, __uint_as_float(u.y & 0xffff0000u), a3);
    }
  }

  size_t base = (size_t)node * 256;
  float v0 = a0 + bias[lane];
  float v1 = a1 + bias[64 + lane];
  float v2 = a2 + bias[128 + lane];
  float v3 = a3 + bias[192 + lane];
  if (RES) {
    v0 += hin[base + lane];
    v1 += hin[base + 64 + lane];
    v2 += hin[base + 128 + lane];
    v3 += hin[base + 192 + lane];
  }
  float o0 = eluf(v0), o1 = eluf(v1), o2 = eluf(v2), o3 = eluf(v3);
  hout[base + lane]       = o0;
  hout[base + 64 + lane]  = o1;
  hout[base + 128 + lane] = o2;
  hout[base + 192 + lane] = o3;
  if (NEXT) {
    houtb[base + lane]       = __float2bfloat16(o0);
    houtb[base + 64 + lane]  = __float2bfloat16(o1);
    houtb[base + 128 + lane] = __float2bfloat16(o2);
    houtb[base + 192 + lane] = __float2bfloat16(o3);
#pragma unroll
    for (int hh = 0; hh < 4; ++hh) {
      float sl = o0 * Waln[hh * 256 + lane] + o1 * Waln[hh * 256 + 64 + lane] +
                 o2 * Waln[hh * 256 + 128 + lane] + o3 * Waln[hh * 256 + 192 + lane];
      float sr = o0 * Warn[hh * 256 + lane] + o1 * Warn[hh * 256 + 64 + lane] +
                 o2 * Warn[hh * 256 + 128 + lane] + o3 * Warn[hh * 256 + 192 + lane];
      sl = wsum(sl);
      sr = wsum(sr);
      if (lane == 0) {
        eln[node * 4 + hh] = sl;
        ern[node * 4 + hh] = sr;
      }
    }
  }
}

// ---------------- layer 4 projection (fp32, unchanged) ----------------
__global__ __launch_bounds__(256) void l4_proj_k(const float* __restrict__ h,
                                                 const float* __restrict__ W4,
                                                 const float* __restrict__ rW4,
                                                 const float* __restrict__ al4,
                                                 const float* __restrict__ ar4,
                                                 float* __restrict__ feat4,
                                                 float* __restrict__ res4,
                                                 float* __restrict__ el4,
                                                 float* __restrict__ er4, int n) {
  int node = blockIdx.x * 4 + (threadIdx.x >> 6);
  int lane = threadIdx.x & 63;
  if (node >= n) return;
  float4 hv = *(const float4*)(h + (size_t)node * 256 + lane * 4);
  float fo[8], ro[8];
#pragma unroll
  for (int m = 0; m < 8; ++m) {
    float4 wv = *(const float4*)(W4 + m * 256 + lane * 4);
    fo[m] = wsum(fmaf(hv.x, wv.x, fmaf(hv.y, wv.y, fmaf(hv.z, wv.z, hv.w * wv.w))));
    float4 rv = *(const float4*)(rW4 + m * 256 + lane * 4);
    ro[m] = wsum(fmaf(hv.x, rv.x, fmaf(hv.y, rv.y, fmaf(hv.z, rv.z, hv.w * rv.w))));
  }
  if (lane == 0) {
#pragma unroll
    for (int m = 0; m < 8; ++m) {
      feat4[(size_t)node * 8 + m] = fo[m];
      res4[(size_t)node * 8 + m] = ro[m];
    }
#pragma unroll
    for (int hh = 0; hh < 4; ++hh) {
      el4[(size_t)node * 4 + hh] = fo[2 * hh] * al4[2 * hh] + fo[2 * hh + 1] * al4[2 * hh + 1];
      er4[(size_t)node * 4 + hh] = fo[2 * hh] * ar4[2 * hh] + fo[2 * hh + 1] * ar4[2 * hh + 1];
    }
  }
}

// ---------------- layer 4 aggregate + per-head softmax + head mean ----------------
__global__ __launch_bounds__(256) void agg4_k(const float* __restrict__ feat4,
                                              const float* __restrict__ el4,
                                              const float* __restrict__ er4,
                                              const int* __restrict__ rowp,
                                              const int* __restrict__ csrc,
                                              const float* __restrict__ res4,
                                              const float* __restrict__ b4,
                                              float* __restrict__ out, int n) {
  int node = blockIdx.x * 4 + (threadIdx.x >> 6);
  int lane = threadIdx.x & 63;
  if (node >= n) return;
  int s0 = rowp[node], s1 = rowp[node + 1];
  int deg = s1 - s0;
  float4 erv = *(const float4*)(er4 + (size_t)node * 4);
  float acc = 0.f;
  int p = lane & 7, hh = p >> 1;

  if (deg <= 64) {
    int sown = 0;
    float e0 = -INFINITY, e1 = -INFINITY, e2 = -INFINITY, e3 = -INFINITY;
    if (lane < deg) {
      sown = csrc[s0 + lane];
      float4 e = *(const float4*)(el4 + (size_t)sown * 4);
      e0 = leaky(e.x + erv.x);
      e1 = leaky(e.y + erv.y);
      e2 = leaky(e.z + erv.z);
      e3 = leaky(e.w + erv.w);
    }
    float m0 = wmax(e0), m1 = wmax(e1), m2 = wmax(e2), m3 = wmax(e3);
    float x0 = (lane < deg) ? __expf(e0 - m0) : 0.f;
    float x1 = (lane < deg) ? __expf(e1 - m1) : 0.f;
    float x2 = (lane < deg) ? __expf(e2 - m2) : 0.f;
    float x3 = (lane < deg) ? __expf(e3 - m3) : 0.f;
    float d0 = wsum(x0), d1 = wsum(x1), d2 = wsum(x2), d3 = wsum(x3);
    float w0 = x0 * (d0 > 0.f ? 1.f / d0 : 0.f);
    float w1 = x1 * (d1 > 0.f ? 1.f / d1 : 0.f);
    float w2 = x2 * (d2 > 0.f ? 1.f / d2 : 0.f);
    float w3 = x3 * (d3 > 0.f ? 1.f / d3 : 0.f);
    int g = lane >> 3;
    int nt = (deg + 7) >> 3;
    for (int t = 0; t < nt; ++t) {
      int k = g + t * 8;
      bool ok = k < deg;
      int kk = k & 63;
      int sk = __shfl(sown, kk);
      float w0k = __shfl(w0, kk), w1k = __shfl(w1, kk);
      float w2k = __shfl(w2, kk), w3k = __shfl(w3, kk);
      float wk = (hh == 0) ? w0k : (hh == 1) ? w1k : (hh == 2) ? w2k : w3k;
      if (ok) acc = fmaf(wk, feat4[(size_t)sk * 8 + p], acc);
    }
    acc += __shfl_xor(acc, 8);
    acc += __shfl_xor(acc, 16);
    acc += __shfl_xor(acc, 32);
  } else {
    float m0 = -INFINITY, m1 = -INFINITY, m2 = -INFINITY, m3 = -INFINITY;
    for (int k = s0 + lane; k < s1; k += 64) {
      int s = csrc[k];
      float4 e = *(const float4*)(el4 + (size_t)s * 4);
      m0 = fmaxf(m0, leaky(e.x + erv.x));
      m1 = fmaxf(m1, leaky(e.y + erv.y));
      m2 = fmaxf(m2, leaky(e.z + erv.z));
      m3 = fmaxf(m3, leaky(e.w + erv.w));
    }
    m0 = wmax(m0); m1 = wmax(m1); m2 = wmax(m2); m3 = wmax(m3);
    float d0 = 0, d1 = 0, d2 = 0, d3 = 0;
    for (int k = s0 + lane; k < s1; k += 64) {
      int s = csrc[k];
      float4 e = *(const float4*)(el4 + (size_t)s * 4);
      d0 += __expf(leaky(e.x + erv.x) - m0);
      d1 += __expf(leaky(e.y + erv.y) - m1);
      d2 += __expf(leaky(e.z + erv.z) - m2);
      d3 += __expf(leaky(e.w + erv.w) - m3);
    }
    d0 = wsum(d0); d1 = wsum(d1); d2 = wsum(d2); d3 = wsum(d3);
    float i0 = d0 > 0.f ? 1.f / d0 : 0.f;
    float i1 = d1 > 0.f ? 1.f / d1 : 0.f;
    float i2 = d2 > 0.f ? 1.f / d2 : 0.f;
    float i3 = d3 > 0.f ? 1.f / d3 : 0.f;
    for (int k = s0; k < s1; ++k) {
      int s = csrc[k];
      float4 e = *(const float4*)(el4 + (size_t)s * 4);
      float w0 = __expf(leaky(e.x + erv.x) - m0) * i0;
      float w1 = __expf(leaky(e.y + erv.y) - m1) * i1;
      float w2 = __expf(leaky(e.z + erv.z) - m2) * i2;
      float w3 = __expf(leaky(e.w + erv.w) - m3) * i3;
      float wk = (hh == 0) ? w0 : (hh == 1) ? w1 : (hh == 2) ? w2 : w3;
      if (lane < 8) acc = fmaf(wk, feat4[(size_t)s * 8 + p], acc);
    }
  }

  float v = 0.f;
  if (lane < 8) v = acc + res4[(size_t)node * 8 + lane] + b4[lane];
  float pv = __shfl_xor(v, 1);
  float mx = fmaxf(v, pv);
  float ex = __expf(v - mx);
  float sm = ex + __shfl_xor(ex, 1);
  float pr = ex / sm;
  float t = pr + __shfl_xor(pr, 2);
  t += __shfl_xor(t, 4);
  if (lane < 2) out[(size_t)node * 2 + lane] = t * 0.25f;
}

extern "C" void kernel_launch(void* const* d_in, const int* in_sizes, int n_in,
                              void* d_out, int out_size, void* d_ws, size_t ws_size,
                              hipStream_t stream) {
  const float* x   = (const float*)d_in[0];
  const int* src   = (const int*)d_in[1];
  const int* dst   = (const int*)d_in[2];
  const float* W1  = (const float*)d_in[3];
  const float* al1 = (const float*)d_in[4];
  const float* ar1 = (const float*)d_in[5];
  const float* b1  = (const float*)d_in[6];
  const float* W2  = (const float*)d_in[7];
  const float* al2 = (const float*)d_in[8];
  const float* ar2 = (const float*)d_in[9];
  const float* b2  = (const float*)d_in[10];
  const float* W3  = (const float*)d_in[11];
  const float* al3 = (const float*)d_in[12];
  const float* ar3 = (const float*)d_in[13];
  const float* b3  = (const float*)d_in[14];
  const float* W4  = (const float*)d_in[15];
  const float* al4 = (const float*)d_in[16];
  const float* ar4 = (const float*)d_in[17];
  const float* b4  = (const float*)d_in[18];
  const float* rW4 = (const float*)d_in[19];
  float* out = (float*)d_out;

  const int n = in_sizes[0] / 128;  // 50000
  const int e = in_sizes[1];        // 800000

  char* ws = (char*)d_ws;
  auto alloc = [&](size_t bytes) -> char* {
    char* p = ws;
    ws += (bytes + 255) & ~(size_t)255;
    return p;
  };
  float* hA    = (float*)alloc((size_t)n * 256 * 4);
  float* hB    = (float*)alloc((size_t)n * 256 * 4);
  __hip_bfloat16* featb = (__hip_bfloat16*)alloc((size_t)n * 256 * 2);
  __hip_bfloat16* hAb   = (__hip_bfloat16*)alloc((size_t)n * 256 * 2);
  __hip_bfloat16* hBb   = (__hip_bfloat16*)alloc((size_t)n * 256 * 2);
  __hip_bfloat16* xb    = (__hip_bfloat16*)alloc((size_t)n * 128 * 2);
  __hip_bfloat16* W1b   = (__hip_bfloat16*)alloc((size_t)256 * 128 * 2);
  __hip_bfloat16* W2b   = (__hip_bfloat16*)alloc((size_t)256 * 256 * 2);
  __hip_bfloat16* W3b   = (__hip_bfloat16*)alloc((size_t)256 * 256 * 2);
  float* Wal1 = (float*)alloc((size_t)4 * 128 * 4);
  float* War1 = (float*)alloc((size_t)4 * 128 * 4);
  float* Wal2 = (float*)alloc((size_t)4 * 256 * 4);
  float* War2 = (float*)alloc((size_t)4 * 256 * 4);
  float* Wal3 = (float*)alloc((size_t)4 * 256 * 4);
  float* War3 = (float*)alloc((size_t)4 * 256 * 4);
  float* elA   = (float*)alloc((size_t)n * 4 * 4);
  float* erA   = (float*)alloc((size_t)n * 4 * 4);
  float* elB   = (float*)alloc((size_t)n * 4 * 4);
  float* erB   = (float*)alloc((size_t)n * 4 * 4);
  float* feat4 = (float*)alloc((size_t)n * 8 * 4);
  float* res4  = (float*)alloc((size_t)n * 8 * 4);
  float* el4   = (float*)alloc((size_t)n * 4 * 4);
  float* er4   = (float*)alloc((size_t)n * 4 * 4);
  int* deg     = (int*)alloc((size_t)n * 4);
  int* cur     = (int*)alloc((size_t)n * 4);
  int* rowp    = (int*)alloc((size_t)(n + 1) * 4);
  int* csrc    = (int*)alloc((size_t)e * 4);
  int nb_scan  = (n + 1023) / 1024;
  int* bsum    = (int*)alloc((size_t)(nb_scan + 1) * 4);

  // CSR build
  hipMemsetAsync(deg, 0, (size_t)n * 4, stream);
  hipMemsetAsync(cur, 0, (size_t)n * 4, stream);
  hist_k<<<(e + 255) / 256, 256, 0, stream>>>(dst, deg, e);
  scan1_k<<<nb_scan, 1024, 0, stream>>>(deg, rowp, bsum, n);
  scan2_k<<<1, 64, 0, stream>>>(bsum, nb_scan);
  scan3_k<<<(n + 256) / 256, 256, 0, stream>>>(bsum, rowp, n, nb_scan);
  scatter_k<<<(e + 255) / 256, 256, 0, stream>>>(src, dst, rowp, cur, csrc, e);

  // weight prep
  cvt_k<<<(n * 128 + 255) / 256, 256, 0, stream>>>(x, xb, n * 128);
  cvt_k<<<(256 * 128 + 255) / 256, 256, 0, stream>>>(W1, W1b, 256 * 128);
  cvt_k<<<(256 * 256 + 255) / 256, 256, 0, stream>>>(W2, W2b, 256 * 256);
  cvt_k<<<(256 * 256 + 255) / 256, 256, 0, stream>>>(W3, W3b, 256 * 256);
  wa_k<<<(4 * 128 + 255) / 256, 256, 0, stream>>>(W1, al1, ar1, Wal1, War1, 128);
  wa_k<<<(4 * 256 + 255) / 256, 256, 0, stream>>>(W2, al2, ar2, Wal2, War2, 256);
  wa_k<<<(4 * 256 + 255) / 256, 256, 0, stream>>>(W3, al3, ar3, Wal3, War3, 256);

  dim3 ggrid((n + 127) / 128, 2);
  int nb4 = (n + 3) / 4;

  // layer 1
  elproj_k<<<nb4, 256, 0, stream>>>(x, Wal1, War1, elA, erA, n);
  gemm_mfma<128><<<ggrid, 256, 0, stream>>>(xb, W1b, featb, n);
  agg64_k<0, 1><<<nb4, 256, 0, stream>>>(featb, elA, erA, rowp, csrc, nullptr, b1, hA, hAb,
                                         Wal2, War2, elB, erB, n);
  // layer 2
  gemm_mfma<256><<<ggrid, 256, 0, stream>>>(hAb, W2b, featb, n);
  agg64_k<1, 1><<<nb4, 256, 0, stream>>>(featb, elB, erB, rowp, csrc, hA, b2, hB, hBb,
                                         Wal3, War3, elA, erA, n);
  // layer 3
  gemm_mfma<256><<<ggrid, 256, 0, stream>>>(hBb, W3b, featb, n);
  agg64_k<1, 0><<<nb4, 256, 0, stream>>>(featb, elA, erA, rowp, csrc, hB, b3, hA, nullptr,
                                         nullptr, nullptr, nullptr, nullptr, n);
  // layer 4
  l4_proj_k<<<nb4, 256, 0, stream>>>(hA, W4, rW4, al4, ar4, feat4, res4, el4, er4, n);
  agg4_k<<<nb4, 256, 0, stream>>>(feat4, el4, er4, rowp, csrc, res4, b4, out, n);
}

// Round 4
// 661.877 us; speedup vs baseline: 1.8428x; 1.0764x over previous
//
#include <hip/hip_runtime.h>
#include <hip/hip_bf16.h>
#include <math.h>

// GAT, 4 layers: N=50000, E=800000, IN=128, HID=64, H=4, C=2.
// R4: all-bf16 node features (h) — fp32 h buffers deleted; attention logits
// stay fp32 via fused Wal/War projections from register fp32 values.
// agg64 gather loop 4-wide unrolled for MLP. Prep kernels fused.

#define LEAKY_SLOPE 0.2f

typedef __bf16 bf16x8_t __attribute__((ext_vector_type(8)));
typedef float f32x4_t __attribute__((ext_vector_type(4)));

__device__ __forceinline__ float leaky(float x) { return x > 0.f ? x : LEAKY_SLOPE * x; }
__device__ __forceinline__ float eluf(float x)  { return x > 0.f ? x : expm1f(x); }
__device__ __forceinline__ float bflo(unsigned u) { return __uint_as_float(u << 16); }
__device__ __forceinline__ float bfhi(unsigned u) { return __uint_as_float(u & 0xffff0000u); }

__device__ __forceinline__ float wsum(float v) {
#pragma unroll
  for (int o = 32; o; o >>= 1) v += __shfl_xor(v, o);
  return v;
}
__device__ __forceinline__ float wmax(float v) {
#pragma unroll
  for (int o = 32; o; o >>= 1) v = fmaxf(v, __shfl_xor(v, o));
  return v;
}

// ---------------- CSR build ----------------
__global__ void hist_k(const int* __restrict__ dst, int* __restrict__ deg, int e) {
  int i = blockIdx.x * 256 + threadIdx.x;
  if (i < e) atomicAdd(&deg[dst[i]], 1);
}

__global__ __launch_bounds__(1024) void scan1_k(const int* __restrict__ deg,
                                                int* __restrict__ rowp,
                                                int* __restrict__ bsum, int n) {
  __shared__ int sd[1024];
  int tid = threadIdx.x;
  int i = blockIdx.x * 1024 + tid;
  int v = (i < n) ? deg[i] : 0;
  int x = v;
  sd[tid] = x;
  __syncthreads();
  for (int off = 1; off < 1024; off <<= 1) {
    int t = (tid >= off) ? sd[tid - off] : 0;
    __syncthreads();
    x += t;
    sd[tid] = x;
    __syncthreads();
  }
  if (i < n) rowp[i] = x - v;
  if (tid == 1023) bsum[blockIdx.x] = x;
}

__global__ __launch_bounds__(64) void scan2_k(int* __restrict__ bsum, int nb) {
  int lane = threadIdx.x;
  if (nb <= 64) {
    int v = (lane < nb) ? bsum[lane] : 0;
    int x = v;
#pragma unroll
    for (int off = 1; off < 64; off <<= 1) {
      int t = __shfl_up(x, off);
      if (lane >= off) x += t;
    }
    if (lane < nb) bsum[lane] = x - v;
    if (lane == 63) bsum[nb] = x;
  } else if (lane == 0) {
    int run = 0;
    for (int i = 0; i < nb; ++i) { int t = bsum[i]; bsum[i] = run; run += t; }
    bsum[nb] = run;
  }
}

__global__ void scan3_k(const int* __restrict__ bsum, int* __restrict__ rowp, int n, int nb) {
  int i = blockIdx.x * 256 + threadIdx.x;
  if (i < n) rowp[i] += bsum[i >> 10];
  if (i == n) rowp[n] = bsum[nb];
}

__global__ void scatter_k(const int* __restrict__ src, const int* __restrict__ dst,
                          const int* __restrict__ rowp, int* __restrict__ cur,
                          int* __restrict__ csrc, int e) {
  int i = blockIdx.x * 256 + threadIdx.x;
  if (i < e) {
    int d = dst[i];
    int p = atomicAdd(&cur[d], 1);
    csrc[rowp[d] + p] = src[i];
  }
}

// ---------------- prep: converts + Wal/War projections ----------------
__global__ void cvt_k(const float* __restrict__ a, __hip_bfloat16* __restrict__ b, int cnt) {
  int i = blockIdx.x * 256 + threadIdx.x;
  if (i < cnt) b[i] = __float2bfloat16(a[i]);
}

// all three weight matrices in one launch: W1(32768) | W2(65536) | W3(65536)
__global__ void cvtw_k(const float* __restrict__ W1, const float* __restrict__ W2,
                       const float* __restrict__ W3, __hip_bfloat16* __restrict__ W1b,
                       __hip_bfloat16* __restrict__ W2b, __hip_bfloat16* __restrict__ W3b) {
  int i = blockIdx.x * 256 + threadIdx.x;
  if (i < 32768) W1b[i] = __float2bfloat16(W1[i]);
  else if (i < 98304) { int j = i - 32768; W2b[j] = __float2bfloat16(W2[j]); }
  else if (i < 163840) { int j = i - 98304; W3b[j] = __float2bfloat16(W3[j]); }
}

// Wal[hh][col] = sum_o al[hh*64+o] * W[(hh*64+o)*K + col]; 3 layers fused.
__global__ void wa_all_k(const float* __restrict__ W1, const float* __restrict__ al1,
                         const float* __restrict__ ar1, float* __restrict__ Wal1,
                         float* __restrict__ War1, const float* __restrict__ W2,
                         const float* __restrict__ al2, const float* __restrict__ ar2,
                         float* __restrict__ Wal2, float* __restrict__ War2,
                         const float* __restrict__ W3, const float* __restrict__ al3,
                         const float* __restrict__ ar3, float* __restrict__ Wal3,
                         float* __restrict__ War3) {
  int i = blockIdx.x * 256 + threadIdx.x;
  const float *W, *al, *ar;
  float *Wal, *War;
  int K, idx;
  if (i < 512)       { W = W1; al = al1; ar = ar1; Wal = Wal1; War = War1; K = 128; idx = i; }
  else if (i < 1536) { W = W2; al = al2; ar = ar2; Wal = Wal2; War = War2; K = 256; idx = i - 512; }
  else if (i < 2560) { W = W3; al = al3; ar = ar3; Wal = Wal3; War = War3; K = 256; idx = i - 1536; }
  else return;
  int hh = idx / K, col = idx - hh * K;
  float sl = 0.f, sr = 0.f;
  const float* wp = W + (size_t)(hh * 64) * K + col;
#pragma unroll 4
  for (int o = 0; o < 64; ++o) {
    float wv = wp[(size_t)o * K];
    sl = fmaf(al[hh * 64 + o], wv, sl);
    sr = fmaf(ar[hh * 64 + o], wv, sr);
  }
  Wal[idx] = sl;
  War[idx] = sr;
}

// layer-1 el/er from fp32 x (K=128): one wave per node (exact logits)
__global__ __launch_bounds__(256) void elproj_k(const float* __restrict__ x,
                                                const float* __restrict__ Wal,
                                                const float* __restrict__ War,
                                                float* __restrict__ el,
                                                float* __restrict__ er, int n) {
  int node = blockIdx.x * 4 + (threadIdx.x >> 6);
  int lane = threadIdx.x & 63;
  if (node >= n) return;
  float2 xv = *(const float2*)(x + (size_t)node * 128 + lane * 2);
#pragma unroll
  for (int hh = 0; hh < 4; ++hh) {
    float sl = xv.x * Wal[hh * 128 + 2 * lane] + xv.y * Wal[hh * 128 + 2 * lane + 1];
    float sr = xv.x * War[hh * 128 + 2 * lane] + xv.y * War[hh * 128 + 2 * lane + 1];
    sl = wsum(sl);
    sr = wsum(sr);
    if (lane == 0) {
      el[node * 4 + hh] = sl;
      er[node * 4 + hh] = sr;
    }
  }
}

// ---------------- MFMA GEMM: featb[n][o=64][h=4](bf16) = A[n][K] @ B[256][K]^T ----------------
template <int K>
__global__ __launch_bounds__(256) void gemm_mfma(const __hip_bfloat16* __restrict__ A,
                                                 const __hip_bfloat16* __restrict__ B,
                                                 __hip_bfloat16* __restrict__ featb, int n) {
  __shared__ __bf16 As[128 * 40];
  __shared__ __bf16 Bs[128 * 40];
  const int tid = threadIdx.x;
  const int lane = tid & 63, w = tid >> 6;
  const int tm = lane & 15, tq = lane >> 4;
  const int wm = (w & 1) * 64, wn = (w >> 1) * 64;
  const int r0 = blockIdx.x * 128, c0 = blockIdx.y * 128;
  const int srow = tid >> 1, sko = (tid & 1) * 16;

  f32x4_t acc[4][4];
#pragma unroll
  for (int i = 0; i < 4; ++i)
#pragma unroll
    for (int j = 0; j < 4; ++j) acc[i][j] = 0.f;

  for (int kk = 0; kk < K; kk += 32) {
    uint4 av0 = {0, 0, 0, 0}, av1 = {0, 0, 0, 0};
    int arw = r0 + srow;
    if (arw < n) {
      const uint4* p = (const uint4*)(A + (size_t)arw * K + kk + sko);
      av0 = p[0];
      av1 = p[1];
    }
    const uint4* q = (const uint4*)(B + (size_t)(c0 + srow) * K + kk + sko);
    uint4 bv0 = q[0], bv1 = q[1];
    __syncthreads();
    *(uint4*)&As[srow * 40 + sko] = av0;
    *(uint4*)&As[srow * 40 + sko + 8] = av1;
    *(uint4*)&Bs[srow * 40 + sko] = bv0;
    *(uint4*)&Bs[srow * 40 + sko + 8] = bv1;
    __syncthreads();
    bf16x8_t af[4], bfr[4];
#pragma unroll
    for (int i = 0; i < 4; ++i) af[i] = *(const bf16x8_t*)&As[(wm + i * 16 + tm) * 40 + tq * 8];
#pragma unroll
    for (int j = 0; j < 4; ++j) bfr[j] = *(const bf16x8_t*)&Bs[(wn + j * 16 + tm) * 40 + tq * 8];
#pragma unroll
    for (int i = 0; i < 4; ++i)
#pragma unroll
      for (int j = 0; j < 4; ++j)
        acc[i][j] = __builtin_amdgcn_mfma_f32_16x16x32_bf16(af[i], bfr[j], acc[i][j], 0, 0, 0);
  }

#pragma unroll
  for (int i = 0; i < 4; ++i) {
#pragma unroll
    for (int j = 0; j < 4; ++j) {
      int col = c0 + wn + j * 16 + tm;
      int hh = col >> 6, oo = col & 63;
#pragma unroll
      for (int rr = 0; rr < 4; ++rr) {
        int row = r0 + wm + i * 16 + tq * 4 + rr;
        if (row < n) featb[(size_t)row * 256 + oo * 4 + hh] = __float2bfloat16(acc[i][j][rr]);
      }
    }
  }
}

// ---------------- aggregate layers 1-3: one wave per dst node ----------------
// h kept bf16 everywhere; el/er for next layer from fp32 register values.
template <int RES, int NEXT>
__global__ __launch_bounds__(256) void agg64_k(const __hip_bfloat16* __restrict__ featb,
                                               const float* __restrict__ el,
                                               const float* __restrict__ er,
                                               const int* __restrict__ rowp,
                                               const int* __restrict__ csrc,
                                               const __hip_bfloat16* __restrict__ hinb,
                                               const float* __restrict__ bias,
                                               __hip_bfloat16* __restrict__ houtb,
                                               const float* __restrict__ Waln,
                                               const float* __restrict__ Warn,
                                               float* __restrict__ eln,
                                               float* __restrict__ ern, int n) {
  int node = blockIdx.x * 4 + (threadIdx.x >> 6);
  int lane = threadIdx.x & 63;
  if (node >= n) return;
  int s0 = rowp[node], s1 = rowp[node + 1];
  int deg = s1 - s0;
  float4 erv = *(const float4*)(er + (size_t)node * 4);
  float a0 = 0, a1 = 0, a2 = 0, a3 = 0;

  if (deg <= 64) {
    int sown = 0;
    float e0 = -INFINITY, e1 = -INFINITY, e2 = -INFINITY, e3 = -INFINITY;
    if (lane < deg) {
      sown = csrc[s0 + lane];
      float4 e = *(const float4*)(el + (size_t)sown * 4);
      e0 = leaky(e.x + erv.x);
      e1 = leaky(e.y + erv.y);
      e2 = leaky(e.z + erv.z);
      e3 = leaky(e.w + erv.w);
    }
    float m0 = wmax(e0), m1 = wmax(e1), m2 = wmax(e2), m3 = wmax(e3);
    float x0 = (lane < deg) ? __expf(e0 - m0) : 0.f;
    float x1 = (lane < deg) ? __expf(e1 - m1) : 0.f;
    float x2 = (lane < deg) ? __expf(e2 - m2) : 0.f;
    float x3 = (lane < deg) ? __expf(e3 - m3) : 0.f;
    float d0 = wsum(x0), d1 = wsum(x1), d2 = wsum(x2), d3 = wsum(x3);
    float w0 = x0 * (d0 > 0.f ? 1.f / d0 : 0.f);
    float w1 = x1 * (d1 > 0.f ? 1.f / d1 : 0.f);
    float w2 = x2 * (d2 > 0.f ? 1.f / d2 : 0.f);
    float w3 = x3 * (d3 > 0.f ? 1.f / d3 : 0.f);

    // 4-wide unrolled gather: 4 independent 8B row loads in flight
    int k = 0;
    for (; k + 4 <= deg; k += 4) {
      int sk0 = __shfl(sown, k + 0);
      int sk1 = __shfl(sown, k + 1);
      int sk2 = __shfl(sown, k + 2);
      int sk3 = __shfl(sown, k + 3);
      uint2 u0 = ((const uint2*)(featb + ((size_t)sk0 << 8)))[lane];
      uint2 u1 = ((const uint2*)(featb + ((size_t)sk1 << 8)))[lane];
      uint2 u2 = ((const uint2*)(featb + ((size_t)sk2 << 8)))[lane];
      uint2 u3 = ((const uint2*)(featb + ((size_t)sk3 << 8)))[lane];
      float w00 = __shfl(w0, k + 0), w10 = __shfl(w1, k + 0), w20 = __shfl(w2, k + 0), w30 = __shfl(w3, k + 0);
      float w01 = __shfl(w0, k + 1), w11 = __shfl(w1, k + 1), w21 = __shfl(w2, k + 1), w31 = __shfl(w3, k + 1);
      float w02 = __shfl(w0, k + 2), w12 = __shfl(w1, k + 2), w22 = __shfl(w2, k + 2), w32 = __shfl(w3, k + 2);
      float w03 = __shfl(w0, k + 3), w13 = __shfl(w1, k + 3), w23 = __shfl(w2, k + 3), w33 = __shfl(w3, k + 3);
      a0 = fmaf(w00, bflo(u0.x), a0); a1 = fmaf(w10, bfhi(u0.x), a1);
      a2 = fmaf(w20, bflo(u0.y), a2); a3 = fmaf(w30, bfhi(u0.y), a3);
      a0 = fmaf(w01, bflo(u1.x), a0); a1 = fmaf(w11, bfhi(u1.x), a1);
      a2 = fmaf(w21, bflo(u1.y), a2); a3 = fmaf(w31, bfhi(u1.y), a3);
      a0 = fmaf(w02, bflo(u2.x), a0); a1 = fmaf(w12, bfhi(u2.x), a1);
      a2 = fmaf(w22, bflo(u2.y), a2); a3 = fmaf(w32, bfhi(u2.y), a3);
      a0 = fmaf(w03, bflo(u3.x), a0); a1 = fmaf(w13, bfhi(u3.x), a1);
      a2 = fmaf(w23, bflo(u3.y), a2); a3 = fmaf(w33, bfhi(u3.y), a3);
    }
    for (; k < deg; ++k) {
      int sk = __shfl(sown, k);
      float w0k = __shfl(w0, k), w1k = __shfl(w1, k);
      float w2k = __shfl(w2, k), w3k = __shfl(w3, k);
      uint2 u = ((const uint2*)(featb + ((size_t)sk << 8)))[lane];
      a0 = fmaf(w0k, bflo(u.x), a0);
      a1 = fmaf(w1k, bfhi(u.x), a1);
      a2 = fmaf(w2k, bflo(u.y), a2);
      a3 = fmaf(w3k, bfhi(u.y), a3);
    }
  } else {
    float m0 = -INFINITY, m1 = -INFINITY, m2 = -INFINITY, m3 = -INFINITY;
    for (int k = s0 + lane; k < s1; k += 64) {
      int s = csrc[k];
      float4 e = *(const float4*)(el + (size_t)s * 4);
      m0 = fmaxf(m0, leaky(e.x + erv.x));
      m1 = fmaxf(m1, leaky(e.y + erv.y));
      m2 = fmaxf(m2, leaky(e.z + erv.z));
      m3 = fmaxf(m3, leaky(e.w + erv.w));
    }
    m0 = wmax(m0); m1 = wmax(m1); m2 = wmax(m2); m3 = wmax(m3);
    float d0 = 0, d1 = 0, d2 = 0, d3 = 0;
    for (int k = s0 + lane; k < s1; k += 64) {
      int s = csrc[k];
      float4 e = *(const float4*)(el + (size_t)s * 4);
      d0 += __expf(leaky(e.x + erv.x) - m0);
      d1 += __expf(leaky(e.y + erv.y) - m1);
      d2 += __expf(leaky(e.z + erv.z) - m2);
      d3 += __expf(leaky(e.w + erv.w) - m3);
    }
    d0 = wsum(d0); d1 = wsum(d1); d2 = wsum(d2); d3 = wsum(d3);
    float i0 = d0 > 0.f ? 1.f / d0 : 0.f;
    float i1 = d1 > 0.f ? 1.f / d1 : 0.f;
    float i2 = d2 > 0.f ? 1.f / d2 : 0.f;
    float i3 = d3 > 0.f ? 1.f / d3 : 0.f;
    for (int k = s0; k < s1; ++k) {
      int s = csrc[k];
      float4 e = *(const float4*)(el + (size_t)s * 4);
      float w0 = __expf(leaky(e.x + erv.x) - m0) * i0;
      float w1 = __expf(leaky(e.y + erv.y) - m1) * i1;
      float w2 = __expf(leaky(e.z + erv.z) - m2) * i2;
      float w3 = __expf(leaky(e.w + erv.w) - m3) * i3;
      uint2 u = ((const uint2*)(featb + ((size_t)s << 8)))[lane];
      a0 = fmaf(w0, bflo(u.x), a0);
      a1 = fmaf(w1, bfhi(u.x), a1);
      a2 = fmaf(w2, bflo(u.y), a2);
      a3 = fmaf(w3, bfhi(u.y), a3);
    }
  }

  size_t base = (size_t)node * 256;
  float v0 = a0 + bias[lane];
  float v1 = a1 + bias[64 + lane];
  float v2 = a2 + bias[128 + lane];
  float v3 = a3 + bias[192 + lane];
  if (RES) {
    v0 += __bfloat162float(hinb[base + lane]);
    v1 += __bfloat162float(hinb[base + 64 + lane]);
    v2 += __bfloat162float(hinb[base + 128 + lane]);
    v3 += __bfloat162float(hinb[base + 192 + lane]);
  }
  float o0 = eluf(v0), o1 = eluf(v1), o2 = eluf(v2), o3 = eluf(v3);
  houtb[base + lane]       = __float2bfloat16(o0);
  houtb[base + 64 + lane]  = __float2bfloat16(o1);
  houtb[base + 128 + lane] = __float2bfloat16(o2);
  houtb[base + 192 + lane] = __float2bfloat16(o3);
  if (NEXT) {
#pragma unroll
    for (int hh = 0; hh < 4; ++hh) {
      float sl = o0 * Waln[hh * 256 + lane] + o1 * Waln[hh * 256 + 64 + lane] +
                 o2 * Waln[hh * 256 + 128 + lane] + o3 * Waln[hh * 256 + 192 + lane];
      float sr = o0 * Warn[hh * 256 + lane] + o1 * Warn[hh * 256 + 64 + lane] +
                 o2 * Warn[hh * 256 + 128 + lane] + o3 * Warn[hh * 256 + 192 + lane];
      sl = wsum(sl);
      sr = wsum(sr);
      if (lane == 0) {
        eln[node * 4 + hh] = sl;
        ern[node * 4 + hh] = sr;
      }
    }
  }
}

// ---------------- layer 4 projection from bf16 h ----------------
__global__ __launch_bounds__(256) void l4_proj_k(const __hip_bfloat16* __restrict__ hb,
                                                 const float* __restrict__ W4,
                                                 const float* __restrict__ rW4,
                                                 const float* __restrict__ al4,
                                                 const float* __restrict__ ar4,
                                                 float* __restrict__ feat4,
                                                 float* __restrict__ res4,
                                                 float* __restrict__ el4,
                                                 float* __restrict__ er4, int n) {
  int node = blockIdx.x * 4 + (threadIdx.x >> 6);
  int lane = threadIdx.x & 63;
  if (node >= n) return;
  uint2 hu = *(const uint2*)(hb + (size_t)node * 256 + lane * 4);
  float hx = bflo(hu.x), hy = bfhi(hu.x), hz = bflo(hu.y), hw = bfhi(hu.y);
  float fo[8], ro[8];
#pragma unroll
  for (int m = 0; m < 8; ++m) {
    float4 wv = *(const float4*)(W4 + m * 256 + lane * 4);
    fo[m] = wsum(fmaf(hx, wv.x, fmaf(hy, wv.y, fmaf(hz, wv.z, hw * wv.w))));
    float4 rv = *(const float4*)(rW4 + m * 256 + lane * 4);
    ro[m] = wsum(fmaf(hx, rv.x, fmaf(hy, rv.y, fmaf(hz, rv.z, hw * rv.w))));
  }
  if (lane == 0) {
#pragma unroll
    for (int m = 0; m < 8; ++m) {
      feat4[(size_t)node * 8 + m] = fo[m];
      res4[(size_t)node * 8 + m] = ro[m];
    }
#pragma unroll
    for (int hh = 0; hh < 4; ++hh) {
      el4[(size_t)node * 4 + hh] = fo[2 * hh] * al4[2 * hh] + fo[2 * hh + 1] * al4[2 * hh + 1];
      er4[(size_t)node * 4 + hh] = fo[2 * hh] * ar4[2 * hh] + fo[2 * hh + 1] * ar4[2 * hh + 1];
    }
  }
}

// ---------------- layer 4 aggregate + per-head softmax + head mean ----------------
__global__ __launch_bounds__(256) void agg4_k(const float* __restrict__ feat4,
                                              const float* __restrict__ el4,
                                              const float* __restrict__ er4,
                                              const int* __restrict__ rowp,
                                              const int* __restrict__ csrc,
                                              const float* __restrict__ res4,
                                              const float* __restrict__ b4,
                                              float* __restrict__ out, int n) {
  int node = blockIdx.x * 4 + (threadIdx.x >> 6);
  int lane = threadIdx.x & 63;
  if (node >= n) return;
  int s0 = rowp[node], s1 = rowp[node + 1];
  int deg = s1 - s0;
  float4 erv = *(const float4*)(er4 + (size_t)node * 4);
  float acc = 0.f;
  int p = lane & 7, hh = p >> 1;

  if (deg <= 64) {
    int sown = 0;
    float e0 = -INFINITY, e1 = -INFINITY, e2 = -INFINITY, e3 = -INFINITY;
    if (lane < deg) {
      sown = csrc[s0 + lane];
      float4 e = *(const float4*)(el4 + (size_t)sown * 4);
      e0 = leaky(e.x + erv.x);
      e1 = leaky(e.y + erv.y);
      e2 = leaky(e.z + erv.z);
      e3 = leaky(e.w + erv.w);
    }
    float m0 = wmax(e0), m1 = wmax(e1), m2 = wmax(e2), m3 = wmax(e3);
    float x0 = (lane < deg) ? __expf(e0 - m0) : 0.f;
    float x1 = (lane < deg) ? __expf(e1 - m1) : 0.f;
    float x2 = (lane < deg) ? __expf(e2 - m2) : 0.f;
    float x3 = (lane < deg) ? __expf(e3 - m3) : 0.f;
    float d0 = wsum(x0), d1 = wsum(x1), d2 = wsum(x2), d3 = wsum(x3);
    float w0 = x0 * (d0 > 0.f ? 1.f / d0 : 0.f);
    float w1 = x1 * (d1 > 0.f ? 1.f / d1 : 0.f);
    float w2 = x2 * (d2 > 0.f ? 1.f / d2 : 0.f);
    float w3 = x3 * (d3 > 0.f ? 1.f / d3 : 0.f);
    int g = lane >> 3;
    int nt = (deg + 7) >> 3;
    for (int t = 0; t < nt; ++t) {
      int k = g + t * 8;
      bool ok = k < deg;
      int kk = k & 63;
      int sk = __shfl(sown, kk);
      float w0k = __shfl(w0, kk), w1k = __shfl(w1, kk);
      float w2k = __shfl(w2, kk), w3k = __shfl(w3, kk);
      float wk = (hh == 0) ? w0k : (hh == 1) ? w1k : (hh == 2) ? w2k : w3k;
      if (ok) acc = fmaf(wk, feat4[(size_t)sk * 8 + p], acc);
    }
    acc += __shfl_xor(acc, 8);
    acc += __shfl_xor(acc, 16);
    acc += __shfl_xor(acc, 32);
  } else {
    float m0 = -INFINITY, m1 = -INFINITY, m2 = -INFINITY, m3 = -INFINITY;
    for (int k = s0 + lane; k < s1; k += 64) {
      int s = csrc[k];
      float4 e = *(const float4*)(el4 + (size_t)s * 4);
      m0 = fmaxf(m0, leaky(e.x + erv.x));
      m1 = fmaxf(m1, leaky(e.y + erv.y));
      m2 = fmaxf(m2, leaky(e.z + erv.z));
      m3 = fmaxf(m3, leaky(e.w + erv.w));
    }
    m0 = wmax(m0); m1 = wmax(m1); m2 = wmax(m2); m3 = wmax(m3);
    float d0 = 0, d1 = 0, d2 = 0, d3 = 0;
    for (int k = s0 + lane; k < s1; k += 64) {
      int s = csrc[k];
      float4 e = *(const float4*)(el4 + (size_t)s * 4);
      d0 += __expf(leaky(e.x + erv.x) - m0);
      d1 += __expf(leaky(e.y + erv.y) - m1);
      d2 += __expf(leaky(e.z + erv.z) - m2);
      d3 += __expf(leaky(e.w + erv.w) - m3);
    }
    d0 = wsum(d0); d1 = wsum(d1); d2 = wsum(d2); d3 = wsum(d3);
    float i0 = d0 > 0.f ? 1.f / d0 : 0.f;
    float i1 = d1 > 0.f ? 1.f / d1 : 0.f;
    float i2 = d2 > 0.f ? 1.f / d2 : 0.f;
    float i3 = d3 > 0.f ? 1.f / d3 : 0.f;
    for (int k = s0; k < s1; ++k) {
      int s = csrc[k];
      float4 e = *(const float4*)(el4 + (size_t)s * 4);
      float w0 = __expf(leaky(e.x + erv.x) - m0) * i0;
      float w1 = __expf(leaky(e.y + erv.y) - m1) * i1;
      float w2 = __expf(leaky(e.z + erv.z) - m2) * i2;
      float w3 = __expf(leaky(e.w + erv.w) - m3) * i3;
      float wk = (hh == 0) ? w0 : (hh == 1) ? w1 : (hh == 2) ? w2 : w3;
      if (lane < 8) acc = fmaf(wk, feat4[(size_t)s * 8 + p], acc);
    }
  }

  float v = 0.f;
  if (lane < 8) v = acc + res4[(size_t)node * 8 + lane] + b4[lane];
  float pv = __shfl_xor(v, 1);
  float mx = fmaxf(v, pv);
  float ex = __expf(v - mx);
  float sm = ex + __shfl_xor(ex, 1);
  float pr = ex / sm;
  float t = pr + __shfl_xor(pr, 2);
  t += __shfl_xor(t, 4);
  if (lane < 2) out[(size_t)node * 2 + lane] = t * 0.25f;
}

extern "C" void kernel_launch(void* const* d_in, const int* in_sizes, int n_in,
                              void* d_out, int out_size, void* d_ws, size_t ws_size,
                              hipStream_t stream) {
  const float* x   = (const float*)d_in[0];
  const int* src   = (const int*)d_in[1];
  const int* dst   = (const int*)d_in[2];
  const float* W1  = (const float*)d_in[3];
  const float* al1 = (const float*)d_in[4];
  const float* ar1 = (const float*)d_in[5];
  const float* b1  = (const float*)d_in[6];
  const float* W2  = (const float*)d_in[7];
  const float* al2 = (const float*)d_in[8];
  const float* ar2 = (const float*)d_in[9];
  const float* b2  = (const float*)d_in[10];
  const float* W3  = (const float*)d_in[11];
  const float* al3 = (const float*)d_in[12];
  const float* ar3 = (const float*)d_in[13];
  const float* b3  = (const float*)d_in[14];
  const float* W4  = (const float*)d_in[15];
  const float* al4 = (const float*)d_in[16];
  const float* ar4 = (const float*)d_in[17];
  const float* b4  = (const float*)d_in[18];
  const float* rW4 = (const float*)d_in[19];
  float* out = (float*)d_out;

  const int n = in_sizes[0] / 128;  // 50000
  const int e = in_sizes[1];        // 800000

  char* ws = (char*)d_ws;
  auto alloc = [&](size_t bytes) -> char* {
    char* p = ws;
    ws += (bytes + 255) & ~(size_t)255;
    return p;
  };
  __hip_bfloat16* featb = (__hip_bfloat16*)alloc((size_t)n * 256 * 2);
  __hip_bfloat16* h1b   = (__hip_bfloat16*)alloc((size_t)n * 256 * 2);
  __hip_bfloat16* h2b   = (__hip_bfloat16*)alloc((size_t)n * 256 * 2);
  __hip_bfloat16* h3b   = (__hip_bfloat16*)alloc((size_t)n * 256 * 2);
  __hip_bfloat16* xb    = (__hip_bfloat16*)alloc((size_t)n * 128 * 2);
  __hip_bfloat16* W1b   = (__hip_bfloat16*)alloc((size_t)256 * 128 * 2);
  __hip_bfloat16* W2b   = (__hip_bfloat16*)alloc((size_t)256 * 256 * 2);
  __hip_bfloat16* W3b   = (__hip_bfloat16*)alloc((size_t)256 * 256 * 2);
  float* Wal1 = (float*)alloc((size_t)4 * 128 * 4);
  float* War1 = (float*)alloc((size_t)4 * 128 * 4);
  float* Wal2 = (float*)alloc((size_t)4 * 256 * 4);
  float* War2 = (float*)alloc((size_t)4 * 256 * 4);
  float* Wal3 = (float*)alloc((size_t)4 * 256 * 4);
  float* War3 = (float*)alloc((size_t)4 * 256 * 4);
  float* elA   = (float*)alloc((size_t)n * 4 * 4);
  float* erA   = (float*)alloc((size_t)n * 4 * 4);
  float* elB   = (float*)alloc((size_t)n * 4 * 4);
  float* erB   = (float*)alloc((size_t)n * 4 * 4);
  float* feat4 = (float*)alloc((size_t)n * 8 * 4);
  float* res4  = (float*)alloc((size_t)n * 8 * 4);
  float* el4   = (float*)alloc((size_t)n * 4 * 4);
  float* er4   = (float*)alloc((size_t)n * 4 * 4);
  int* deg     = (int*)alloc((size_t)n * 4);
  int* cur     = (int*)alloc((size_t)n * 4);
  int* rowp    = (int*)alloc((size_t)(n + 1) * 4);
  int* csrc    = (int*)alloc((size_t)e * 4);
  int nb_scan  = (n + 1023) / 1024;
  int* bsum    = (int*)alloc((size_t)(nb_scan + 1) * 4);

  // CSR build
  hipMemsetAsync(deg, 0, (size_t)n * 4, stream);
  hipMemsetAsync(cur, 0, (size_t)n * 4, stream);
  hist_k<<<(e + 255) / 256, 256, 0, stream>>>(dst, deg, e);
  scan1_k<<<nb_scan, 1024, 0, stream>>>(deg, rowp, bsum, n);
  scan2_k<<<1, 64, 0, stream>>>(bsum, nb_scan);
  scan3_k<<<(n + 256) / 256, 256, 0, stream>>>(bsum, rowp, n, nb_scan);
  scatter_k<<<(e + 255) / 256, 256, 0, stream>>>(src, dst, rowp, cur, csrc, e);

  // prep
  cvt_k<<<(n * 128 + 255) / 256, 256, 0, stream>>>(x, xb, n * 128);
  cvtw_k<<<(163840 + 255) / 256, 256, 0, stream>>>(W1, W2, W3, W1b, W2b, W3b);
  wa_all_k<<<(2560 + 255) / 256, 256, 0, stream>>>(W1, al1, ar1, Wal1, War1,
                                                   W2, al2, ar2, Wal2, War2,
                                                   W3, al3, ar3, Wal3, War3);

  dim3 ggrid((n + 127) / 128, 2);
  int nb4 = (n + 3) / 4;

  // layer 1
  elproj_k<<<nb4, 256, 0, stream>>>(x, Wal1, War1, elA, erA, n);
  gemm_mfma<128><<<ggrid, 256, 0, stream>>>(xb, W1b, featb, n);
  agg64_k<0, 1><<<nb4, 256, 0, stream>>>(featb, elA, erA, rowp, csrc, nullptr, b1, h1b,
                                         Wal2, War2, elB, erB, n);
  // layer 2
  gemm_mfma<256><<<ggrid, 256, 0, stream>>>(h1b, W2b, featb, n);
  agg64_k<1, 1><<<nb4, 256, 0, stream>>>(featb, elB, erB, rowp, csrc, h1b, b2, h2b,
                                         Wal3, War3, elA, erA, n);
  // layer 3
  gemm_mfma<256><<<ggrid, 256, 0, stream>>>(h2b, W3b, featb, n);
  agg64_k<1, 0><<<nb4, 256, 0, stream>>>(featb, elA, erA, rowp, csrc, h2b, b3, h3b,
                                         nullptr, nullptr, nullptr, nullptr, n);
  // layer 4
  l4_proj_k<<<nb4, 256, 0, stream>>>(h3b, W4, rW4, al4, ar4, feat4, res4, el4, er4, n);
  agg4_k<<<nb4, 256, 0, stream>>>(feat4, el4, er4, rowp, csrc, res4, b4, out, n);
}

// Round 6
// 541.658 us; speedup vs baseline: 2.2518x; 1.2219x over previous
//
#include <hip/hip_runtime.h>
#include <hip/hip_bf16.h>
#include <math.h>

// GAT, 4 layers: N=50000, E=800000, IN=128, HID=64, H=4, C=2.
// R5b: kill the DS-pipe bottleneck. agg64 weight/src broadcasts via v_readlane
// (VALU) instead of ds_bpermute; softmax max-subtraction dropped (identity);
// wave reductions via DPP row_shr/row_bcast (VALU, ctrl as template constant);
// l4 projection as MFMA GEMM (bf16 Wcat) + tiny el4/er4 kernel.

#define LEAKY_SLOPE 0.2f

typedef __bf16 bf16x8_t __attribute__((ext_vector_type(8)));
typedef float f32x4_t __attribute__((ext_vector_type(4)));

__device__ __forceinline__ float leaky(float x) { return x > 0.f ? x : LEAKY_SLOPE * x; }
__device__ __forceinline__ float eluf(float x)  { return x > 0.f ? x : expm1f(x); }
__device__ __forceinline__ float bflo(unsigned u) { return __uint_as_float(u << 16); }
__device__ __forceinline__ float bfhi(unsigned u) { return __uint_as_float(u & 0xffff0000u); }

__device__ __forceinline__ int rli(int v, int l) { return __builtin_amdgcn_readlane(v, l); }
__device__ __forceinline__ float rlf(float v, int l) {
  return __uint_as_float((unsigned)__builtin_amdgcn_readlane((int)__float_as_uint(v), l));
}
// DPP wave64 sum: row_shr 1/2/4/8 then row_bcast15/31; total lands in lane 63.
template <int CTRL>
__device__ __forceinline__ float dpp_add(float x) {
  int t = __builtin_amdgcn_update_dpp(0, (int)__float_as_uint(x), CTRL, 0xf, 0xf, false);
  return x + __uint_as_float((unsigned)t);
}
__device__ __forceinline__ float wsum_dpp(float x) {
  x = dpp_add<0x111>(x);  // row_shr:1
  x = dpp_add<0x112>(x);  // row_shr:2
  x = dpp_add<0x114>(x);  // row_shr:4
  x = dpp_add<0x118>(x);  // row_shr:8
  x = dpp_add<0x142>(x);  // row_bcast:15
  x = dpp_add<0x143>(x);  // row_bcast:31
  return rlf(x, 63);
}
__device__ __forceinline__ float wmax(float v) {
#pragma unroll
  for (int o = 32; o; o >>= 1) v = fmaxf(v, __shfl_xor(v, o));
  return v;
}
__device__ __forceinline__ float wsum_sh(float v) {
#pragma unroll
  for (int o = 32; o; o >>= 1) v += __shfl_xor(v, o);
  return v;
}

// ---------------- CSR build ----------------
__global__ void hist_k(const int* __restrict__ dst, int* __restrict__ deg, int e) {
  int i = blockIdx.x * 256 + threadIdx.x;
  if (i < e) atomicAdd(&deg[dst[i]], 1);
}

__global__ __launch_bounds__(1024) void scan1_k(const int* __restrict__ deg,
                                                int* __restrict__ rowp,
                                                int* __restrict__ bsum, int n) {
  __shared__ int sd[1024];
  int tid = threadIdx.x;
  int i = blockIdx.x * 1024 + tid;
  int v = (i < n) ? deg[i] : 0;
  int x = v;
  sd[tid] = x;
  __syncthreads();
  for (int off = 1; off < 1024; off <<= 1) {
    int t = (tid >= off) ? sd[tid - off] : 0;
    __syncthreads();
    x += t;
    sd[tid] = x;
    __syncthreads();
  }
  if (i < n) rowp[i] = x - v;
  if (tid == 1023) bsum[blockIdx.x] = x;
}

__global__ __launch_bounds__(64) void scan2_k(int* __restrict__ bsum, int nb) {
  int lane = threadIdx.x;
  if (nb <= 64) {
    int v = (lane < nb) ? bsum[lane] : 0;
    int x = v;
#pragma unroll
    for (int off = 1; off < 64; off <<= 1) {
      int t = __shfl_up(x, off);
      if (lane >= off) x += t;
    }
    if (lane < nb) bsum[lane] = x - v;
    if (lane == 63) bsum[nb] = x;
  } else if (lane == 0) {
    int run = 0;
    for (int i = 0; i < nb; ++i) { int t = bsum[i]; bsum[i] = run; run += t; }
    bsum[nb] = run;
  }
}

__global__ void scan3_k(const int* __restrict__ bsum, int* __restrict__ rowp, int n, int nb) {
  int i = blockIdx.x * 256 + threadIdx.x;
  if (i < n) rowp[i] += bsum[i >> 10];
  if (i == n) rowp[n] = bsum[nb];
}

__global__ void scatter_k(const int* __restrict__ src, const int* __restrict__ dst,
                          const int* __restrict__ rowp, int* __restrict__ cur,
                          int* __restrict__ csrc, int e) {
  int i = blockIdx.x * 256 + threadIdx.x;
  if (i < e) {
    int d = dst[i];
    int p = atomicAdd(&cur[d], 1);
    csrc[rowp[d] + p] = src[i];
  }
}

// ---------------- prep ----------------
__global__ void cvt_k(const float* __restrict__ a, __hip_bfloat16* __restrict__ b, int cnt) {
  int i = blockIdx.x * 256 + threadIdx.x;
  if (i < cnt) b[i] = __float2bfloat16(a[i]);
}

// W1|W2|W3|W4|rW4 -> bf16 (W4,rW4 packed as Wcat[16][256])
__global__ void cvtw_k(const float* __restrict__ W1, const float* __restrict__ W2,
                       const float* __restrict__ W3, const float* __restrict__ W4,
                       const float* __restrict__ rW4, __hip_bfloat16* __restrict__ W1b,
                       __hip_bfloat16* __restrict__ W2b, __hip_bfloat16* __restrict__ W3b,
                       __hip_bfloat16* __restrict__ Wcatb) {
  int i = blockIdx.x * 256 + threadIdx.x;
  if (i < 32768) W1b[i] = __float2bfloat16(W1[i]);
  else if (i < 98304)  { int j = i - 32768;  W2b[j] = __float2bfloat16(W2[j]); }
  else if (i < 163840) { int j = i - 98304;  W3b[j] = __float2bfloat16(W3[j]); }
  else if (i < 165888) { int j = i - 163840; Wcatb[j] = __float2bfloat16(W4[j]); }
  else if (i < 167936) { int j = i - 165888; Wcatb[2048 + j] = __float2bfloat16(rW4[j]); }
}

// Wal[hh][col] = sum_o al[hh*64+o] * W[(hh*64+o)*K + col]; 3 layers fused.
__global__ void wa_all_k(const float* __restrict__ W1, const float* __restrict__ al1,
                         const float* __restrict__ ar1, float* __restrict__ Wal1,
                         float* __restrict__ War1, const float* __restrict__ W2,
                         const float* __restrict__ al2, const float* __restrict__ ar2,
                         float* __restrict__ Wal2, float* __restrict__ War2,
                         const float* __restrict__ W3, const float* __restrict__ al3,
                         const float* __restrict__ ar3, float* __restrict__ Wal3,
                         float* __restrict__ War3) {
  int i = blockIdx.x * 256 + threadIdx.x;
  const float *W, *al, *ar;
  float *Wal, *War;
  int K, idx;
  if (i < 512)       { W = W1; al = al1; ar = ar1; Wal = Wal1; War = War1; K = 128; idx = i; }
  else if (i < 1536) { W = W2; al = al2; ar = ar2; Wal = Wal2; War = War2; K = 256; idx = i - 512; }
  else if (i < 2560) { W = W3; al = al3; ar = ar3; Wal = Wal3; War = War3; K = 256; idx = i - 1536; }
  else return;
  int hh = idx / K, col = idx - hh * K;
  float sl = 0.f, sr = 0.f;
  const float* wp = W + (size_t)(hh * 64) * K + col;
#pragma unroll 4
  for (int o = 0; o < 64; ++o) {
    float wv = wp[(size_t)o * K];
    sl = fmaf(al[hh * 64 + o], wv, sl);
    sr = fmaf(ar[hh * 64 + o], wv, sr);
  }
  Wal[idx] = sl;
  War[idx] = sr;
}

// layer-1 el/er from fp32 x (exact logits)
__global__ __launch_bounds__(256) void elproj_k(const float* __restrict__ x,
                                                const float* __restrict__ Wal,
                                                const float* __restrict__ War,
                                                float* __restrict__ el,
                                                float* __restrict__ er, int n) {
  int node = blockIdx.x * 4 + (threadIdx.x >> 6);
  int lane = threadIdx.x & 63;
  if (node >= n) return;
  float2 xv = *(const float2*)(x + (size_t)node * 128 + lane * 2);
#pragma unroll
  for (int hh = 0; hh < 4; ++hh) {
    float sl = xv.x * Wal[hh * 128 + 2 * lane] + xv.y * Wal[hh * 128 + 2 * lane + 1];
    float sr = xv.x * War[hh * 128 + 2 * lane] + xv.y * War[hh * 128 + 2 * lane + 1];
    sl = wsum_dpp(sl);
    sr = wsum_dpp(sr);
    if (lane == 0) {
      el[node * 4 + hh] = sl;
      er[node * 4 + hh] = sr;
    }
  }
}

// ---------------- MFMA GEMM: featb[n][o=64][h=4](bf16) = A[n][K] @ B[256][K]^T ----------------
template <int K>
__global__ __launch_bounds__(256) void gemm_mfma(const __hip_bfloat16* __restrict__ A,
                                                 const __hip_bfloat16* __restrict__ B,
                                                 __hip_bfloat16* __restrict__ featb, int n) {
  __shared__ __bf16 As[128 * 40];
  __shared__ __bf16 Bs[128 * 40];
  const int tid = threadIdx.x;
  const int lane = tid & 63, w = tid >> 6;
  const int tm = lane & 15, tq = lane >> 4;
  const int wm = (w & 1) * 64, wn = (w >> 1) * 64;
  const int r0 = blockIdx.x * 128, c0 = blockIdx.y * 128;
  const int srow = tid >> 1, sko = (tid & 1) * 16;

  f32x4_t acc[4][4];
#pragma unroll
  for (int i = 0; i < 4; ++i)
#pragma unroll
    for (int j = 0; j < 4; ++j) acc[i][j] = 0.f;

  for (int kk = 0; kk < K; kk += 32) {
    uint4 av0 = {0, 0, 0, 0}, av1 = {0, 0, 0, 0};
    int arw = r0 + srow;
    if (arw < n) {
      const uint4* p = (const uint4*)(A + (size_t)arw * K + kk + sko);
      av0 = p[0];
      av1 = p[1];
    }
    const uint4* q = (const uint4*)(B + (size_t)(c0 + srow) * K + kk + sko);
    uint4 bv0 = q[0], bv1 = q[1];
    __syncthreads();
    *(uint4*)&As[srow * 40 + sko] = av0;
    *(uint4*)&As[srow * 40 + sko + 8] = av1;
    *(uint4*)&Bs[srow * 40 + sko] = bv0;
    *(uint4*)&Bs[srow * 40 + sko + 8] = bv1;
    __syncthreads();
    bf16x8_t af[4], bfr[4];
#pragma unroll
    for (int i = 0; i < 4; ++i) af[i] = *(const bf16x8_t*)&As[(wm + i * 16 + tm) * 40 + tq * 8];
#pragma unroll
    for (int j = 0; j < 4; ++j) bfr[j] = *(const bf16x8_t*)&Bs[(wn + j * 16 + tm) * 40 + tq * 8];
#pragma unroll
    for (int i = 0; i < 4; ++i)
#pragma unroll
      for (int j = 0; j < 4; ++j)
        acc[i][j] = __builtin_amdgcn_mfma_f32_16x16x32_bf16(af[i], bfr[j], acc[i][j], 0, 0, 0);
  }

#pragma unroll
  for (int i = 0; i < 4; ++i) {
#pragma unroll
    for (int j = 0; j < 4; ++j) {
      int col = c0 + wn + j * 16 + tm;
      int hh = col >> 6, oo = col & 63;
#pragma unroll
      for (int rr = 0; rr < 4; ++rr) {
        int row = r0 + wm + i * 16 + tq * 4 + rr;
        if (row < n) featb[(size_t)row * 256 + oo * 4 + hh] = __float2bfloat16(acc[i][j][rr]);
      }
    }
  }
}

// ---------------- aggregate layers 1-3: one wave per dst node ----------------
template <int RES, int NEXT>
__global__ __launch_bounds__(256) void agg64_k(const __hip_bfloat16* __restrict__ featb,
                                               const float* __restrict__ el,
                                               const float* __restrict__ er,
                                               const int* __restrict__ rowp,
                                               const int* __restrict__ csrc,
                                               const __hip_bfloat16* __restrict__ hinb,
                                               const float* __restrict__ bias,
                                               __hip_bfloat16* __restrict__ houtb,
                                               const float* __restrict__ Waln,
                                               const float* __restrict__ Warn,
                                               float* __restrict__ eln,
                                               float* __restrict__ ern, int n) {
  int node = blockIdx.x * 4 + (threadIdx.x >> 6);
  int lane = threadIdx.x & 63;
  if (node >= n) return;
  int s0 = rowp[node], s1 = rowp[node + 1];
  int deg = s1 - s0;
  float4 erv = *(const float4*)(er + (size_t)node * 4);
  float a0 = 0, a1 = 0, a2 = 0, a3 = 0;
  float i0 = 1.f, i1 = 1.f, i2 = 1.f, i3 = 1.f;

  if (deg <= 64) {
    // lane owns edge `lane`: unnormalized exp weights (no max subtraction —
    // identity for softmax; logits are O(few sigma), overflow needs e>88)
    int sown = 0;
    float x0 = 0.f, x1 = 0.f, x2 = 0.f, x3 = 0.f;
    if (lane < deg) {
      sown = csrc[s0 + lane];
      float4 e = *(const float4*)(el + (size_t)sown * 4);
      x0 = __expf(leaky(e.x + erv.x));
      x1 = __expf(leaky(e.y + erv.y));
      x2 = __expf(leaky(e.z + erv.z));
      x3 = __expf(leaky(e.w + erv.w));
    }
    float d0 = wsum_dpp(x0), d1 = wsum_dpp(x1), d2 = wsum_dpp(x2), d3 = wsum_dpp(x3);
    i0 = d0 > 0.f ? 1.f / d0 : 0.f;
    i1 = d1 > 0.f ? 1.f / d1 : 0.f;
    i2 = d2 > 0.f ? 1.f / d2 : 0.f;
    i3 = d3 > 0.f ? 1.f / d3 : 0.f;

    // gather: broadcasts via v_readlane (VALU pipe, zero DS ops); src row
    // index lands in SGPR -> scalar-base global loads.
    int k = 0;
    for (; k + 4 <= deg; k += 4) {
      int sk0 = rli(sown, k + 0), sk1 = rli(sown, k + 1);
      int sk2 = rli(sown, k + 2), sk3 = rli(sown, k + 3);
      uint2 u0 = ((const uint2*)(featb + ((size_t)sk0 << 8)))[lane];
      uint2 u1 = ((const uint2*)(featb + ((size_t)sk1 << 8)))[lane];
      uint2 u2 = ((const uint2*)(featb + ((size_t)sk2 << 8)))[lane];
      uint2 u3 = ((const uint2*)(featb + ((size_t)sk3 << 8)))[lane];
      float w00 = rlf(x0, k + 0), w10 = rlf(x1, k + 0), w20 = rlf(x2, k + 0), w30 = rlf(x3, k + 0);
      float w01 = rlf(x0, k + 1), w11 = rlf(x1, k + 1), w21 = rlf(x2, k + 1), w31 = rlf(x3, k + 1);
      float w02 = rlf(x0, k + 2), w12 = rlf(x1, k + 2), w22 = rlf(x2, k + 2), w32 = rlf(x3, k + 2);
      float w03 = rlf(x0, k + 3), w13 = rlf(x1, k + 3), w23 = rlf(x2, k + 3), w33 = rlf(x3, k + 3);
      a0 = fmaf(w00, bflo(u0.x), a0); a1 = fmaf(w10, bfhi(u0.x), a1);
      a2 = fmaf(w20, bflo(u0.y), a2); a3 = fmaf(w30, bfhi(u0.y), a3);
      a0 = fmaf(w01, bflo(u1.x), a0); a1 = fmaf(w11, bfhi(u1.x), a1);
      a2 = fmaf(w21, bflo(u1.y), a2); a3 = fmaf(w31, bfhi(u1.y), a3);
      a0 = fmaf(w02, bflo(u2.x), a0); a1 = fmaf(w12, bfhi(u2.x), a1);
      a2 = fmaf(w22, bflo(u2.y), a2); a3 = fmaf(w32, bfhi(u2.y), a3);
      a0 = fmaf(w03, bflo(u3.x), a0); a1 = fmaf(w13, bfhi(u3.x), a1);
      a2 = fmaf(w23, bflo(u3.y), a2); a3 = fmaf(w33, bfhi(u3.y), a3);
    }
    for (; k < deg; ++k) {
      int sk = rli(sown, k);
      float w0k = rlf(x0, k), w1k = rlf(x1, k), w2k = rlf(x2, k), w3k = rlf(x3, k);
      uint2 u = ((const uint2*)(featb + ((size_t)sk << 8)))[lane];
      a0 = fmaf(w0k, bflo(u.x), a0);
      a1 = fmaf(w1k, bfhi(u.x), a1);
      a2 = fmaf(w2k, bflo(u.y), a2);
      a3 = fmaf(w3k, bfhi(u.y), a3);
    }
  } else {
    // fallback (rare): 3-pass with max, normalized per-edge; scale stays 1.
    float m0 = -INFINITY, m1 = -INFINITY, m2 = -INFINITY, m3 = -INFINITY;
    for (int k = s0 + lane; k < s1; k += 64) {
      int s = csrc[k];
      float4 e = *(const float4*)(el + (size_t)s * 4);
      m0 = fmaxf(m0, leaky(e.x + erv.x));
      m1 = fmaxf(m1, leaky(e.y + erv.y));
      m2 = fmaxf(m2, leaky(e.z + erv.z));
      m3 = fmaxf(m3, leaky(e.w + erv.w));
    }
    m0 = wmax(m0); m1 = wmax(m1); m2 = wmax(m2); m3 = wmax(m3);
    float d0 = 0, d1 = 0, d2 = 0, d3 = 0;
    for (int k = s0 + lane; k < s1; k += 64) {
      int s = csrc[k];
      float4 e = *(const float4*)(el + (size_t)s * 4);
      d0 += __expf(leaky(e.x + erv.x) - m0);
      d1 += __expf(leaky(e.y + erv.y) - m1);
      d2 += __expf(leaky(e.z + erv.z) - m2);
      d3 += __expf(leaky(e.w + erv.w) - m3);
    }
    d0 = wsum_sh(d0); d1 = wsum_sh(d1); d2 = wsum_sh(d2); d3 = wsum_sh(d3);
    float j0 = d0 > 0.f ? 1.f / d0 : 0.f;
    float j1 = d1 > 0.f ? 1.f / d1 : 0.f;
    float j2 = d2 > 0.f ? 1.f / d2 : 0.f;
    float j3 = d3 > 0.f ? 1.f / d3 : 0.f;
    for (int k = s0; k < s1; ++k) {
      int s = csrc[k];
      float4 e = *(const float4*)(el + (size_t)s * 4);
      float w0 = __expf(leaky(e.x + erv.x) - m0) * j0;
      float w1 = __expf(leaky(e.y + erv.y) - m1) * j1;
      float w2 = __expf(leaky(e.z + erv.z) - m2) * j2;
      float w3 = __expf(leaky(e.w + erv.w) - m3) * j3;
      uint2 u = ((const uint2*)(featb + ((size_t)s << 8)))[lane];
      a0 = fmaf(w0, bflo(u.x), a0);
      a1 = fmaf(w1, bfhi(u.x), a1);
      a2 = fmaf(w2, bflo(u.y), a2);
      a3 = fmaf(w3, bfhi(u.y), a3);
    }
  }

  size_t base = (size_t)node * 256;
  float v0 = a0 * i0 + bias[lane];
  float v1 = a1 * i1 + bias[64 + lane];
  float v2 = a2 * i2 + bias[128 + lane];
  float v3 = a3 * i3 + bias[192 + lane];
  if (RES) {
    v0 += __bfloat162float(hinb[base + lane]);
    v1 += __bfloat162float(hinb[base + 64 + lane]);
    v2 += __bfloat162float(hinb[base + 128 + lane]);
    v3 += __bfloat162float(hinb[base + 192 + lane]);
  }
  float o0 = eluf(v0), o1 = eluf(v1), o2 = eluf(v2), o3 = eluf(v3);
  houtb[base + lane]       = __float2bfloat16(o0);
  houtb[base + 64 + lane]  = __float2bfloat16(o1);
  houtb[base + 128 + lane] = __float2bfloat16(o2);
  houtb[base + 192 + lane] = __float2bfloat16(o3);
  if (NEXT) {
#pragma unroll
    for (int hh = 0; hh < 4; ++hh) {
      float sl = o0 * Waln[hh * 256 + lane] + o1 * Waln[hh * 256 + 64 + lane] +
                 o2 * Waln[hh * 256 + 128 + lane] + o3 * Waln[hh * 256 + 192 + lane];
      float sr = o0 * Warn[hh * 256 + lane] + o1 * Warn[hh * 256 + 64 + lane] +
                 o2 * Warn[hh * 256 + 128 + lane] + o3 * Warn[hh * 256 + 192 + lane];
      sl = wsum_dpp(sl);
      sr = wsum_dpp(sr);
      if (lane == 0) {
        eln[node * 4 + hh] = sl;
        ern[node * 4 + hh] = sr;
      }
    }
  }
}

// ---------------- layer 4 projection: MFMA [n x 256] @ Wcat^T -> [n x 16] ----------------
__global__ __launch_bounds__(256) void l4mfma_k(const __hip_bfloat16* __restrict__ hb,
                                                const __hip_bfloat16* __restrict__ Wcat,
                                                float* __restrict__ feat4,
                                                float* __restrict__ res4, int n) {
  int wid = blockIdx.x * 4 + (threadIdx.x >> 6);
  int n16 = (n + 15) >> 4;
  if (wid >= n16) return;
  int lane = threadIdx.x & 63;
  int tm = lane & 15, tq = lane >> 4;
  int row = wid * 16 + tm;
  int rowc = row < n ? row : n - 1;
  const __hip_bfloat16* ap = hb + (size_t)rowc * 256 + tq * 8;
  const __hip_bfloat16* bp = Wcat + (size_t)tm * 256 + tq * 8;
  f32x4_t acc = {0.f, 0.f, 0.f, 0.f};
#pragma unroll
  for (int k = 0; k < 8; ++k) {
    bf16x8_t af = *(const bf16x8_t*)(ap + k * 32);
    bf16x8_t bf = *(const bf16x8_t*)(bp + k * 32);
    acc = __builtin_amdgcn_mfma_f32_16x16x32_bf16(af, bf, acc, 0, 0, 0);
  }
  // C/D: col = lane&15 (output idx 0..15), row = (lane>>4)*4 + r (node in group)
  float* dstp = (tm < 8) ? feat4 : res4;
  int cc = tm & 7;
#pragma unroll
  for (int r = 0; r < 4; ++r) {
    int node = wid * 16 + tq * 4 + r;
    if (node < n) dstp[(size_t)node * 8 + cc] = acc[r];
  }
}

__global__ void el4er4_k(const float* __restrict__ feat4, const float* __restrict__ al4,
                         const float* __restrict__ ar4, float* __restrict__ el4,
                         float* __restrict__ er4, int n) {
  int i = blockIdx.x * 256 + threadIdx.x;
  if (i >= n) return;
  float4 f0 = ((const float4*)(feat4 + (size_t)i * 8))[0];
  float4 f1 = ((const float4*)(feat4 + (size_t)i * 8))[1];
  float4 lv, rv;
  lv.x = f0.x * al4[0] + f0.y * al4[1];
  lv.y = f0.z * al4[2] + f0.w * al4[3];
  lv.z = f1.x * al4[4] + f1.y * al4[5];
  lv.w = f1.z * al4[6] + f1.w * al4[7];
  rv.x = f0.x * ar4[0] + f0.y * ar4[1];
  rv.y = f0.z * ar4[2] + f0.w * ar4[3];
  rv.z = f1.x * ar4[4] + f1.y * ar4[5];
  rv.w = f1.z * ar4[6] + f1.w * ar4[7];
  *(float4*)(el4 + (size_t)i * 4) = lv;
  *(float4*)(er4 + (size_t)i * 4) = rv;
}

// ---------------- layer 4 aggregate + per-head softmax + head mean ----------------
__global__ __launch_bounds__(256) void agg4_k(const float* __restrict__ feat4,
                                              const float* __restrict__ el4,
                                              const float* __restrict__ er4,
                                              const int* __restrict__ rowp,
                                              const int* __restrict__ csrc,
                                              const float* __restrict__ res4,
                                              const float* __restrict__ b4,
                                              float* __restrict__ out, int n) {
  int node = blockIdx.x * 4 + (threadIdx.x >> 6);
  int lane = threadIdx.x & 63;
  if (node >= n) return;
  int s0 = rowp[node], s1 = rowp[node + 1];
  int deg = s1 - s0;
  float4 erv = *(const float4*)(er4 + (size_t)node * 4);
  float acc = 0.f;
  float scale = 1.f;
  int p = lane & 7, hh = p >> 1;

  if (deg <= 64) {
    int sown = 0;
    float x0 = 0.f, x1 = 0.f, x2 = 0.f, x3 = 0.f;
    if (lane < deg) {
      sown = csrc[s0 + lane];
      float4 e = *(const float4*)(el4 + (size_t)sown * 4);
      x0 = __expf(leaky(e.x + erv.x));
      x1 = __expf(leaky(e.y + erv.y));
      x2 = __expf(leaky(e.z + erv.z));
      x3 = __expf(leaky(e.w + erv.w));
    }
    float d0 = wsum_dpp(x0), d1 = wsum_dpp(x1), d2 = wsum_dpp(x2), d3 = wsum_dpp(x3);
    float i0 = d0 > 0.f ? 1.f / d0 : 0.f;
    float i1 = d1 > 0.f ? 1.f / d1 : 0.f;
    float i2 = d2 > 0.f ? 1.f / d2 : 0.f;
    float i3 = d3 > 0.f ? 1.f / d3 : 0.f;
    scale = (hh == 0) ? i0 : (hh == 1) ? i1 : (hh == 2) ? i2 : i3;
    int g = lane >> 3;
    int nt = (deg + 7) >> 3;
    for (int t = 0; t < nt; ++t) {
      int k = g + t * 8;
      bool ok = k < deg;
      int kk = k & 63;
      int sk = __shfl(sown, kk);
      float x0k = __shfl(x0, kk), x1k = __shfl(x1, kk);
      float x2k = __shfl(x2, kk), x3k = __shfl(x3, kk);
      float wk = (hh == 0) ? x0k : (hh == 1) ? x1k : (hh == 2) ? x2k : x3k;
      if (ok) acc = fmaf(wk, feat4[(size_t)sk * 8 + p], acc);
    }
    acc += __shfl_xor(acc, 8);
    acc += __shfl_xor(acc, 16);
    acc += __shfl_xor(acc, 32);
  } else {
    float m0 = -INFINITY, m1 = -INFINITY, m2 = -INFINITY, m3 = -INFINITY;
    for (int k = s0 + lane; k < s1; k += 64) {
      int s = csrc[k];
      float4 e = *(const float4*)(el4 + (size_t)s * 4);
      m0 = fmaxf(m0, leaky(e.x + erv.x));
      m1 = fmaxf(m1, leaky(e.y + erv.y));
      m2 = fmaxf(m2, leaky(e.z + erv.z));
      m3 = fmaxf(m3, leaky(e.w + erv.w));
    }
    m0 = wmax(m0); m1 = wmax(m1); m2 = wmax(m2); m3 = wmax(m3);
    float d0 = 0, d1 = 0, d2 = 0, d3 = 0;
    for (int k = s0 + lane; k < s1; k += 64) {
      int s = csrc[k];
      float4 e = *(const float4*)(el4 + (size_t)s * 4);
      d0 += __expf(leaky(e.x + erv.x) - m0);
      d1 += __expf(leaky(e.y + erv.y) - m1);
      d2 += __expf(leaky(e.z + erv.z) - m2);
      d3 += __expf(leaky(e.w + erv.w) - m3);
    }
    d0 = wsum_sh(d0); d1 = wsum_sh(d1); d2 = wsum_sh(d2); d3 = wsum_sh(d3);
    float i0 = d0 > 0.f ? 1.f / d0 : 0.f;
    float i1 = d1 > 0.f ? 1.f / d1 : 0.f;
    float i2 = d2 > 0.f ? 1.f / d2 : 0.f;
    float i3 = d3 > 0.f ? 1.f / d3 : 0.f;
    for (int k = s0; k < s1; ++k) {
      int s = csrc[k];
      float4 e = *(const float4*)(el4 + (size_t)s * 4);
      float w0 = __expf(leaky(e.x + erv.x) - m0) * i0;
      float w1 = __expf(leaky(e.y + erv.y) - m1) * i1;
      float w2 = __expf(leaky(e.z + erv.z) - m2) * i2;
      float w3 = __expf(leaky(e.w + erv.w) - m3) * i3;
      float wk = (hh == 0) ? w0 : (hh == 1) ? w1 : (hh == 2) ? w2 : w3;
      if (lane < 8) acc = fmaf(wk, feat4[(size_t)s * 8 + p], acc);
    }
  }

  float v = 0.f;
  if (lane < 8) v = acc * scale + res4[(size_t)node * 8 + lane] + b4[lane];
  float pv = __shfl_xor(v, 1);
  float mx = fmaxf(v, pv);
  float ex = __expf(v - mx);
  float sm = ex + __shfl_xor(ex, 1);
  float pr = ex / sm;
  float t = pr + __shfl_xor(pr, 2);
  t += __shfl_xor(t, 4);
  if (lane < 2) out[(size_t)node * 2 + lane] = t * 0.25f;
}

extern "C" void kernel_launch(void* const* d_in, const int* in_sizes, int n_in,
                              void* d_out, int out_size, void* d_ws, size_t ws_size,
                              hipStream_t stream) {
  const float* x   = (const float*)d_in[0];
  const int* src   = (const int*)d_in[1];
  const int* dst   = (const int*)d_in[2];
  const float* W1  = (const float*)d_in[3];
  const float* al1 = (const float*)d_in[4];
  const float* ar1 = (const float*)d_in[5];
  const float* b1  = (const float*)d_in[6];
  const float* W2  = (const float*)d_in[7];
  const float* al2 = (const float*)d_in[8];
  const float* ar2 = (const float*)d_in[9];
  const float* b2  = (const float*)d_in[10];
  const float* W3  = (const float*)d_in[11];
  const float* al3 = (const float*)d_in[12];
  const float* ar3 = (const float*)d_in[13];
  const float* b3  = (const float*)d_in[14];
  const float* W4  = (const float*)d_in[15];
  const float* al4 = (const float*)d_in[16];
  const float* ar4 = (const float*)d_in[17];
  const float* b4  = (const float*)d_in[18];
  const float* rW4 = (const float*)d_in[19];
  float* out = (float*)d_out;

  const int n = in_sizes[0] / 128;  // 50000
  const int e = in_sizes[1];        // 800000

  char* ws = (char*)d_ws;
  auto alloc = [&](size_t bytes) -> char* {
    char* p = ws;
    ws += (bytes + 255) & ~(size_t)255;
    return p;
  };
  __hip_bfloat16* featb = (__hip_bfloat16*)alloc((size_t)n * 256 * 2);
  __hip_bfloat16* h1b   = (__hip_bfloat16*)alloc((size_t)n * 256 * 2);
  __hip_bfloat16* h2b   = (__hip_bfloat16*)alloc((size_t)n * 256 * 2);
  __hip_bfloat16* h3b   = (__hip_bfloat16*)alloc((size_t)n * 256 * 2);
  __hip_bfloat16* xb    = (__hip_bfloat16*)alloc((size_t)n * 128 * 2);
  __hip_bfloat16* W1b   = (__hip_bfloat16*)alloc((size_t)256 * 128 * 2);
  __hip_bfloat16* W2b   = (__hip_bfloat16*)alloc((size_t)256 * 256 * 2);
  __hip_bfloat16* W3b   = (__hip_bfloat16*)alloc((size_t)256 * 256 * 2);
  __hip_bfloat16* Wcatb = (__hip_bfloat16*)alloc((size_t)16 * 256 * 2);
  float* Wal1 = (float*)alloc((size_t)4 * 128 * 4);
  float* War1 = (float*)alloc((size_t)4 * 128 * 4);
  float* Wal2 = (float*)alloc((size_t)4 * 256 * 4);
  float* War2 = (float*)alloc((size_t)4 * 256 * 4);
  float* Wal3 = (float*)alloc((size_t)4 * 256 * 4);
  float* War3 = (float*)alloc((size_t)4 * 256 * 4);
  float* elA   = (float*)alloc((size_t)n * 4 * 4);
  float* erA   = (float*)alloc((size_t)n * 4 * 4);
  float* elB   = (float*)alloc((size_t)n * 4 * 4);
  float* erB   = (float*)alloc((size_t)n * 4 * 4);
  float* feat4 = (float*)alloc((size_t)n * 8 * 4);
  float* res4  = (float*)alloc((size_t)n * 8 * 4);
  float* el4   = (float*)alloc((size_t)n * 4 * 4);
  float* er4   = (float*)alloc((size_t)n * 4 * 4);
  int* deg     = (int*)alloc((size_t)n * 4);
  int* cur     = (int*)alloc((size_t)n * 4);
  int* rowp    = (int*)alloc((size_t)(n + 1) * 4);
  int* csrc    = (int*)alloc((size_t)e * 4);
  int nb_scan  = (n + 1023) / 1024;
  int* bsum    = (int*)alloc((size_t)(nb_scan + 1) * 4);

  // CSR build
  (void)hipMemsetAsync(deg, 0, (size_t)n * 4, stream);
  (void)hipMemsetAsync(cur, 0, (size_t)n * 4, stream);
  hist_k<<<(e + 255) / 256, 256, 0, stream>>>(dst, deg, e);
  scan1_k<<<nb_scan, 1024, 0, stream>>>(deg, rowp, bsum, n);
  scan2_k<<<1, 64, 0, stream>>>(bsum, nb_scan);
  scan3_k<<<(n + 256) / 256, 256, 0, stream>>>(bsum, rowp, n, nb_scan);
  scatter_k<<<(e + 255) / 256, 256, 0, stream>>>(src, dst, rowp, cur, csrc, e);

  // prep
  cvt_k<<<(n * 128 + 255) / 256, 256, 0, stream>>>(x, xb, n * 128);
  cvtw_k<<<(167936 + 255) / 256, 256, 0, stream>>>(W1, W2, W3, W4, rW4, W1b, W2b, W3b, Wcatb);
  wa_all_k<<<(2560 + 255) / 256, 256, 0, stream>>>(W1, al1, ar1, Wal1, War1,
                                                   W2, al2, ar2, Wal2, War2,
                                                   W3, al3, ar3, Wal3, War3);

  dim3 ggrid((n + 127) / 128, 2);
  int nb4 = (n + 3) / 4;

  // layer 1
  elproj_k<<<nb4, 256, 0, stream>>>(x, Wal1, War1, elA, erA, n);
  gemm_mfma<128><<<ggrid, 256, 0, stream>>>(xb, W1b, featb, n);
  agg64_k<0, 1><<<nb4, 256, 0, stream>>>(featb, elA, erA, rowp, csrc, nullptr, b1, h1b,
                                         Wal2, War2, elB, erB, n);
  // layer 2
  gemm_mfma<256><<<ggrid, 256, 0, stream>>>(h1b, W2b, featb, n);
  agg64_k<1, 1><<<nb4, 256, 0, stream>>>(featb, elB, erB, rowp, csrc, h1b, b2, h2b,
                                         Wal3, War3, elA, erA, n);
  // layer 3
  gemm_mfma<256><<<ggrid, 256, 0, stream>>>(h2b, W3b, featb, n);
  agg64_k<1, 0><<<nb4, 256, 0, stream>>>(featb, elA, erA, rowp, csrc, h2b, b3, h3b,
                                         nullptr, nullptr, nullptr, nullptr, n);
  // layer 4
  int n16 = (n + 15) / 16;
  l4mfma_k<<<(n16 + 3) / 4, 256, 0, stream>>>(h3b, Wcatb, feat4, res4, n);
  el4er4_k<<<(n + 255) / 256, 256, 0, stream>>>(feat4, al4, ar4, el4, er4, n);
  agg4_k<<<nb4, 256, 0, stream>>>(feat4, el4, er4, rowp, csrc, res4, b4, out, n);
}

// Round 7
// 515.747 us; speedup vs baseline: 2.3649x; 1.0502x over previous
//
#include <hip/hip_runtime.h>
#include <hip/hip_bf16.h>
#include <math.h>

// GAT, 4 layers: N=50000, E=800000, IN=128, HID=64, H=4, C=2.
// R6: el/er computed in GEMM epilogue from fp32 MFMA accumulators (deletes
// elproj/wa_all/el4er4 and agg64's NEXT epilogue); agg64/agg4 edge-weight
// broadcasts via LDS wave-uniform reads (DS pipe) instead of v_readlane/
// ds_bpermute storms; prep kernels fused.

#define LEAKY_SLOPE 0.2f

typedef __bf16 bf16x8_t __attribute__((ext_vector_type(8)));
typedef float f32x4_t __attribute__((ext_vector_type(4)));

__device__ __forceinline__ float leaky(float x) { return x > 0.f ? x : LEAKY_SLOPE * x; }
__device__ __forceinline__ float eluf(float x)  { return x > 0.f ? x : expm1f(x); }
__device__ __forceinline__ float bflo(unsigned u) { return __uint_as_float(u << 16); }
__device__ __forceinline__ float bfhi(unsigned u) { return __uint_as_float(u & 0xffff0000u); }

__device__ __forceinline__ int rli(int v, int l) { return __builtin_amdgcn_readlane(v, l); }
__device__ __forceinline__ float rlf(float v, int l) {
  return __uint_as_float((unsigned)__builtin_amdgcn_readlane((int)__float_as_uint(v), l));
}
template <int CTRL>
__device__ __forceinline__ float dpp_add(float x) {
  int t = __builtin_amdgcn_update_dpp(0, (int)__float_as_uint(x), CTRL, 0xf, 0xf, false);
  return x + __uint_as_float((unsigned)t);
}
__device__ __forceinline__ float wsum_dpp(float x) {
  x = dpp_add<0x111>(x);
  x = dpp_add<0x112>(x);
  x = dpp_add<0x114>(x);
  x = dpp_add<0x118>(x);
  x = dpp_add<0x142>(x);
  x = dpp_add<0x143>(x);
  return rlf(x, 63);
}
__device__ __forceinline__ float wmax(float v) {
#pragma unroll
  for (int o = 32; o; o >>= 1) v = fmaxf(v, __shfl_xor(v, o));
  return v;
}
__device__ __forceinline__ float wsum_sh(float v) {
#pragma unroll
  for (int o = 32; o; o >>= 1) v += __shfl_xor(v, o);
  return v;
}

// ---------------- CSR build ----------------
__global__ void hist_k(const int* __restrict__ dst, int* __restrict__ deg, int e) {
  int i = blockIdx.x * 256 + threadIdx.x;
  if (i < e) atomicAdd(&deg[dst[i]], 1);
}

__global__ __launch_bounds__(1024) void scan1_k(const int* __restrict__ deg,
                                                int* __restrict__ rowp,
                                                int* __restrict__ bsum, int n) {
  __shared__ int sd[1024];
  int tid = threadIdx.x;
  int i = blockIdx.x * 1024 + tid;
  int v = (i < n) ? deg[i] : 0;
  int x = v;
  sd[tid] = x;
  __syncthreads();
  for (int off = 1; off < 1024; off <<= 1) {
    int t = (tid >= off) ? sd[tid - off] : 0;
    __syncthreads();
    x += t;
    sd[tid] = x;
    __syncthreads();
  }
  if (i < n) rowp[i] = x - v;
  if (tid == 1023) bsum[blockIdx.x] = x;
}

__global__ __launch_bounds__(64) void scan2_k(int* __restrict__ bsum, int nb) {
  int lane = threadIdx.x;
  if (nb <= 64) {
    int v = (lane < nb) ? bsum[lane] : 0;
    int x = v;
#pragma unroll
    for (int off = 1; off < 64; off <<= 1) {
      int t = __shfl_up(x, off);
      if (lane >= off) x += t;
    }
    if (lane < nb) bsum[lane] = x - v;
    if (lane == 63) bsum[nb] = x;
  } else if (lane == 0) {
    int run = 0;
    for (int i = 0; i < nb; ++i) { int t = bsum[i]; bsum[i] = run; run += t; }
    bsum[nb] = run;
  }
}

__global__ void scan3_k(const int* __restrict__ bsum, int* __restrict__ rowp, int n, int nb) {
  int i = blockIdx.x * 256 + threadIdx.x;
  if (i < n) rowp[i] += bsum[i >> 10];
  if (i == n) rowp[n] = bsum[nb];
}

__global__ void scatter_k(const int* __restrict__ src, const int* __restrict__ dst,
                          const int* __restrict__ rowp, int* __restrict__ cur,
                          int* __restrict__ csrc, int e) {
  int i = blockIdx.x * 256 + threadIdx.x;
  if (i < e) {
    int d = dst[i];
    int p = atomicAdd(&cur[d], 1);
    csrc[rowp[d] + p] = src[i];
  }
}

// ---------------- prep: x + all weights -> bf16, one launch ----------------
__global__ void cvtall_k(const float* __restrict__ x, const float* __restrict__ W1,
                         const float* __restrict__ W2, const float* __restrict__ W3,
                         const float* __restrict__ W4, const float* __restrict__ rW4,
                         __hip_bfloat16* __restrict__ xb, __hip_bfloat16* __restrict__ W1b,
                         __hip_bfloat16* __restrict__ W2b, __hip_bfloat16* __restrict__ W3b,
                         __hip_bfloat16* __restrict__ Wcatb, int nx) {
  int i = blockIdx.x * 256 + threadIdx.x;
  if (i < nx) { xb[i] = __float2bfloat16(x[i]); return; }
  int j = i - nx;
  if (j < 32768) W1b[j] = __float2bfloat16(W1[j]);
  else if (j < 98304)  { int k = j - 32768;  W2b[k] = __float2bfloat16(W2[k]); }
  else if (j < 163840) { int k = j - 98304;  W3b[k] = __float2bfloat16(W3[k]); }
  else if (j < 165888) { int k = j - 163840; Wcatb[k] = __float2bfloat16(W4[k]); }
  else if (j < 167936) { int k = j - 165888; Wcatb[2048 + k] = __float2bfloat16(rW4[k]); }
}

// ---------------- MFMA GEMM + el/er epilogue ----------------
// featb[n][o=64][h=4](bf16) = A[n][K] @ B[256][K]^T ; el/er[n][4] = feat.al/.ar
template <int K>
__global__ __launch_bounds__(256) void gemm_mfma(const __hip_bfloat16* __restrict__ A,
                                                 const __hip_bfloat16* __restrict__ B,
                                                 __hip_bfloat16* __restrict__ featb,
                                                 const float* __restrict__ al,
                                                 const float* __restrict__ ar,
                                                 float* __restrict__ el,
                                                 float* __restrict__ er, int n) {
  __shared__ __bf16 As[128 * 40];
  __shared__ __bf16 Bs[128 * 40];
  const int tid = threadIdx.x;
  const int lane = tid & 63, w = tid >> 6;
  const int tm = lane & 15, tq = lane >> 4;
  const int wm = (w & 1) * 64, wn = (w >> 1) * 64;
  const int r0 = blockIdx.x * 128, c0 = blockIdx.y * 128;
  const int srow = tid >> 1, sko = (tid & 1) * 16;

  f32x4_t acc[4][4];
#pragma unroll
  for (int i = 0; i < 4; ++i)
#pragma unroll
    for (int j = 0; j < 4; ++j) acc[i][j] = 0.f;

  for (int kk = 0; kk < K; kk += 32) {
    uint4 av0 = {0, 0, 0, 0}, av1 = {0, 0, 0, 0};
    int arw = r0 + srow;
    if (arw < n) {
      const uint4* p = (const uint4*)(A + (size_t)arw * K + kk + sko);
      av0 = p[0];
      av1 = p[1];
    }
    const uint4* q = (const uint4*)(B + (size_t)(c0 + srow) * K + kk + sko);
    uint4 bv0 = q[0], bv1 = q[1];
    __syncthreads();
    *(uint4*)&As[srow * 40 + sko] = av0;
    *(uint4*)&As[srow * 40 + sko + 8] = av1;
    *(uint4*)&Bs[srow * 40 + sko] = bv0;
    *(uint4*)&Bs[srow * 40 + sko + 8] = bv1;
    __syncthreads();
    bf16x8_t af[4], bfr[4];
#pragma unroll
    for (int i = 0; i < 4; ++i) af[i] = *(const bf16x8_t*)&As[(wm + i * 16 + tm) * 40 + tq * 8];
#pragma unroll
    for (int j = 0; j < 4; ++j) bfr[j] = *(const bf16x8_t*)&Bs[(wn + j * 16 + tm) * 40 + tq * 8];
#pragma unroll
    for (int i = 0; i < 4; ++i)
#pragma unroll
      for (int j = 0; j < 4; ++j)
        acc[i][j] = __builtin_amdgcn_mfma_f32_16x16x32_bf16(af[i], bfr[j], acc[i][j], 0, 0, 0);
  }

  // featb store
#pragma unroll
  for (int i = 0; i < 4; ++i) {
#pragma unroll
    for (int j = 0; j < 4; ++j) {
      int col = c0 + wn + j * 16 + tm;
      int hh = col >> 6, oo = col & 63;
#pragma unroll
      for (int rr = 0; rr < 4; ++rr) {
        int row = r0 + wm + i * 16 + tq * 4 + rr;
        if (row < n) featb[(size_t)row * 256 + oo * 4 + hh] = __float2bfloat16(acc[i][j][rr]);
      }
    }
  }

  // el/er epilogue: this wave owns head hd = (c0+wn)>>6 entirely (64 cols)
  {
    const int hd = (c0 + wn) >> 6;
    float alv[4], arv[4];
#pragma unroll
    for (int j = 0; j < 4; ++j) {
      alv[j] = al[hd * 64 + j * 16 + tm];
      arv[j] = ar[hd * 64 + j * 16 + tm];
    }
#pragma unroll
    for (int i = 0; i < 4; ++i) {
#pragma unroll
      for (int rr = 0; rr < 4; ++rr) {
        float se = acc[i][0][rr] * alv[0] + acc[i][1][rr] * alv[1] +
                   acc[i][2][rr] * alv[2] + acc[i][3][rr] * alv[3];
        float sr2 = acc[i][0][rr] * arv[0] + acc[i][1][rr] * arv[1] +
                    acc[i][2][rr] * arv[2] + acc[i][3][rr] * arv[3];
#pragma unroll
        for (int o = 1; o < 16; o <<= 1) {
          se += __shfl_xor(se, o);
          sr2 += __shfl_xor(sr2, o);
        }
        if (tm == 0) {
          int row = r0 + wm + i * 16 + tq * 4 + rr;
          if (row < n) {
            el[(size_t)row * 4 + hd] = se;
            er[(size_t)row * 4 + hd] = sr2;
          }
        }
      }
    }
  }
}

// ---------------- aggregate layers 1-3: one wave per dst node ----------------
template <int RES>
__global__ __launch_bounds__(256) void agg64_k(const __hip_bfloat16* __restrict__ featb,
                                               const float* __restrict__ el,
                                               const float* __restrict__ er,
                                               const int* __restrict__ rowp,
                                               const int* __restrict__ csrc,
                                               const __hip_bfloat16* __restrict__ hinb,
                                               const float* __restrict__ bias,
                                               __hip_bfloat16* __restrict__ houtb, int n) {
  __shared__ float wsh[4][256];
  int wv = threadIdx.x >> 6;
  int node = blockIdx.x * 4 + wv;
  int lane = threadIdx.x & 63;
  if (node >= n) return;
  int s0 = rowp[node], s1 = rowp[node + 1];
  int deg = s1 - s0;
  float4 erv = *(const float4*)(er + (size_t)node * 4);
  float a0 = 0, a1 = 0, a2 = 0, a3 = 0;
  float i0 = 1.f, i1 = 1.f, i2 = 1.f, i3 = 1.f;

  if (deg <= 64) {
    // lane owns edge `lane`: unnormalized exp weights (max-sub is identity)
    int sown = 0;
    float x0 = 0.f, x1 = 0.f, x2 = 0.f, x3 = 0.f;
    if (lane < deg) {
      sown = csrc[s0 + lane];
      float4 e = *(const float4*)(el + (size_t)sown * 4);
      x0 = __expf(leaky(e.x + erv.x));
      x1 = __expf(leaky(e.y + erv.y));
      x2 = __expf(leaky(e.z + erv.z));
      x3 = __expf(leaky(e.w + erv.w));
    }
    float d0 = wsum_dpp(x0), d1 = wsum_dpp(x1), d2 = wsum_dpp(x2), d3 = wsum_dpp(x3);
    i0 = d0 > 0.f ? 1.f / d0 : 0.f;
    i1 = d1 > 0.f ? 1.f / d1 : 0.f;
    i2 = d2 > 0.f ? 1.f / d2 : 0.f;
    i3 = d3 > 0.f ? 1.f / d3 : 0.f;

    // stash weights in LDS; loop reads them at wave-uniform addr (broadcast)
    float4 wq = {x0, x1, x2, x3};
    *(float4*)&wsh[wv][lane * 4] = wq;

    int k = 0;
    for (; k + 4 <= deg; k += 4) {
      int sk0 = rli(sown, k + 0), sk1 = rli(sown, k + 1);
      int sk2 = rli(sown, k + 2), sk3 = rli(sown, k + 3);
      uint2 u0 = ((const uint2*)(featb + ((size_t)sk0 << 8)))[lane];
      uint2 u1 = ((const uint2*)(featb + ((size_t)sk1 << 8)))[lane];
      uint2 u2 = ((const uint2*)(featb + ((size_t)sk2 << 8)))[lane];
      uint2 u3 = ((const uint2*)(featb + ((size_t)sk3 << 8)))[lane];
      float4 w0 = *(const float4*)&wsh[wv][(k + 0) * 4];
      float4 w1 = *(const float4*)&wsh[wv][(k + 1) * 4];
      float4 w2 = *(const float4*)&wsh[wv][(k + 2) * 4];
      float4 w3 = *(const float4*)&wsh[wv][(k + 3) * 4];
      a0 = fmaf(w0.x, bflo(u0.x), a0); a1 = fmaf(w0.y, bfhi(u0.x), a1);
      a2 = fmaf(w0.z, bflo(u0.y), a2); a3 = fmaf(w0.w, bfhi(u0.y), a3);
      a0 = fmaf(w1.x, bflo(u1.x), a0); a1 = fmaf(w1.y, bfhi(u1.x), a1);
      a2 = fmaf(w1.z, bflo(u1.y), a2); a3 = fmaf(w1.w, bfhi(u1.y), a3);
      a0 = fmaf(w2.x, bflo(u2.x), a0); a1 = fmaf(w2.y, bfhi(u2.x), a1);
      a2 = fmaf(w2.z, bflo(u2.y), a2); a3 = fmaf(w2.w, bfhi(u2.y), a3);
      a0 = fmaf(w3.x, bflo(u3.x), a0); a1 = fmaf(w3.y, bfhi(u3.x), a1);
      a2 = fmaf(w3.z, bflo(u3.y), a2); a3 = fmaf(w3.w, bfhi(u3.y), a3);
    }
    for (; k < deg; ++k) {
      int sk = rli(sown, k);
      uint2 u = ((const uint2*)(featb + ((size_t)sk << 8)))[lane];
      float4 wk = *(const float4*)&wsh[wv][k * 4];
      a0 = fmaf(wk.x, bflo(u.x), a0);
      a1 = fmaf(wk.y, bfhi(u.x), a1);
      a2 = fmaf(wk.z, bflo(u.y), a2);
      a3 = fmaf(wk.w, bfhi(u.y), a3);
    }
  } else {
    // fallback (rare): 3-pass with max
    float m0 = -INFINITY, m1 = -INFINITY, m2 = -INFINITY, m3 = -INFINITY;
    for (int k = s0 + lane; k < s1; k += 64) {
      int s = csrc[k];
      float4 e = *(const float4*)(el + (size_t)s * 4);
      m0 = fmaxf(m0, leaky(e.x + erv.x));
      m1 = fmaxf(m1, leaky(e.y + erv.y));
      m2 = fmaxf(m2, leaky(e.z + erv.z));
      m3 = fmaxf(m3, leaky(e.w + erv.w));
    }
    m0 = wmax(m0); m1 = wmax(m1); m2 = wmax(m2); m3 = wmax(m3);
    float d0 = 0, d1 = 0, d2 = 0, d3 = 0;
    for (int k = s0 + lane; k < s1; k += 64) {
      int s = csrc[k];
      float4 e = *(const float4*)(el + (size_t)s * 4);
      d0 += __expf(leaky(e.x + erv.x) - m0);
      d1 += __expf(leaky(e.y + erv.y) - m1);
      d2 += __expf(leaky(e.z + erv.z) - m2);
      d3 += __expf(leaky(e.w + erv.w) - m3);
    }
    d0 = wsum_sh(d0); d1 = wsum_sh(d1); d2 = wsum_sh(d2); d3 = wsum_sh(d3);
    float j0 = d0 > 0.f ? 1.f / d0 : 0.f;
    float j1 = d1 > 0.f ? 1.f / d1 : 0.f;
    float j2 = d2 > 0.f ? 1.f / d2 : 0.f;
    float j3 = d3 > 0.f ? 1.f / d3 : 0.f;
    for (int k = s0; k < s1; ++k) {
      int s = csrc[k];
      float4 e = *(const float4*)(el + (size_t)s * 4);
      float w0 = __expf(leaky(e.x + erv.x) - m0) * j0;
      float w1 = __expf(leaky(e.y + erv.y) - m1) * j1;
      float w2 = __expf(leaky(e.z + erv.z) - m2) * j2;
      float w3 = __expf(leaky(e.w + erv.w) - m3) * j3;
      uint2 u = ((const uint2*)(featb + ((size_t)s << 8)))[lane];
      a0 = fmaf(w0, bflo(u.x), a0);
      a1 = fmaf(w1, bfhi(u.x), a1);
      a2 = fmaf(w2, bflo(u.y), a2);
      a3 = fmaf(w3, bfhi(u.y), a3);
    }
  }

  size_t base = (size_t)node * 256;
  float v0 = a0 * i0 + bias[lane];
  float v1 = a1 * i1 + bias[64 + lane];
  float v2 = a2 * i2 + bias[128 + lane];
  float v3 = a3 * i3 + bias[192 + lane];
  if (RES) {
    v0 += __bfloat162float(hinb[base + lane]);
    v1 += __bfloat162float(hinb[base + 64 + lane]);
    v2 += __bfloat162float(hinb[base + 128 + lane]);
    v3 += __bfloat162float(hinb[base + 192 + lane]);
  }
  houtb[base + lane]       = __float2bfloat16(eluf(v0));
  houtb[base + 64 + lane]  = __float2bfloat16(eluf(v1));
  houtb[base + 128 + lane] = __float2bfloat16(eluf(v2));
  houtb[base + 192 + lane] = __float2bfloat16(eluf(v3));
}

// ---------------- layer 4 projection (MFMA) + el4/er4 epilogue ----------------
__global__ __launch_bounds__(256) void l4mfma_k(const __hip_bfloat16* __restrict__ hb,
                                                const __hip_bfloat16* __restrict__ Wcat,
                                                const float* __restrict__ al4,
                                                const float* __restrict__ ar4,
                                                float* __restrict__ feat4,
                                                float* __restrict__ res4,
                                                float* __restrict__ el4,
                                                float* __restrict__ er4, int n) {
  int wid = blockIdx.x * 4 + (threadIdx.x >> 6);
  int n16 = (n + 15) >> 4;
  if (wid >= n16) return;
  int lane = threadIdx.x & 63;
  int tm = lane & 15, tq = lane >> 4;
  int row = wid * 16 + tm;
  int rowc = row < n ? row : n - 1;
  const __hip_bfloat16* ap = hb + (size_t)rowc * 256 + tq * 8;
  const __hip_bfloat16* bp = Wcat + (size_t)tm * 256 + tq * 8;
  f32x4_t acc = {0.f, 0.f, 0.f, 0.f};
#pragma unroll
  for (int k = 0; k < 8; ++k) {
    bf16x8_t af = *(const bf16x8_t*)(ap + k * 32);
    bf16x8_t bf = *(const bf16x8_t*)(bp + k * 32);
    acc = __builtin_amdgcn_mfma_f32_16x16x32_bf16(af, bf, acc, 0, 0, 0);
  }
  float* dstp = (tm < 8) ? feat4 : res4;
  int cc = tm & 7;
  float a4 = (tm < 8) ? al4[tm] : 0.f;
  float r4 = (tm < 8) ? ar4[tm] : 0.f;
#pragma unroll
  for (int r = 0; r < 4; ++r) {
    int node = wid * 16 + tq * 4 + r;
    float te = acc[r] * a4;
    float tr = acc[r] * r4;
    te += __shfl_xor(te, 1);
    tr += __shfl_xor(tr, 1);
    if (node < n) {
      dstp[(size_t)node * 8 + cc] = acc[r];
      if (tm < 8 && (tm & 1) == 0) {
        el4[(size_t)node * 4 + (tm >> 1)] = te;
        er4[(size_t)node * 4 + (tm >> 1)] = tr;
      }
    }
  }
}

// ---------------- layer 4 aggregate + per-head softmax + head mean ----------------
__global__ __launch_bounds__(256) void agg4_k(const float* __restrict__ feat4,
                                              const float* __restrict__ el4,
                                              const float* __restrict__ er4,
                                              const int* __restrict__ rowp,
                                              const int* __restrict__ csrc,
                                              const float* __restrict__ res4,
                                              const float* __restrict__ b4,
                                              float* __restrict__ out, int n) {
  __shared__ int ssh[4][64];
  __shared__ float wsh[4][256];
  int wv = threadIdx.x >> 6;
  int node = blockIdx.x * 4 + wv;
  int lane = threadIdx.x & 63;
  if (node >= n) return;
  int s0 = rowp[node], s1 = rowp[node + 1];
  int deg = s1 - s0;
  float4 erv = *(const float4*)(er4 + (size_t)node * 4);
  float acc = 0.f;
  float scale = 1.f;
  int p = lane & 7, hh = p >> 1;

  if (deg <= 64) {
    int sown = 0;
    float x0 = 0.f, x1 = 0.f, x2 = 0.f, x3 = 0.f;
    if (lane < deg) {
      sown = csrc[s0 + lane];
      float4 e = *(const float4*)(el4 + (size_t)sown * 4);
      x0 = __expf(leaky(e.x + erv.x));
      x1 = __expf(leaky(e.y + erv.y));
      x2 = __expf(leaky(e.z + erv.z));
      x3 = __expf(leaky(e.w + erv.w));
    }
    float d0 = wsum_dpp(x0), d1 = wsum_dpp(x1), d2 = wsum_dpp(x2), d3 = wsum_dpp(x3);
    float i0 = d0 > 0.f ? 1.f / d0 : 0.f;
    float i1 = d1 > 0.f ? 1.f / d1 : 0.f;
    float i2 = d2 > 0.f ? 1.f / d2 : 0.f;
    float i3 = d3 > 0.f ? 1.f / d3 : 0.f;
    scale = (hh == 0) ? i0 : (hh == 1) ? i1 : (hh == 2) ? i2 : i3;
    ssh[wv][lane] = sown;
    float4 wq = {x0, x1, x2, x3};
    *(float4*)&wsh[wv][lane * 4] = wq;
    int g = lane >> 3;
    int nt = (deg + 7) >> 3;
    for (int t = 0; t < nt; ++t) {
      int k = g + t * 8;
      bool ok = k < deg;
      int kk = k & 63;
      int sk = ssh[wv][kk];
      float wk = wsh[wv][kk * 4 + hh];
      if (ok) acc = fmaf(wk, feat4[(size_t)sk * 8 + p], acc);
    }
    acc += __shfl_xor(acc, 8);
    acc += __shfl_xor(acc, 16);
    acc += __shfl_xor(acc, 32);
  } else {
    float m0 = -INFINITY, m1 = -INFINITY, m2 = -INFINITY, m3 = -INFINITY;
    for (int k = s0 + lane; k < s1; k += 64) {
      int s = csrc[k];
      float4 e = *(const float4*)(el4 + (size_t)s * 4);
      m0 = fmaxf(m0, leaky(e.x + erv.x));
      m1 = fmaxf(m1, leaky(e.y + erv.y));
      m2 = fmaxf(m2, leaky(e.z + erv.z));
      m3 = fmaxf(m3, leaky(e.w + erv.w));
    }
    m0 = wmax(m0); m1 = wmax(m1); m2 = wmax(m2); m3 = wmax(m3);
    float d0 = 0, d1 = 0, d2 = 0, d3 = 0;
    for (int k = s0 + lane; k < s1; k += 64) {
      int s = csrc[k];
      float4 e = *(const float4*)(el4 + (size_t)s * 4);
      d0 += __expf(leaky(e.x + erv.x) - m0);
      d1 += __expf(leaky(e.y + erv.y) - m1);
      d2 += __expf(leaky(e.z + erv.z) - m2);
      d3 += __expf(leaky(e.w + erv.w) - m3);
    }
    d0 = wsum_sh(d0); d1 = wsum_sh(d1); d2 = wsum_sh(d2); d3 = wsum_sh(d3);
    float i0 = d0 > 0.f ? 1.f / d0 : 0.f;
    float i1 = d1 > 0.f ? 1.f / d1 : 0.f;
    float i2 = d2 > 0.f ? 1.f / d2 : 0.f;
    float i3 = d3 > 0.f ? 1.f / d3 : 0.f;
    for (int k = s0; k < s1; ++k) {
      int s = csrc[k];
      float4 e = *(const float4*)(el4 + (size_t)s * 4);
      float w0 = __expf(leaky(e.x + erv.x) - m0) * i0;
      float w1 = __expf(leaky(e.y + erv.y) - m1) * i1;
      float w2 = __expf(leaky(e.z + erv.z) - m2) * i2;
      float w3 = __expf(leaky(e.w + erv.w) - m3) * i3;
      float wk = (hh == 0) ? w0 : (hh == 1) ? w1 : (hh == 2) ? w2 : w3;
      if (lane < 8) acc = fmaf(wk, feat4[(size_t)s * 8 + p], acc);
    }
  }

  float v = 0.f;
  if (lane < 8) v = acc * scale + res4[(size_t)node * 8 + lane] + b4[lane];
  float pv = __shfl_xor(v, 1);
  float mx = fmaxf(v, pv);
  float ex = __expf(v - mx);
  float sm = ex + __shfl_xor(ex, 1);
  float pr = ex / sm;
  float t = pr + __shfl_xor(pr, 2);
  t += __shfl_xor(t, 4);
  if (lane < 2) out[(size_t)node * 2 + lane] = t * 0.25f;
}

extern "C" void kernel_launch(void* const* d_in, const int* in_sizes, int n_in,
                              void* d_out, int out_size, void* d_ws, size_t ws_size,
                              hipStream_t stream) {
  const float* x   = (const float*)d_in[0];
  const int* src   = (const int*)d_in[1];
  const int* dst   = (const int*)d_in[2];
  const float* W1  = (const float*)d_in[3];
  const float* al1 = (const float*)d_in[4];
  const float* ar1 = (const float*)d_in[5];
  const float* b1  = (const float*)d_in[6];
  const float* W2  = (const float*)d_in[7];
  const float* al2 = (const float*)d_in[8];
  const float* ar2 = (const float*)d_in[9];
  const float* b2  = (const float*)d_in[10];
  const float* W3  = (const float*)d_in[11];
  const float* al3 = (const float*)d_in[12];
  const float* ar3 = (const float*)d_in[13];
  const float* b3  = (const float*)d_in[14];
  const float* W4  = (const float*)d_in[15];
  const float* al4 = (const float*)d_in[16];
  const float* ar4 = (const float*)d_in[17];
  const float* b4  = (const float*)d_in[18];
  const float* rW4 = (const float*)d_in[19];
  float* out = (float*)d_out;

  const int n = in_sizes[0] / 128;  // 50000
  const int e = in_sizes[1];        // 800000

  char* ws = (char*)d_ws;
  auto alloc = [&](size_t bytes) -> char* {
    char* p = ws;
    ws += (bytes + 255) & ~(size_t)255;
    return p;
  };
  __hip_bfloat16* featb = (__hip_bfloat16*)alloc((size_t)n * 256 * 2);
  __hip_bfloat16* h1b   = (__hip_bfloat16*)alloc((size_t)n * 256 * 2);
  __hip_bfloat16* h2b   = (__hip_bfloat16*)alloc((size_t)n * 256 * 2);
  __hip_bfloat16* h3b   = (__hip_bfloat16*)alloc((size_t)n * 256 * 2);
  __hip_bfloat16* xb    = (__hip_bfloat16*)alloc((size_t)n * 128 * 2);
  __hip_bfloat16* W1b   = (__hip_bfloat16*)alloc((size_t)256 * 128 * 2);
  __hip_bfloat16* W2b   = (__hip_bfloat16*)alloc((size_t)256 * 256 * 2);
  __hip_bfloat16* W3b   = (__hip_bfloat16*)alloc((size_t)256 * 256 * 2);
  __hip_bfloat16* Wcatb = (__hip_bfloat16*)alloc((size_t)16 * 256 * 2);
  float* el    = (float*)alloc((size_t)n * 4 * 4);
  float* er    = (float*)alloc((size_t)n * 4 * 4);
  float* feat4 = (float*)alloc((size_t)n * 8 * 4);
  float* res4  = (float*)alloc((size_t)n * 8 * 4);
  float* el4   = (float*)alloc((size_t)n * 4 * 4);
  float* er4   = (float*)alloc((size_t)n * 4 * 4);
  int* deg     = (int*)alloc((size_t)n * 4);
  int* cur     = (int*)alloc((size_t)n * 4);
  int* rowp    = (int*)alloc((size_t)(n + 1) * 4);
  int* csrc    = (int*)alloc((size_t)e * 4);
  int nb_scan  = (n + 1023) / 1024;
  int* bsum    = (int*)alloc((size_t)(nb_scan + 1) * 4);

  // CSR build
  (void)hipMemsetAsync(deg, 0, (size_t)n * 4, stream);
  (void)hipMemsetAsync(cur, 0, (size_t)n * 4, stream);
  hist_k<<<(e + 255) / 256, 256, 0, stream>>>(dst, deg, e);
  scan1_k<<<nb_scan, 1024, 0, stream>>>(deg, rowp, bsum, n);
  scan2_k<<<1, 64, 0, stream>>>(bsum, nb_scan);
  scan3_k<<<(n + 256) / 256, 256, 0, stream>>>(bsum, rowp, n, nb_scan);
  scatter_k<<<(e + 255) / 256, 256, 0, stream>>>(src, dst, rowp, cur, csrc, e);

  // prep (single launch)
  int nx = n * 128;
  cvtall_k<<<(nx + 167936 + 255) / 256, 256, 0, stream>>>(x, W1, W2, W3, W4, rW4, xb, W1b,
                                                          W2b, W3b, Wcatb, nx);

  dim3 ggrid((n + 127) / 128, 2);
  int nb4 = (n + 3) / 4;

  // layer 1
  gemm_mfma<128><<<ggrid, 256, 0, stream>>>(xb, W1b, featb, al1, ar1, el, er, n);
  agg64_k<0><<<nb4, 256, 0, stream>>>(featb, el, er, rowp, csrc, nullptr, b1, h1b, n);
  // layer 2
  gemm_mfma<256><<<ggrid, 256, 0, stream>>>(h1b, W2b, featb, al2, ar2, el, er, n);
  agg64_k<1><<<nb4, 256, 0, stream>>>(featb, el, er, rowp, csrc, h1b, b2, h2b, n);
  // layer 3
  gemm_mfma<256><<<ggrid, 256, 0, stream>>>(h2b, W3b, featb, al3, ar3, el, er, n);
  agg64_k<1><<<nb4, 256, 0, stream>>>(featb, el, er, rowp, csrc, h2b, b3, h3b, n);
  // layer 4
  int n16 = (n + 15) / 16;
  l4mfma_k<<<(n16 + 3) / 4, 256, 0, stream>>>(h3b, Wcatb, al4, ar4, feat4, res4, el4, er4, n);
  agg4_k<<<nb4, 256, 0, stream>>>(feat4, el4, er4, rowp, csrc, res4, b4, out, n);
}

// Round 8
// 508.731 us; speedup vs baseline: 2.3976x; 1.0138x over previous
//
#include <hip/hip_runtime.h>
#include <hip/hip_bf16.h>
#include <math.h>

// GAT, 4 layers: N=50000, E=800000, IN=128, HID=64, H=4, C=2.
// R7: GEMM staging via global_load_lds width=16 (unpadded 128x32 LDS tiles,
// wave-uniform base + lane*16B); agg64 gather 8-wide unrolled with
// pre-normalized weights in LDS.

#define LEAKY_SLOPE 0.2f

typedef __bf16 bf16x8_t __attribute__((ext_vector_type(8)));
typedef float f32x4_t __attribute__((ext_vector_type(4)));

__device__ __forceinline__ float leaky(float x) { return x > 0.f ? x : LEAKY_SLOPE * x; }
__device__ __forceinline__ float eluf(float x)  { return x > 0.f ? x : expm1f(x); }
__device__ __forceinline__ float bflo(unsigned u) { return __uint_as_float(u << 16); }
__device__ __forceinline__ float bfhi(unsigned u) { return __uint_as_float(u & 0xffff0000u); }

__device__ __forceinline__ int rli(int v, int l) { return __builtin_amdgcn_readlane(v, l); }
__device__ __forceinline__ float rlf(float v, int l) {
  return __uint_as_float((unsigned)__builtin_amdgcn_readlane((int)__float_as_uint(v), l));
}
template <int CTRL>
__device__ __forceinline__ float dpp_add(float x) {
  int t = __builtin_amdgcn_update_dpp(0, (int)__float_as_uint(x), CTRL, 0xf, 0xf, false);
  return x + __uint_as_float((unsigned)t);
}
__device__ __forceinline__ float wsum_dpp(float x) {
  x = dpp_add<0x111>(x);
  x = dpp_add<0x112>(x);
  x = dpp_add<0x114>(x);
  x = dpp_add<0x118>(x);
  x = dpp_add<0x142>(x);
  x = dpp_add<0x143>(x);
  return rlf(x, 63);
}
__device__ __forceinline__ float wmax(float v) {
#pragma unroll
  for (int o = 32; o; o >>= 1) v = fmaxf(v, __shfl_xor(v, o));
  return v;
}
__device__ __forceinline__ float wsum_sh(float v) {
#pragma unroll
  for (int o = 32; o; o >>= 1) v += __shfl_xor(v, o);
  return v;
}

// async global->LDS, 16B per lane; LDS dest = wave-uniform base + lane*16
__device__ __forceinline__ void gl_lds16(const __hip_bfloat16* g, __bf16* l) {
  __builtin_amdgcn_global_load_lds((const __attribute__((address_space(1))) void*)g,
                                   (__attribute__((address_space(3))) void*)l, 16, 0, 0);
}

// ---------------- CSR build ----------------
__global__ void hist_k(const int* __restrict__ dst, int* __restrict__ deg, int e) {
  int i = blockIdx.x * 256 + threadIdx.x;
  if (i < e) atomicAdd(&deg[dst[i]], 1);
}

__global__ __launch_bounds__(1024) void scan1_k(const int* __restrict__ deg,
                                                int* __restrict__ rowp,
                                                int* __restrict__ bsum, int n) {
  __shared__ int sd[1024];
  int tid = threadIdx.x;
  int i = blockIdx.x * 1024 + tid;
  int v = (i < n) ? deg[i] : 0;
  int x = v;
  sd[tid] = x;
  __syncthreads();
  for (int off = 1; off < 1024; off <<= 1) {
    int t = (tid >= off) ? sd[tid - off] : 0;
    __syncthreads();
    x += t;
    sd[tid] = x;
    __syncthreads();
  }
  if (i < n) rowp[i] = x - v;
  if (tid == 1023) bsum[blockIdx.x] = x;
}

__global__ __launch_bounds__(64) void scan2_k(int* __restrict__ bsum, int nb) {
  int lane = threadIdx.x;
  if (nb <= 64) {
    int v = (lane < nb) ? bsum[lane] : 0;
    int x = v;
#pragma unroll
    for (int off = 1; off < 64; off <<= 1) {
      int t = __shfl_up(x, off);
      if (lane >= off) x += t;
    }
    if (lane < nb) bsum[lane] = x - v;
    if (lane == 63) bsum[nb] = x;
  } else if (lane == 0) {
    int run = 0;
    for (int i = 0; i < nb; ++i) { int t = bsum[i]; bsum[i] = run; run += t; }
    bsum[nb] = run;
  }
}

__global__ void scan3_k(const int* __restrict__ bsum, int* __restrict__ rowp, int n, int nb) {
  int i = blockIdx.x * 256 + threadIdx.x;
  if (i < n) rowp[i] += bsum[i >> 10];
  if (i == n) rowp[n] = bsum[nb];
}

__global__ void scatter_k(const int* __restrict__ src, const int* __restrict__ dst,
                          const int* __restrict__ rowp, int* __restrict__ cur,
                          int* __restrict__ csrc, int e) {
  int i = blockIdx.x * 256 + threadIdx.x;
  if (i < e) {
    int d = dst[i];
    int p = atomicAdd(&cur[d], 1);
    csrc[rowp[d] + p] = src[i];
  }
}

// ---------------- prep: x + all weights -> bf16, one launch ----------------
__global__ void cvtall_k(const float* __restrict__ x, const float* __restrict__ W1,
                         const float* __restrict__ W2, const float* __restrict__ W3,
                         const float* __restrict__ W4, const float* __restrict__ rW4,
                         __hip_bfloat16* __restrict__ xb, __hip_bfloat16* __restrict__ W1b,
                         __hip_bfloat16* __restrict__ W2b, __hip_bfloat16* __restrict__ W3b,
                         __hip_bfloat16* __restrict__ Wcatb, int nx) {
  int i = blockIdx.x * 256 + threadIdx.x;
  if (i < nx) { xb[i] = __float2bfloat16(x[i]); return; }
  int j = i - nx;
  if (j < 32768) W1b[j] = __float2bfloat16(W1[j]);
  else if (j < 98304)  { int k = j - 32768;  W2b[k] = __float2bfloat16(W2[k]); }
  else if (j < 163840) { int k = j - 98304;  W3b[k] = __float2bfloat16(W3[k]); }
  else if (j < 165888) { int k = j - 163840; Wcatb[k] = __float2bfloat16(W4[k]); }
  else if (j < 167936) { int k = j - 165888; Wcatb[2048 + k] = __float2bfloat16(rW4[k]); }
}

// ---------------- MFMA GEMM + el/er epilogue ----------------
// featb[n][o=64][h=4](bf16) = A[n][K] @ B[256][K]^T ; el/er[n][4] = feat.al/.ar
// LDS tiles unpadded 128x32 bf16; staging via global_load_lds (interior blocks).
template <int K>
__global__ __launch_bounds__(256) void gemm_mfma(const __hip_bfloat16* __restrict__ A,
                                                 const __hip_bfloat16* __restrict__ B,
                                                 __hip_bfloat16* __restrict__ featb,
                                                 const float* __restrict__ al,
                                                 const float* __restrict__ ar,
                                                 float* __restrict__ el,
                                                 float* __restrict__ er, int n) {
  __shared__ __bf16 As[128 * 32];
  __shared__ __bf16 Bs[128 * 32];
  const int tid = threadIdx.x;
  const int lane = tid & 63, w = tid >> 6;
  const int tm = lane & 15, tq = lane >> 4;
  const int wm = (w & 1) * 64, wn = (w >> 1) * 64;
  const int r0 = blockIdx.x * 128, c0 = blockIdx.y * 128;

  f32x4_t acc[4][4];
#pragma unroll
  for (int i = 0; i < 4; ++i)
#pragma unroll
    for (int j = 0; j < 4; ++j) acc[i][j] = 0.f;

  const bool interior = (r0 + 128 <= n);
  if (interior) {
    // staging map: wave w, call c in {0,1}, lane l ->
    //   LDS 16B-chunk idx = w*128 + c*64 + l  -> row = idx>>2, c8 = idx&3
    const int srow = w * 32 + (lane >> 2);
    const int scol = (lane & 3) * 8;
    for (int kk = 0; kk < K; kk += 32) {
      __syncthreads();  // prior iter's LDS reads complete before overwrite
      const __hip_bfloat16* ga = A + (size_t)(r0 + srow) * K + kk + scol;
      const __hip_bfloat16* gb = B + (size_t)(c0 + srow) * K + kk + scol;
      gl_lds16(ga, As + w * 1024);
      gl_lds16(ga + (size_t)16 * K, As + w * 1024 + 512);
      gl_lds16(gb, Bs + w * 1024);
      gl_lds16(gb + (size_t)16 * K, Bs + w * 1024 + 512);
      __syncthreads();  // drains vmcnt -> staged data visible
      bf16x8_t af[4], bfr[4];
#pragma unroll
      for (int i = 0; i < 4; ++i) af[i] = *(const bf16x8_t*)&As[(wm + i * 16 + tm) * 32 + tq * 8];
#pragma unroll
      for (int j = 0; j < 4; ++j) bfr[j] = *(const bf16x8_t*)&Bs[(wn + j * 16 + tm) * 32 + tq * 8];
#pragma unroll
      for (int i = 0; i < 4; ++i)
#pragma unroll
        for (int j = 0; j < 4; ++j)
          acc[i][j] = __builtin_amdgcn_mfma_f32_16x16x32_bf16(af[i], bfr[j], acc[i][j], 0, 0, 0);
    }
  } else {
    // boundary block (rows may exceed n): guarded VGPR staging
    const int srow = tid >> 1, sko = (tid & 1) * 16;
    for (int kk = 0; kk < K; kk += 32) {
      uint4 av0 = {0, 0, 0, 0}, av1 = {0, 0, 0, 0};
      int arw = r0 + srow;
      if (arw < n) {
        const uint4* p = (const uint4*)(A + (size_t)arw * K + kk + sko);
        av0 = p[0];
        av1 = p[1];
      }
      const uint4* q = (const uint4*)(B + (size_t)(c0 + srow) * K + kk + sko);
      uint4 bv0 = q[0], bv1 = q[1];
      __syncthreads();
      *(uint4*)&As[srow * 32 + sko] = av0;
      *(uint4*)&As[srow * 32 + sko + 8] = av1;
      *(uint4*)&Bs[srow * 32 + sko] = bv0;
      *(uint4*)&Bs[srow * 32 + sko + 8] = bv1;
      __syncthreads();
      bf16x8_t af[4], bfr[4];
#pragma unroll
      for (int i = 0; i < 4; ++i) af[i] = *(const bf16x8_t*)&As[(wm + i * 16 + tm) * 32 + tq * 8];
#pragma unroll
      for (int j = 0; j < 4; ++j) bfr[j] = *(const bf16x8_t*)&Bs[(wn + j * 16 + tm) * 32 + tq * 8];
#pragma unroll
      for (int i = 0; i < 4; ++i)
#pragma unroll
        for (int j = 0; j < 4; ++j)
          acc[i][j] = __builtin_amdgcn_mfma_f32_16x16x32_bf16(af[i], bfr[j], acc[i][j], 0, 0, 0);
    }
  }

  // featb store
#pragma unroll
  for (int i = 0; i < 4; ++i) {
#pragma unroll
    for (int j = 0; j < 4; ++j) {
      int col = c0 + wn + j * 16 + tm;
      int hh = col >> 6, oo = col & 63;
#pragma unroll
      for (int rr = 0; rr < 4; ++rr) {
        int row = r0 + wm + i * 16 + tq * 4 + rr;
        if (row < n) featb[(size_t)row * 256 + oo * 4 + hh] = __float2bfloat16(acc[i][j][rr]);
      }
    }
  }

  // el/er epilogue: this wave owns head hd = (c0+wn)>>6 entirely (64 cols)
  {
    const int hd = (c0 + wn) >> 6;
    float alv[4], arv[4];
#pragma unroll
    for (int j = 0; j < 4; ++j) {
      alv[j] = al[hd * 64 + j * 16 + tm];
      arv[j] = ar[hd * 64 + j * 16 + tm];
    }
#pragma unroll
    for (int i = 0; i < 4; ++i) {
#pragma unroll
      for (int rr = 0; rr < 4; ++rr) {
        float se = acc[i][0][rr] * alv[0] + acc[i][1][rr] * alv[1] +
                   acc[i][2][rr] * alv[2] + acc[i][3][rr] * alv[3];
        float sr2 = acc[i][0][rr] * arv[0] + acc[i][1][rr] * arv[1] +
                    acc[i][2][rr] * arv[2] + acc[i][3][rr] * arv[3];
#pragma unroll
        for (int o = 1; o < 16; o <<= 1) {
          se += __shfl_xor(se, o);
          sr2 += __shfl_xor(sr2, o);
        }
        if (tm == 0) {
          int row = r0 + wm + i * 16 + tq * 4 + rr;
          if (row < n) {
            el[(size_t)row * 4 + hd] = se;
            er[(size_t)row * 4 + hd] = sr2;
          }
        }
      }
    }
  }
}

// ---------------- aggregate layers 1-3: one wave per dst node ----------------
template <int RES>
__global__ __launch_bounds__(256) void agg64_k(const __hip_bfloat16* __restrict__ featb,
                                               const float* __restrict__ el,
                                               const float* __restrict__ er,
                                               const int* __restrict__ rowp,
                                               const int* __restrict__ csrc,
                                               const __hip_bfloat16* __restrict__ hinb,
                                               const float* __restrict__ bias,
                                               __hip_bfloat16* __restrict__ houtb, int n) {
  __shared__ float wsh[4][256];
  int wv = threadIdx.x >> 6;
  int node = blockIdx.x * 4 + wv;
  int lane = threadIdx.x & 63;
  if (node >= n) return;
  int s0 = rowp[node], s1 = rowp[node + 1];
  int deg = s1 - s0;
  float4 erv = *(const float4*)(er + (size_t)node * 4);
  float a0 = 0, a1 = 0, a2 = 0, a3 = 0;

  if (deg <= 64) {
    // lane owns edge `lane`: unnormalized exp (max-sub is identity), then
    // pre-normalize and stash in LDS; loop reads at wave-uniform addr.
    int sown = 0;
    float x0 = 0.f, x1 = 0.f, x2 = 0.f, x3 = 0.f;
    if (lane < deg) {
      sown = csrc[s0 + lane];
      float4 e = *(const float4*)(el + (size_t)sown * 4);
      x0 = __expf(leaky(e.x + erv.x));
      x1 = __expf(leaky(e.y + erv.y));
      x2 = __expf(leaky(e.z + erv.z));
      x3 = __expf(leaky(e.w + erv.w));
    }
    float d0 = wsum_dpp(x0), d1 = wsum_dpp(x1), d2 = wsum_dpp(x2), d3 = wsum_dpp(x3);
    float i0 = d0 > 0.f ? 1.f / d0 : 0.f;
    float i1 = d1 > 0.f ? 1.f / d1 : 0.f;
    float i2 = d2 > 0.f ? 1.f / d2 : 0.f;
    float i3 = d3 > 0.f ? 1.f / d3 : 0.f;
    float4 wq = {x0 * i0, x1 * i1, x2 * i2, x3 * i3};
    *(float4*)&wsh[wv][lane * 4] = wq;

    int k = 0;
    for (; k + 8 <= deg; k += 8) {
      int sk0 = rli(sown, k + 0), sk1 = rli(sown, k + 1);
      int sk2 = rli(sown, k + 2), sk3 = rli(sown, k + 3);
      int sk4 = rli(sown, k + 4), sk5 = rli(sown, k + 5);
      int sk6 = rli(sown, k + 6), sk7 = rli(sown, k + 7);
      uint2 u0 = ((const uint2*)(featb + ((size_t)sk0 << 8)))[lane];
      uint2 u1 = ((const uint2*)(featb + ((size_t)sk1 << 8)))[lane];
      uint2 u2 = ((const uint2*)(featb + ((size_t)sk2 << 8)))[lane];
      uint2 u3 = ((const uint2*)(featb + ((size_t)sk3 << 8)))[lane];
      uint2 u4 = ((const uint2*)(featb + ((size_t)sk4 << 8)))[lane];
      uint2 u5 = ((const uint2*)(featb + ((size_t)sk5 << 8)))[lane];
      uint2 u6 = ((const uint2*)(featb + ((size_t)sk6 << 8)))[lane];
      uint2 u7 = ((const uint2*)(featb + ((size_t)sk7 << 8)))[lane];
      float4 w0 = *(const float4*)&wsh[wv][(k + 0) * 4];
      float4 w1 = *(const float4*)&wsh[wv][(k + 1) * 4];
      float4 w2 = *(const float4*)&wsh[wv][(k + 2) * 4];
      float4 w3 = *(const float4*)&wsh[wv][(k + 3) * 4];
      float4 w4 = *(const float4*)&wsh[wv][(k + 4) * 4];
      float4 w5 = *(const float4*)&wsh[wv][(k + 5) * 4];
      float4 w6 = *(const float4*)&wsh[wv][(k + 6) * 4];
      float4 w7 = *(const float4*)&wsh[wv][(k + 7) * 4];
      a0 = fmaf(w0.x, bflo(u0.x), a0); a1 = fmaf(w0.y, bfhi(u0.x), a1);
      a2 = fmaf(w0.z, bflo(u0.y), a2); a3 = fmaf(w0.w, bfhi(u0.y), a3);
      a0 = fmaf(w1.x, bflo(u1.x), a0); a1 = fmaf(w1.y, bfhi(u1.x), a1);
      a2 = fmaf(w1.z, bflo(u1.y), a2); a3 = fmaf(w1.w, bfhi(u1.y), a3);
      a0 = fmaf(w2.x, bflo(u2.x), a0); a1 = fmaf(w2.y, bfhi(u2.x), a1);
      a2 = fmaf(w2.z, bflo(u2.y), a2); a3 = fmaf(w2.w, bfhi(u2.y), a3);
      a0 = fmaf(w3.x, bflo(u3.x), a0); a1 = fmaf(w3.y, bfhi(u3.x), a1);
      a2 = fmaf(w3.z, bflo(u3.y), a2); a3 = fmaf(w3.w, bfhi(u3.y), a3);
      a0 = fmaf(w4.x, bflo(u4.x), a0); a1 = fmaf(w4.y, bfhi(u4.x), a1);
      a2 = fmaf(w4.z, bflo(u4.y), a2); a3 = fmaf(w4.w, bfhi(u4.y), a3);
      a0 = fmaf(w5.x, bflo(u5.x), a0); a1 = fmaf(w5.y, bfhi(u5.x), a1);
      a2 = fmaf(w5.z, bflo(u5.y), a2); a3 = fmaf(w5.w, bfhi(u5.y), a3);
      a0 = fmaf(w6.x, bflo(u6.x), a0); a1 = fmaf(w6.y, bfhi(u6.x), a1);
      a2 = fmaf(w6.z, bflo(u6.y), a2); a3 = fmaf(w6.w, bfhi(u6.y), a3);
      a0 = fmaf(w7.x, bflo(u7.x), a0); a1 = fmaf(w7.y, bfhi(u7.x), a1);
      a2 = fmaf(w7.z, bflo(u7.y), a2); a3 = fmaf(w7.w, bfhi(u7.y), a3);
    }
    for (; k + 4 <= deg; k += 4) {
      int sk0 = rli(sown, k + 0), sk1 = rli(sown, k + 1);
      int sk2 = rli(sown, k + 2), sk3 = rli(sown, k + 3);
      uint2 u0 = ((const uint2*)(featb + ((size_t)sk0 << 8)))[lane];
      uint2 u1 = ((const uint2*)(featb + ((size_t)sk1 << 8)))[lane];
      uint2 u2 = ((const uint2*)(featb + ((size_t)sk2 << 8)))[lane];
      uint2 u3 = ((const uint2*)(featb + ((size_t)sk3 << 8)))[lane];
      float4 w0 = *(const float4*)&wsh[wv][(k + 0) * 4];
      float4 w1 = *(const float4*)&wsh[wv][(k + 1) * 4];
      float4 w2 = *(const float4*)&wsh[wv][(k + 2) * 4];
      float4 w3 = *(const float4*)&wsh[wv][(k + 3) * 4];
      a0 = fmaf(w0.x, bflo(u0.x), a0); a1 = fmaf(w0.y, bfhi(u0.x), a1);
      a2 = fmaf(w0.z, bflo(u0.y), a2); a3 = fmaf(w0.w, bfhi(u0.y), a3);
      a0 = fmaf(w1.x, bflo(u1.x), a0); a1 = fmaf(w1.y, bfhi(u1.x), a1);
      a2 = fmaf(w1.z, bflo(u1.y), a2); a3 = fmaf(w1.w, bfhi(u1.y), a3);
      a0 = fmaf(w2.x, bflo(u2.x), a0); a1 = fmaf(w2.y, bfhi(u2.x), a1);
      a2 = fmaf(w2.z, bflo(u2.y), a2); a3 = fmaf(w2.w, bfhi(u2.y), a3);
      a0 = fmaf(w3.x, bflo(u3.x), a0); a1 = fmaf(w3.y, bfhi(u3.x), a1);
      a2 = fmaf(w3.z, bflo(u3.y), a2); a3 = fmaf(w3.w, bfhi(u3.y), a3);
    }
    for (; k < deg; ++k) {
      int sk = rli(sown, k);
      uint2 u = ((const uint2*)(featb + ((size_t)sk << 8)))[lane];
      float4 wk = *(const float4*)&wsh[wv][k * 4];
      a0 = fmaf(wk.x, bflo(u.x), a0);
      a1 = fmaf(wk.y, bfhi(u.x), a1);
      a2 = fmaf(wk.z, bflo(u.y), a2);
      a3 = fmaf(wk.w, bfhi(u.y), a3);
    }
  } else {
    // fallback (rare): 3-pass with max
    float m0 = -INFINITY, m1 = -INFINITY, m2 = -INFINITY, m3 = -INFINITY;
    for (int k = s0 + lane; k < s1; k += 64) {
      int s = csrc[k];
      float4 e = *(const float4*)(el + (size_t)s * 4);
      m0 = fmaxf(m0, leaky(e.x + erv.x));
      m1 = fmaxf(m1, leaky(e.y + erv.y));
      m2 = fmaxf(m2, leaky(e.z + erv.z));
      m3 = fmaxf(m3, leaky(e.w + erv.w));
    }
    m0 = wmax(m0); m1 = wmax(m1); m2 = wmax(m2); m3 = wmax(m3);
    float d0 = 0, d1 = 0, d2 = 0, d3 = 0;
    for (int k = s0 + lane; k < s1; k += 64) {
      int s = csrc[k];
      float4 e = *(const float4*)(el + (size_t)s * 4);
      d0 += __expf(leaky(e.x + erv.x) - m0);
      d1 += __expf(leaky(e.y + erv.y) - m1);
      d2 += __expf(leaky(e.z + erv.z) - m2);
      d3 += __expf(leaky(e.w + erv.w) - m3);
    }
    d0 = wsum_sh(d0); d1 = wsum_sh(d1); d2 = wsum_sh(d2); d3 = wsum_sh(d3);
    float j0 = d0 > 0.f ? 1.f / d0 : 0.f;
    float j1 = d1 > 0.f ? 1.f / d1 : 0.f;
    float j2 = d2 > 0.f ? 1.f / d2 : 0.f;
    float j3 = d3 > 0.f ? 1.f / d3 : 0.f;
    for (int k = s0; k < s1; ++k) {
      int s = csrc[k];
      float4 e = *(const float4*)(el + (size_t)s * 4);
      float w0 = __expf(leaky(e.x + erv.x) - m0) * j0;
      float w1 = __expf(leaky(e.y + erv.y) - m1) * j1;
      float w2 = __expf(leaky(e.z + erv.z) - m2) * j2;
      float w3 = __expf(leaky(e.w + erv.w) - m3) * j3;
      uint2 u = ((const uint2*)(featb + ((size_t)s << 8)))[lane];
      a0 = fmaf(w0, bflo(u.x), a0);
      a1 = fmaf(w1, bfhi(u.x), a1);
      a2 = fmaf(w2, bflo(u.y), a2);
      a3 = fmaf(w3, bfhi(u.y), a3);
    }
  }

  size_t base = (size_t)node * 256;
  float v0 = a0 + bias[lane];
  float v1 = a1 + bias[64 + lane];
  float v2 = a2 + bias[128 + lane];
  float v3 = a3 + bias[192 + lane];
  if (RES) {
    v0 += __bfloat162float(hinb[base + lane]);
    v1 += __bfloat162float(hinb[base + 64 + lane]);
    v2 += __bfloat162float(hinb[base + 128 + lane]);
    v3 += __bfloat162float(hinb[base + 192 + lane]);
  }
  houtb[base + lane]       = __float2bfloat16(eluf(v0));
  houtb[base + 64 + lane]  = __float2bfloat16(eluf(v1));
  houtb[base + 128 + lane] = __float2bfloat16(eluf(v2));
  houtb[base + 192 + lane] = __float2bfloat16(eluf(v3));
}

// ---------------- layer 4 projection (MFMA) + el4/er4 epilogue ----------------
__global__ __launch_bounds__(256) void l4mfma_k(const __hip_bfloat16* __restrict__ hb,
                                                const __hip_bfloat16* __restrict__ Wcat,
                                                const float* __restrict__ al4,
                                                const float* __restrict__ ar4,
                                                float* __restrict__ feat4,
                                                float* __restrict__ res4,
                                                float* __restrict__ el4,
                                                float* __restrict__ er4, int n) {
  int wid = blockIdx.x * 4 + (threadIdx.x >> 6);
  int n16 = (n + 15) >> 4;
  if (wid >= n16) return;
  int lane = threadIdx.x & 63;
  int tm = lane & 15, tq = lane >> 4;
  int row = wid * 16 + tm;
  int rowc = row < n ? row : n - 1;
  const __hip_bfloat16* ap = hb + (size_t)rowc * 256 + tq * 8;
  const __hip_bfloat16* bp = Wcat + (size_t)tm * 256 + tq * 8;
  f32x4_t acc = {0.f, 0.f, 0.f, 0.f};
#pragma unroll
  for (int k = 0; k < 8; ++k) {
    bf16x8_t af = *(const bf16x8_t*)(ap + k * 32);
    bf16x8_t bf = *(const bf16x8_t*)(bp + k * 32);
    acc = __builtin_amdgcn_mfma_f32_16x16x32_bf16(af, bf, acc, 0, 0, 0);
  }
  float* dstp = (tm < 8) ? feat4 : res4;
  int cc = tm & 7;
  float a4 = (tm < 8) ? al4[tm] : 0.f;
  float r4 = (tm < 8) ? ar4[tm] : 0.f;
#pragma unroll
  for (int r = 0; r < 4; ++r) {
    int node = wid * 16 + tq * 4 + r;
    float te = acc[r] * a4;
    float tr = acc[r] * r4;
    te += __shfl_xor(te, 1);
    tr += __shfl_xor(tr, 1);
    if (node < n) {
      dstp[(size_t)node * 8 + cc] = acc[r];
      if (tm < 8 && (tm & 1) == 0) {
        el4[(size_t)node * 4 + (tm >> 1)] = te;
        er4[(size_t)node * 4 + (tm >> 1)] = tr;
      }
    }
  }
}

// ---------------- layer 4 aggregate + per-head softmax + head mean ----------------
__global__ __launch_bounds__(256) void agg4_k(const float* __restrict__ feat4,
                                              const float* __restrict__ el4,
                                              const float* __restrict__ er4,
                                              const int* __restrict__ rowp,
                                              const int* __restrict__ csrc,
                                              const float* __restrict__ res4,
                                              const float* __restrict__ b4,
                                              float* __restrict__ out, int n) {
  __shared__ int ssh[4][64];
  __shared__ float wsh[4][256];
  int wv = threadIdx.x >> 6;
  int node = blockIdx.x * 4 + wv;
  int lane = threadIdx.x & 63;
  if (node >= n) return;
  int s0 = rowp[node], s1 = rowp[node + 1];
  int deg = s1 - s0;
  float4 erv = *(const float4*)(er4 + (size_t)node * 4);
  float acc = 0.f;
  float scale = 1.f;
  int p = lane & 7, hh = p >> 1;

  if (deg <= 64) {
    int sown = 0;
    float x0 = 0.f, x1 = 0.f, x2 = 0.f, x3 = 0.f;
    if (lane < deg) {
      sown = csrc[s0 + lane];
      float4 e = *(const float4*)(el4 + (size_t)sown * 4);
      x0 = __expf(leaky(e.x + erv.x));
      x1 = __expf(leaky(e.y + erv.y));
      x2 = __expf(leaky(e.z + erv.z));
      x3 = __expf(leaky(e.w + erv.w));
    }
    float d0 = wsum_dpp(x0), d1 = wsum_dpp(x1), d2 = wsum_dpp(x2), d3 = wsum_dpp(x3);
    float i0 = d0 > 0.f ? 1.f / d0 : 0.f;
    float i1 = d1 > 0.f ? 1.f / d1 : 0.f;
    float i2 = d2 > 0.f ? 1.f / d2 : 0.f;
    float i3 = d3 > 0.f ? 1.f / d3 : 0.f;
    scale = (hh == 0) ? i0 : (hh == 1) ? i1 : (hh == 2) ? i2 : i3;
    ssh[wv][lane] = sown;
    float4 wq = {x0, x1, x2, x3};
    *(float4*)&wsh[wv][lane * 4] = wq;
    int g = lane >> 3;
    int nt = (deg + 7) >> 3;
    for (int t = 0; t < nt; ++t) {
      int k = g + t * 8;
      bool ok = k < deg;
      int kk = k & 63;
      int sk = ssh[wv][kk];
      float wk = wsh[wv][kk * 4 + hh];
      if (ok) acc = fmaf(wk, feat4[(size_t)sk * 8 + p], acc);
    }
    acc += __shfl_xor(acc, 8);
    acc += __shfl_xor(acc, 16);
    acc += __shfl_xor(acc, 32);
  } else {
    float m0 = -INFINITY, m1 = -INFINITY, m2 = -INFINITY, m3 = -INFINITY;
    for (int k = s0 + lane; k < s1; k += 64) {
      int s = csrc[k];
      float4 e = *(const float4*)(el4 + (size_t)s * 4);
      m0 = fmaxf(m0, leaky(e.x + erv.x));
      m1 = fmaxf(m1, leaky(e.y + erv.y));
      m2 = fmaxf(m2, leaky(e.z + erv.z));
      m3 = fmaxf(m3, leaky(e.w + erv.w));
    }
    m0 = wmax(m0); m1 = wmax(m1); m2 = wmax(m2); m3 = wmax(m3);
    float d0 = 0, d1 = 0, d2 = 0, d3 = 0;
    for (int k = s0 + lane; k < s1; k += 64) {
      int s = csrc[k];
      float4 e = *(const float4*)(el4 + (size_t)s * 4);
      d0 += __expf(leaky(e.x + erv.x) - m0);
      d1 += __expf(leaky(e.y + erv.y) - m1);
      d2 += __expf(leaky(e.z + erv.z) - m2);
      d3 += __expf(leaky(e.w + erv.w) - m3);
    }
    d0 = wsum_sh(d0); d1 = wsum_sh(d1); d2 = wsum_sh(d2); d3 = wsum_sh(d3);
    float i0 = d0 > 0.f ? 1.f / d0 : 0.f;
    float i1 = d1 > 0.f ? 1.f / d1 : 0.f;
    float i2 = d2 > 0.f ? 1.f / d2 : 0.f;
    float i3 = d3 > 0.f ? 1.f / d3 : 0.f;
    for (int k = s0; k < s1; ++k) {
      int s = csrc[k];
      float4 e = *(const float4*)(el4 + (size_t)s * 4);
      float w0 = __expf(leaky(e.x + erv.x) - m0) * i0;
      float w1 = __expf(leaky(e.y + erv.y) - m1) * i1;
      float w2 = __expf(leaky(e.z + erv.z) - m2) * i2;
      float w3 = __expf(leaky(e.w + erv.w) - m3) * i3;
      float wk = (hh == 0) ? w0 : (hh == 1) ? w1 : (hh == 2) ? w2 : w3;
      if (lane < 8) acc = fmaf(wk, feat4[(size_t)s * 8 + p], acc);
    }
  }

  float v = 0.f;
  if (lane < 8) v = acc * scale + res4[(size_t)node * 8 + lane] + b4[lane];
  float pv = __shfl_xor(v, 1);
  float mx = fmaxf(v, pv);
  float ex = __expf(v - mx);
  float sm = ex + __shfl_xor(ex, 1);
  float pr = ex / sm;
  float t = pr + __shfl_xor(pr, 2);
  t += __shfl_xor(t, 4);
  if (lane < 2) out[(size_t)node * 2 + lane] = t * 0.25f;
}

extern "C" void kernel_launch(void* const* d_in, const int* in_sizes, int n_in,
                              void* d_out, int out_size, void* d_ws, size_t ws_size,
                              hipStream_t stream) {
  const float* x   = (const float*)d_in[0];
  const int* src   = (const int*)d_in[1];
  const int* dst   = (const int*)d_in[2];
  const float* W1  = (const float*)d_in[3];
  const float* al1 = (const float*)d_in[4];
  const float* ar1 = (const float*)d_in[5];
  const float* b1  = (const float*)d_in[6];
  const float* W2  = (const float*)d_in[7];
  const float* al2 = (const float*)d_in[8];
  const float* ar2 = (const float*)d_in[9];
  const float* b2  = (const float*)d_in[10];
  const float* W3  = (const float*)d_in[11];
  const float* al3 = (const float*)d_in[12];
  const float* ar3 = (const float*)d_in[13];
  const float* b3  = (const float*)d_in[14];
  const float* W4  = (const float*)d_in[15];
  const float* al4 = (const float*)d_in[16];
  const float* ar4 = (const float*)d_in[17];
  const float* b4  = (const float*)d_in[18];
  const float* rW4 = (const float*)d_in[19];
  float* out = (float*)d_out;

  const int n = in_sizes[0] / 128;  // 50000
  const int e = in_sizes[1];        // 800000

  char* ws = (char*)d_ws;
  auto alloc = [&](size_t bytes) -> char* {
    char* p = ws;
    ws += (bytes + 255) & ~(size_t)255;
    return p;
  };
  __hip_bfloat16* featb = (__hip_bfloat16*)alloc((size_t)n * 256 * 2);
  __hip_bfloat16* h1b   = (__hip_bfloat16*)alloc((size_t)n * 256 * 2);
  __hip_bfloat16* h2b   = (__hip_bfloat16*)alloc((size_t)n * 256 * 2);
  __hip_bfloat16* h3b   = (__hip_bfloat16*)alloc((size_t)n * 256 * 2);
  __hip_bfloat16* xb    = (__hip_bfloat16*)alloc((size_t)n * 128 * 2);
  __hip_bfloat16* W1b   = (__hip_bfloat16*)alloc((size_t)256 * 128 * 2);
  __hip_bfloat16* W2b   = (__hip_bfloat16*)alloc((size_t)256 * 256 * 2);
  __hip_bfloat16* W3b   = (__hip_bfloat16*)alloc((size_t)256 * 256 * 2);
  __hip_bfloat16* Wcatb = (__hip_bfloat16*)alloc((size_t)16 * 256 * 2);
  float* el    = (float*)alloc((size_t)n * 4 * 4);
  float* er    = (float*)alloc((size_t)n * 4 * 4);
  float* feat4 = (float*)alloc((size_t)n * 8 * 4);
  float* res4  = (float*)alloc((size_t)n * 8 * 4);
  float* el4   = (float*)alloc((size_t)n * 4 * 4);
  float* er4   = (float*)alloc((size_t)n * 4 * 4);
  int* deg     = (int*)alloc((size_t)n * 4);
  int* cur     = (int*)alloc((size_t)n * 4);
  int* rowp    = (int*)alloc((size_t)(n + 1) * 4);
  int* csrc    = (int*)alloc((size_t)e * 4);
  int nb_scan  = (n + 1023) / 1024;
  int* bsum    = (int*)alloc((size_t)(nb_scan + 1) * 4);

  // CSR build
  (void)hipMemsetAsync(deg, 0, (size_t)n * 4, stream);
  (void)hipMemsetAsync(cur, 0, (size_t)n * 4, stream);
  hist_k<<<(e + 255) / 256, 256, 0, stream>>>(dst, deg, e);
  scan1_k<<<nb_scan, 1024, 0, stream>>>(deg, rowp, bsum, n);
  scan2_k<<<1, 64, 0, stream>>>(bsum, nb_scan);
  scan3_k<<<(n + 256) / 256, 256, 0, stream>>>(bsum, rowp, n, nb_scan);
  scatter_k<<<(e + 255) / 256, 256, 0, stream>>>(src, dst, rowp, cur, csrc, e);

  // prep (single launch)
  int nx = n * 128;
  cvtall_k<<<(nx + 167936 + 255) / 256, 256, 0, stream>>>(x, W1, W2, W3, W4, rW4, xb, W1b,
                                                          W2b, W3b, Wcatb, nx);

  dim3 ggrid((n + 127) / 128, 2);
  int nb4 = (n + 3) / 4;

  // layer 1
  gemm_mfma<128><<<ggrid, 256, 0, stream>>>(xb, W1b, featb, al1, ar1, el, er, n);
  agg64_k<0><<<nb4, 256, 0, stream>>>(featb, el, er, rowp, csrc, nullptr, b1, h1b, n);
  // layer 2
  gemm_mfma<256><<<ggrid, 256, 0, stream>>>(h1b, W2b, featb, al2, ar2, el, er, n);
  agg64_k<1><<<nb4, 256, 0, stream>>>(featb, el, er, rowp, csrc, h1b, b2, h2b, n);
  // layer 3
  gemm_mfma<256><<<ggrid, 256, 0, stream>>>(h2b, W3b, featb, al3, ar3, el, er, n);
  agg64_k<1><<<nb4, 256, 0, stream>>>(featb, el, er, rowp, csrc, h2b, b3, h3b, n);
  // layer 4
  int n16 = (n + 15) / 16;
  l4mfma_k<<<(n16 + 3) / 4, 256, 0, stream>>>(h3b, Wcatb, al4, ar4, feat4, res4, el4, er4, n);
  agg4_k<<<nb4, 256, 0, stream>>>(feat4, el4, er4, rowp, csrc, res4, b4, out, n);
}

// Round 9
// 498.846 us; speedup vs baseline: 2.4451x; 1.0198x over previous
//
#include <hip/hip_runtime.h>
#include <hip/hip_bf16.h>
#include <math.h>

// GAT, 4 layers: N=50000, E=800000, IN=128, HID=64, H=4, C=2.
// R9: v_pk_fma_f32 (packed fp32) in agg64 gather via __builtin_elementwise_fma;
// gemm el/er epilogue reductions via DPP (VALU) instead of shfl (DS);
// dispatch diet: hist fused into cvtall, scan2 fused into scan3, one memset.

#define LEAKY_SLOPE 0.2f

typedef __bf16 bf16x8_t __attribute__((ext_vector_type(8)));
typedef float f32x4_t __attribute__((ext_vector_type(4)));
typedef float f32x2_t __attribute__((ext_vector_type(2)));

__device__ __forceinline__ float leaky(float x) { return x > 0.f ? x : LEAKY_SLOPE * x; }
__device__ __forceinline__ float eluf(float x)  { return x > 0.f ? x : expm1f(x); }
__device__ __forceinline__ float bflo(unsigned u) { return __uint_as_float(u << 16); }
__device__ __forceinline__ float bfhi(unsigned u) { return __uint_as_float(u & 0xffff0000u); }

__device__ __forceinline__ int rli(int v, int l) { return __builtin_amdgcn_readlane(v, l); }
__device__ __forceinline__ float rlf(float v, int l) {
  return __uint_as_float((unsigned)__builtin_amdgcn_readlane((int)__float_as_uint(v), l));
}
template <int CTRL>
__device__ __forceinline__ float dpp_add(float x) {
  int t = __builtin_amdgcn_update_dpp(0, (int)__float_as_uint(x), CTRL, 0xf, 0xf, false);
  return x + __uint_as_float((unsigned)t);
}
// full-wave sum (row_shr 1..8 then row_bcast15/31; total in lane 63)
__device__ __forceinline__ float wsum_dpp(float x) {
  x = dpp_add<0x111>(x);
  x = dpp_add<0x112>(x);
  x = dpp_add<0x114>(x);
  x = dpp_add<0x118>(x);
  x = dpp_add<0x142>(x);
  x = dpp_add<0x143>(x);
  return rlf(x, 63);
}
// 16-lane row sum: result valid in lane 15 of each row
__device__ __forceinline__ float rowsum_dpp(float x) {
  x = dpp_add<0x111>(x);
  x = dpp_add<0x112>(x);
  x = dpp_add<0x114>(x);
  x = dpp_add<0x118>(x);
  return x;
}
__device__ __forceinline__ float wmax(float v) {
#pragma unroll
  for (int o = 32; o; o >>= 1) v = fmaxf(v, __shfl_xor(v, o));
  return v;
}
__device__ __forceinline__ float wsum_sh(float v) {
#pragma unroll
  for (int o = 32; o; o >>= 1) v += __shfl_xor(v, o);
  return v;
}

// packed fp32 fma pair: a01 += w01*f01 ; a23 += w23*f23 (v_pk_fma_f32)
__device__ __forceinline__ void edge_fma(f32x2_t& a01, f32x2_t& a23, uint2 u, float4 w) {
  f32x2_t f01 = {bflo(u.x), bfhi(u.x)};
  f32x2_t f23 = {bflo(u.y), bfhi(u.y)};
  f32x2_t w01 = {w.x, w.y};
  f32x2_t w23 = {w.z, w.w};
  a01 = __builtin_elementwise_fma(w01, f01, a01);
  a23 = __builtin_elementwise_fma(w23, f23, a23);
}

// async global->LDS, 16B per lane; LDS dest = wave-uniform base + lane*16
__device__ __forceinline__ void gl_lds16(const __hip_bfloat16* g, __bf16* l) {
  __builtin_amdgcn_global_load_lds((const __attribute__((address_space(1))) void*)g,
                                   (__attribute__((address_space(3))) void*)l, 16, 0, 0);
}

// ---------------- CSR build ----------------
__global__ __launch_bounds__(1024) void scan1_k(const int* __restrict__ deg,
                                                int* __restrict__ rowp,
                                                int* __restrict__ bsum, int n) {
  __shared__ int sd[1024];
  int tid = threadIdx.x;
  int i = blockIdx.x * 1024 + tid;
  int v = (i < n) ? deg[i] : 0;
  int x = v;
  sd[tid] = x;
  __syncthreads();
  for (int off = 1; off < 1024; off <<= 1) {
    int t = (tid >= off) ? sd[tid - off] : 0;
    __syncthreads();
    x += t;
    sd[tid] = x;
    __syncthreads();
  }
  if (i < n) rowp[i] = x - v;
  if (tid == 1023) bsum[blockIdx.x] = x;
}

// scan of block sums (redundant per block) + add offsets; nb <= 64 assumed
__global__ void scan23_k(const int* __restrict__ bsum, int* __restrict__ rowp, int n, int nb) {
  __shared__ int pref[65];
  int tid = threadIdx.x;
  if (tid < 64) {
    int v = (tid < nb) ? bsum[tid] : 0;
    int x = v;
#pragma unroll
    for (int off = 1; off < 64; off <<= 1) {
      int t = __shfl_up(x, off);
      if (tid >= off) x += t;
    }
    pref[tid] = x - v;  // exclusive
    if (tid == 63) pref[64] = x;
  }
  __syncthreads();
  int i = blockIdx.x * 256 + tid;
  if (i < n) rowp[i] += pref[i >> 10];
  if (i == n) rowp[n] = pref[64];
}

__global__ void scatter_k(const int* __restrict__ src, const int* __restrict__ dst,
                          const int* __restrict__ rowp, int* __restrict__ cur,
                          int* __restrict__ csrc, int e) {
  int i = blockIdx.x * 256 + threadIdx.x;
  if (i < e) {
    int d = dst[i];
    int p = atomicAdd(&cur[d], 1);
    csrc[rowp[d] + p] = src[i];
  }
}

// ---------------- prep: cvt (x + weights) fused with dst histogram ----------------
__global__ void cvthist_k(const float* __restrict__ x, const float* __restrict__ W1,
                          const float* __restrict__ W2, const float* __restrict__ W3,
                          const float* __restrict__ W4, const float* __restrict__ rW4,
                          __hip_bfloat16* __restrict__ xb, __hip_bfloat16* __restrict__ W1b,
                          __hip_bfloat16* __restrict__ W2b, __hip_bfloat16* __restrict__ W3b,
                          __hip_bfloat16* __restrict__ Wcatb, int nx,
                          const int* __restrict__ dst, int* __restrict__ deg, int e) {
  int i = blockIdx.x * 256 + threadIdx.x;
  if (i < e) atomicAdd(&deg[dst[i]], 1);
  if (i < nx) { xb[i] = __float2bfloat16(x[i]); return; }
  int j = i - nx;
  if (j < 32768) W1b[j] = __float2bfloat16(W1[j]);
  else if (j < 98304)  { int k = j - 32768;  W2b[k] = __float2bfloat16(W2[k]); }
  else if (j < 163840) { int k = j - 98304;  W3b[k] = __float2bfloat16(W3[k]); }
  else if (j < 165888) { int k = j - 163840; Wcatb[k] = __float2bfloat16(W4[k]); }
  else if (j < 167936) { int k = j - 165888; Wcatb[2048 + k] = __float2bfloat16(rW4[k]); }
}

// ---------------- MFMA GEMM + el/er epilogue ----------------
template <int K>
__global__ __launch_bounds__(256) void gemm_mfma(const __hip_bfloat16* __restrict__ A,
                                                 const __hip_bfloat16* __restrict__ B,
                                                 __hip_bfloat16* __restrict__ featb,
                                                 const float* __restrict__ al,
                                                 const float* __restrict__ ar,
                                                 float* __restrict__ el,
                                                 float* __restrict__ er, int n) {
  __shared__ __bf16 As[128 * 32];
  __shared__ __bf16 Bs[128 * 32];
  const int tid = threadIdx.x;
  const int lane = tid & 63, w = tid >> 6;
  const int tm = lane & 15, tq = lane >> 4;
  const int wm = (w & 1) * 64, wn = (w >> 1) * 64;
  const int r0 = blockIdx.x * 128, c0 = blockIdx.y * 128;

  f32x4_t acc[4][4];
#pragma unroll
  for (int i = 0; i < 4; ++i)
#pragma unroll
    for (int j = 0; j < 4; ++j) acc[i][j] = 0.f;

  const bool interior = (r0 + 128 <= n);
  if (interior) {
    const int srow = w * 32 + (lane >> 2);
    const int scol = (lane & 3) * 8;
    for (int kk = 0; kk < K; kk += 32) {
      __syncthreads();
      const __hip_bfloat16* ga = A + (size_t)(r0 + srow) * K + kk + scol;
      const __hip_bfloat16* gb = B + (size_t)(c0 + srow) * K + kk + scol;
      gl_lds16(ga, As + w * 1024);
      gl_lds16(ga + (size_t)16 * K, As + w * 1024 + 512);
      gl_lds16(gb, Bs + w * 1024);
      gl_lds16(gb + (size_t)16 * K, Bs + w * 1024 + 512);
      __syncthreads();
      bf16x8_t af[4], bfr[4];
#pragma unroll
      for (int i = 0; i < 4; ++i) af[i] = *(const bf16x8_t*)&As[(wm + i * 16 + tm) * 32 + tq * 8];
#pragma unroll
      for (int j = 0; j < 4; ++j) bfr[j] = *(const bf16x8_t*)&Bs[(wn + j * 16 + tm) * 32 + tq * 8];
#pragma unroll
      for (int i = 0; i < 4; ++i)
#pragma unroll
        for (int j = 0; j < 4; ++j)
          acc[i][j] = __builtin_amdgcn_mfma_f32_16x16x32_bf16(af[i], bfr[j], acc[i][j], 0, 0, 0);
    }
  } else {
    const int srow = tid >> 1, sko = (tid & 1) * 16;
    for (int kk = 0; kk < K; kk += 32) {
      uint4 av0 = {0, 0, 0, 0}, av1 = {0, 0, 0, 0};
      int arw = r0 + srow;
      if (arw < n) {
        const uint4* p = (const uint4*)(A + (size_t)arw * K + kk + sko);
        av0 = p[0];
        av1 = p[1];
      }
      const uint4* q = (const uint4*)(B + (size_t)(c0 + srow) * K + kk + sko);
      uint4 bv0 = q[0], bv1 = q[1];
      __syncthreads();
      *(uint4*)&As[srow * 32 + sko] = av0;
      *(uint4*)&As[srow * 32 + sko + 8] = av1;
      *(uint4*)&Bs[srow * 32 + sko] = bv0;
      *(uint4*)&Bs[srow * 32 + sko + 8] = bv1;
      __syncthreads();
      bf16x8_t af[4], bfr[4];
#pragma unroll
      for (int i = 0; i < 4; ++i) af[i] = *(const bf16x8_t*)&As[(wm + i * 16 + tm) * 32 + tq * 8];
#pragma unroll
      for (int j = 0; j < 4; ++j) bfr[j] = *(const bf16x8_t*)&Bs[(wn + j * 16 + tm) * 32 + tq * 8];
#pragma unroll
      for (int i = 0; i < 4; ++i)
#pragma unroll
        for (int j = 0; j < 4; ++j)
          acc[i][j] = __builtin_amdgcn_mfma_f32_16x16x32_bf16(af[i], bfr[j], acc[i][j], 0, 0, 0);
    }
  }

  // featb store
#pragma unroll
  for (int i = 0; i < 4; ++i) {
#pragma unroll
    for (int j = 0; j < 4; ++j) {
      int col = c0 + wn + j * 16 + tm;
      int hh = col >> 6, oo = col & 63;
#pragma unroll
      for (int rr = 0; rr < 4; ++rr) {
        int row = r0 + wm + i * 16 + tq * 4 + rr;
        if (row < n) featb[(size_t)row * 256 + oo * 4 + hh] = __float2bfloat16(acc[i][j][rr]);
      }
    }
  }

  // el/er epilogue: wave owns head hd entirely; row sums via DPP (lane tm==15)
  {
    const int hd = (c0 + wn) >> 6;
    float alv[4], arv[4];
#pragma unroll
    for (int j = 0; j < 4; ++j) {
      alv[j] = al[hd * 64 + j * 16 + tm];
      arv[j] = ar[hd * 64 + j * 16 + tm];
    }
#pragma unroll
    for (int i = 0; i < 4; ++i) {
#pragma unroll
      for (int rr = 0; rr < 4; ++rr) {
        float se = acc[i][0][rr] * alv[0] + acc[i][1][rr] * alv[1] +
                   acc[i][2][rr] * alv[2] + acc[i][3][rr] * alv[3];
        float sr2 = acc[i][0][rr] * arv[0] + acc[i][1][rr] * arv[1] +
                    acc[i][2][rr] * arv[2] + acc[i][3][rr] * arv[3];
        se = rowsum_dpp(se);
        sr2 = rowsum_dpp(sr2);
        if (tm == 15) {
          int row = r0 + wm + i * 16 + tq * 4 + rr;
          if (row < n) {
            el[(size_t)row * 4 + hd] = se;
            er[(size_t)row * 4 + hd] = sr2;
          }
        }
      }
    }
  }
}

// ---------------- aggregate layers 1-3: one wave per dst node ----------------
template <int RES>
__global__ __launch_bounds__(256) void agg64_k(const __hip_bfloat16* __restrict__ featb,
                                               const float* __restrict__ el,
                                               const float* __restrict__ er,
                                               const int* __restrict__ rowp,
                                               const int* __restrict__ csrc,
                                               const __hip_bfloat16* __restrict__ hinb,
                                               const float* __restrict__ bias,
                                               __hip_bfloat16* __restrict__ houtb, int n) {
  __shared__ float wsh[4][256];
  int wv = threadIdx.x >> 6;
  int node = blockIdx.x * 4 + wv;
  int lane = threadIdx.x & 63;
  if (node >= n) return;
  int s0 = rowp[node], s1 = rowp[node + 1];
  int deg = s1 - s0;
  float4 erv = *(const float4*)(er + (size_t)node * 4);
  f32x2_t a01 = {0.f, 0.f}, a23 = {0.f, 0.f};

  if (deg <= 64) {
    // lane owns edge `lane`: unnormalized exp (max-sub is identity), then
    // pre-normalize and stash in LDS; loop reads at wave-uniform addr.
    int sown = 0;
    float x0 = 0.f, x1 = 0.f, x2 = 0.f, x3 = 0.f;
    if (lane < deg) {
      sown = csrc[s0 + lane];
      float4 e = *(const float4*)(el + (size_t)sown * 4);
      x0 = __expf(leaky(e.x + erv.x));
      x1 = __expf(leaky(e.y + erv.y));
      x2 = __expf(leaky(e.z + erv.z));
      x3 = __expf(leaky(e.w + erv.w));
    }
    float d0 = wsum_dpp(x0), d1 = wsum_dpp(x1), d2 = wsum_dpp(x2), d3 = wsum_dpp(x3);
    float i0 = d0 > 0.f ? 1.f / d0 : 0.f;
    float i1 = d1 > 0.f ? 1.f / d1 : 0.f;
    float i2 = d2 > 0.f ? 1.f / d2 : 0.f;
    float i3 = d3 > 0.f ? 1.f / d3 : 0.f;
    float4 wq = {x0 * i0, x1 * i1, x2 * i2, x3 * i3};
    *(float4*)&wsh[wv][lane * 4] = wq;

    int k = 0;
    for (; k + 8 <= deg; k += 8) {
      int sk0 = rli(sown, k + 0), sk1 = rli(sown, k + 1);
      int sk2 = rli(sown, k + 2), sk3 = rli(sown, k + 3);
      int sk4 = rli(sown, k + 4), sk5 = rli(sown, k + 5);
      int sk6 = rli(sown, k + 6), sk7 = rli(sown, k + 7);
      uint2 u0 = ((const uint2*)(featb + ((size_t)sk0 << 8)))[lane];
      uint2 u1 = ((const uint2*)(featb + ((size_t)sk1 << 8)))[lane];
      uint2 u2 = ((const uint2*)(featb + ((size_t)sk2 << 8)))[lane];
      uint2 u3 = ((const uint2*)(featb + ((size_t)sk3 << 8)))[lane];
      uint2 u4 = ((const uint2*)(featb + ((size_t)sk4 << 8)))[lane];
      uint2 u5 = ((const uint2*)(featb + ((size_t)sk5 << 8)))[lane];
      uint2 u6 = ((const uint2*)(featb + ((size_t)sk6 << 8)))[lane];
      uint2 u7 = ((const uint2*)(featb + ((size_t)sk7 << 8)))[lane];
      edge_fma(a01, a23, u0, *(const float4*)&wsh[wv][(k + 0) * 4]);
      edge_fma(a01, a23, u1, *(const float4*)&wsh[wv][(k + 1) * 4]);
      edge_fma(a01, a23, u2, *(const float4*)&wsh[wv][(k + 2) * 4]);
      edge_fma(a01, a23, u3, *(const float4*)&wsh[wv][(k + 3) * 4]);
      edge_fma(a01, a23, u4, *(const float4*)&wsh[wv][(k + 4) * 4]);
      edge_fma(a01, a23, u5, *(const float4*)&wsh[wv][(k + 5) * 4]);
      edge_fma(a01, a23, u6, *(const float4*)&wsh[wv][(k + 6) * 4]);
      edge_fma(a01, a23, u7, *(const float4*)&wsh[wv][(k + 7) * 4]);
    }
    for (; k + 4 <= deg; k += 4) {
      int sk0 = rli(sown, k + 0), sk1 = rli(sown, k + 1);
      int sk2 = rli(sown, k + 2), sk3 = rli(sown, k + 3);
      uint2 u0 = ((const uint2*)(featb + ((size_t)sk0 << 8)))[lane];
      uint2 u1 = ((const uint2*)(featb + ((size_t)sk1 << 8)))[lane];
      uint2 u2 = ((const uint2*)(featb + ((size_t)sk2 << 8)))[lane];
      uint2 u3 = ((const uint2*)(featb + ((size_t)sk3 << 8)))[lane];
      edge_fma(a01, a23, u0, *(const float4*)&wsh[wv][(k + 0) * 4]);
      edge_fma(a01, a23, u1, *(const float4*)&wsh[wv][(k + 1) * 4]);
      edge_fma(a01, a23, u2, *(const float4*)&wsh[wv][(k + 2) * 4]);
      edge_fma(a01, a23, u3, *(const float4*)&wsh[wv][(k + 3) * 4]);
    }
    for (; k < deg; ++k) {
      int sk = rli(sown, k);
      uint2 u = ((const uint2*)(featb + ((size_t)sk << 8)))[lane];
      edge_fma(a01, a23, u, *(const float4*)&wsh[wv][k * 4]);
    }
  } else {
    // fallback (rare): 3-pass with max
    float m0 = -INFINITY, m1 = -INFINITY, m2 = -INFINITY, m3 = -INFINITY;
    for (int k = s0 + lane; k < s1; k += 64) {
      int s = csrc[k];
      float4 e = *(const float4*)(el + (size_t)s * 4);
      m0 = fmaxf(m0, leaky(e.x + erv.x));
      m1 = fmaxf(m1, leaky(e.y + erv.y));
      m2 = fmaxf(m2, leaky(e.z + erv.z));
      m3 = fmaxf(m3, leaky(e.w + erv.w));
    }
    m0 = wmax(m0); m1 = wmax(m1); m2 = wmax(m2); m3 = wmax(m3);
    float d0 = 0, d1 = 0, d2 = 0, d3 = 0;
    for (int k = s0 + lane; k < s1; k += 64) {
      int s = csrc[k];
      float4 e = *(const float4*)(el + (size_t)s * 4);
      d0 += __expf(leaky(e.x + erv.x) - m0);
      d1 += __expf(leaky(e.y + erv.y) - m1);
      d2 += __expf(leaky(e.z + erv.z) - m2);
      d3 += __expf(leaky(e.w + erv.w) - m3);
    }
    d0 = wsum_sh(d0); d1 = wsum_sh(d1); d2 = wsum_sh(d2); d3 = wsum_sh(d3);
    float j0 = d0 > 0.f ? 1.f / d0 : 0.f;
    float j1 = d1 > 0.f ? 1.f / d1 : 0.f;
    float j2 = d2 > 0.f ? 1.f / d2 : 0.f;
    float j3 = d3 > 0.f ? 1.f / d3 : 0.f;
    for (int k = s0; k < s1; ++k) {
      int s = csrc[k];
      float4 e = *(const float4*)(el + (size_t)s * 4);
      float4 wk;
      wk.x = __expf(leaky(e.x + erv.x) - m0) * j0;
      wk.y = __expf(leaky(e.y + erv.y) - m1) * j1;
      wk.z = __expf(leaky(e.z + erv.z) - m2) * j2;
      wk.w = __expf(leaky(e.w + erv.w) - m3) * j3;
      uint2 u = ((const uint2*)(featb + ((size_t)s << 8)))[lane];
      edge_fma(a01, a23, u, wk);
    }
  }

  size_t base = (size_t)node * 256;
  float v0 = a01[0] + bias[lane];
  float v1 = a01[1] + bias[64 + lane];
  float v2 = a23[0] + bias[128 + lane];
  float v3 = a23[1] + bias[192 + lane];
  if (RES) {
    v0 += __bfloat162float(hinb[base + lane]);
    v1 += __bfloat162float(hinb[base + 64 + lane]);
    v2 += __bfloat162float(hinb[base + 128 + lane]);
    v3 += __bfloat162float(hinb[base + 192 + lane]);
  }
  houtb[base + lane]       = __float2bfloat16(eluf(v0));
  houtb[base + 64 + lane]  = __float2bfloat16(eluf(v1));
  houtb[base + 128 + lane] = __float2bfloat16(eluf(v2));
  houtb[base + 192 + lane] = __float2bfloat16(eluf(v3));
}

// ---------------- layer 4 projection (MFMA) + el4/er4 epilogue ----------------
__global__ __launch_bounds__(256) void l4mfma_k(const __hip_bfloat16* __restrict__ hb,
                                                const __hip_bfloat16* __restrict__ Wcat,
                                                const float* __restrict__ al4,
                                                const float* __restrict__ ar4,
                                                float* __restrict__ feat4,
                                                float* __restrict__ res4,
                                                float* __restrict__ el4,
                                                float* __restrict__ er4, int n) {
  int wid = blockIdx.x * 4 + (threadIdx.x >> 6);
  int n16 = (n + 15) >> 4;
  if (wid >= n16) return;
  int lane = threadIdx.x & 63;
  int tm = lane & 15, tq = lane >> 4;
  int row = wid * 16 + tm;
  int rowc = row < n ? row : n - 1;
  const __hip_bfloat16* ap = hb + (size_t)rowc * 256 + tq * 8;
  const __hip_bfloat16* bp = Wcat + (size_t)tm * 256 + tq * 8;
  f32x4_t acc = {0.f, 0.f, 0.f, 0.f};
#pragma unroll
  for (int k = 0; k < 8; ++k) {
    bf16x8_t af = *(const bf16x8_t*)(ap + k * 32);
    bf16x8_t bf = *(const bf16x8_t*)(bp + k * 32);
    acc = __builtin_amdgcn_mfma_f32_16x16x32_bf16(af, bf, acc, 0, 0, 0);
  }
  float* dstp = (tm < 8) ? feat4 : res4;
  int cc = tm & 7;
  float a4 = (tm < 8) ? al4[tm] : 0.f;
  float r4 = (tm < 8) ? ar4[tm] : 0.f;
#pragma unroll
  for (int r = 0; r < 4; ++r) {
    int node = wid * 16 + tq * 4 + r;
    float te = acc[r] * a4;
    float tr = acc[r] * r4;
    te += __shfl_xor(te, 1);
    tr += __shfl_xor(tr, 1);
    if (node < n) {
      dstp[(size_t)node * 8 + cc] = acc[r];
      if (tm < 8 && (tm & 1) == 0) {
        el4[(size_t)node * 4 + (tm >> 1)] = te;
        er4[(size_t)node * 4 + (tm >> 1)] = tr;
      }
    }
  }
}

// ---------------- layer 4 aggregate + per-head softmax + head mean ----------------
__global__ __launch_bounds__(256) void agg4_k(const float* __restrict__ feat4,
                                              const float* __restrict__ el4,
                                              const float* __restrict__ er4,
                                              const int* __restrict__ rowp,
                                              const int* __restrict__ csrc,
                                              const float* __restrict__ res4,
                                              const float* __restrict__ b4,
                                              float* __restrict__ out, int n) {
  __shared__ int ssh[4][64];
  __shared__ float wsh[4][256];
  int wv = threadIdx.x >> 6;
  int node = blockIdx.x * 4 + wv;
  int lane = threadIdx.x & 63;
  if (node >= n) return;
  int s0 = rowp[node], s1 = rowp[node + 1];
  int deg = s1 - s0;
  float4 erv = *(const float4*)(er4 + (size_t)node * 4);
  float acc = 0.f;
  float scale = 1.f;
  int p = lane & 7, hh = p >> 1;

  if (deg <= 64) {
    int sown = 0;
    float x0 = 0.f, x1 = 0.f, x2 = 0.f, x3 = 0.f;
    if (lane < deg) {
      sown = csrc[s0 + lane];
      float4 e = *(const float4*)(el4 + (size_t)sown * 4);
      x0 = __expf(leaky(e.x + erv.x));
      x1 = __expf(leaky(e.y + erv.y));
      x2 = __expf(leaky(e.z + erv.z));
      x3 = __expf(leaky(e.w + erv.w));
    }
    float d0 = wsum_dpp(x0), d1 = wsum_dpp(x1), d2 = wsum_dpp(x2), d3 = wsum_dpp(x3);
    float i0 = d0 > 0.f ? 1.f / d0 : 0.f;
    float i1 = d1 > 0.f ? 1.f / d1 : 0.f;
    float i2 = d2 > 0.f ? 1.f / d2 : 0.f;
    float i3 = d3 > 0.f ? 1.f / d3 : 0.f;
    scale = (hh == 0) ? i0 : (hh == 1) ? i1 : (hh == 2) ? i2 : i3;
    ssh[wv][lane] = sown;
    float4 wq = {x0, x1, x2, x3};
    *(float4*)&wsh[wv][lane * 4] = wq;
    int g = lane >> 3;
    int nt = (deg + 7) >> 3;
    for (int t = 0; t < nt; ++t) {
      int k = g + t * 8;
      bool ok = k < deg;
      int kk = k & 63;
      int sk = ssh[wv][kk];
      float wk = wsh[wv][kk * 4 + hh];
      if (ok) acc = fmaf(wk, feat4[(size_t)sk * 8 + p], acc);
    }
    acc += __shfl_xor(acc, 8);
    acc += __shfl_xor(acc, 16);
    acc += __shfl_xor(acc, 32);
  } else {
    float m0 = -INFINITY, m1 = -INFINITY, m2 = -INFINITY, m3 = -INFINITY;
    for (int k = s0 + lane; k < s1; k += 64) {
      int s = csrc[k];
      float4 e = *(const float4*)(el4 + (size_t)s * 4);
      m0 = fmaxf(m0, leaky(e.x + erv.x));
      m1 = fmaxf(m1, leaky(e.y + erv.y));
      m2 = fmaxf(m2, leaky(e.z + erv.z));
      m3 = fmaxf(m3, leaky(e.w + erv.w));
    }
    m0 = wmax(m0); m1 = wmax(m1); m2 = wmax(m2); m3 = wmax(m3);
    float d0 = 0, d1 = 0, d2 = 0, d3 = 0;
    for (int k = s0 + lane; k < s1; k += 64) {
      int s = csrc[k];
      float4 e = *(const float4*)(el4 + (size_t)s * 4);
      d0 += __expf(leaky(e.x + erv.x) - m0);
      d1 += __expf(leaky(e.y + erv.y) - m1);
      d2 += __expf(leaky(e.z + erv.z) - m2);
      d3 += __expf(leaky(e.w + erv.w) - m3);
    }
    d0 = wsum_sh(d0); d1 = wsum_sh(d1); d2 = wsum_sh(d2); d3 = wsum_sh(d3);
    float i0 = d0 > 0.f ? 1.f / d0 : 0.f;
    float i1 = d1 > 0.f ? 1.f / d1 : 0.f;
    float i2 = d2 > 0.f ? 1.f / d2 : 0.f;
    float i3 = d3 > 0.f ? 1.f / d3 : 0.f;
    for (int k = s0; k < s1; ++k) {
      int s = csrc[k];
      float4 e = *(const float4*)(el4 + (size_t)s * 4);
      float w0 = __expf(leaky(e.x + erv.x) - m0) * i0;
      float w1 = __expf(leaky(e.y + erv.y) - m1) * i1;
      float w2 = __expf(leaky(e.z + erv.z) - m2) * i2;
      float w3 = __expf(leaky(e.w + erv.w) - m3) * i3;
      float wk = (hh == 0) ? w0 : (hh == 1) ? w1 : (hh == 2) ? w2 : w3;
      if (lane < 8) acc = fmaf(wk, feat4[(size_t)s * 8 + p], acc);
    }
  }

  float v = 0.f;
  if (lane < 8) v = acc * scale + res4[(size_t)node * 8 + lane] + b4[lane];
  float pv = __shfl_xor(v, 1);
  float mx = fmaxf(v, pv);
  float ex = __expf(v - mx);
  float sm = ex + __shfl_xor(ex, 1);
  float pr = ex / sm;
  float t = pr + __shfl_xor(pr, 2);
  t += __shfl_xor(t, 4);
  if (lane < 2) out[(size_t)node * 2 + lane] = t * 0.25f;
}

extern "C" void kernel_launch(void* const* d_in, const int* in_sizes, int n_in,
                              void* d_out, int out_size, void* d_ws, size_t ws_size,
                              hipStream_t stream) {
  const float* x   = (const float*)d_in[0];
  const int* src   = (const int*)d_in[1];
  const int* dst   = (const int*)d_in[2];
  const float* W1  = (const float*)d_in[3];
  const float* al1 = (const float*)d_in[4];
  const float* ar1 = (const float*)d_in[5];
  const float* b1  = (const float*)d_in[6];
  const float* W2  = (const float*)d_in[7];
  const float* al2 = (const float*)d_in[8];
  const float* ar2 = (const float*)d_in[9];
  const float* b2  = (const float*)d_in[10];
  const float* W3  = (const float*)d_in[11];
  const float* al3 = (const float*)d_in[12];
  const float* ar3 = (const float*)d_in[13];
  const float* b3  = (const float*)d_in[14];
  const float* W4  = (const float*)d_in[15];
  const float* al4 = (const float*)d_in[16];
  const float* ar4 = (const float*)d_in[17];
  const float* b4  = (const float*)d_in[18];
  const float* rW4 = (const float*)d_in[19];
  float* out = (float*)d_out;

  const int n = in_sizes[0] / 128;  // 50000
  const int e = in_sizes[1];        // 800000

  char* ws = (char*)d_ws;
  auto alloc = [&](size_t bytes) -> char* {
    char* p = ws;
    ws += (bytes + 255) & ~(size_t)255;
    return p;
  };
  __hip_bfloat16* featb = (__hip_bfloat16*)alloc((size_t)n * 256 * 2);
  __hip_bfloat16* h1b   = (__hip_bfloat16*)alloc((size_t)n * 256 * 2);
  __hip_bfloat16* h2b   = (__hip_bfloat16*)alloc((size_t)n * 256 * 2);
  __hip_bfloat16* h3b   = (__hip_bfloat16*)alloc((size_t)n * 256 * 2);
  __hip_bfloat16* xb    = (__hip_bfloat16*)alloc((size_t)n * 128 * 2);
  __hip_bfloat16* W1b   = (__hip_bfloat16*)alloc((size_t)256 * 128 * 2);
  __hip_bfloat16* W2b   = (__hip_bfloat16*)alloc((size_t)256 * 256 * 2);
  __hip_bfloat16* W3b   = (__hip_bfloat16*)alloc((size_t)256 * 256 * 2);
  __hip_bfloat16* Wcatb = (__hip_bfloat16*)alloc((size_t)16 * 256 * 2);
  float* el    = (float*)alloc((size_t)n * 4 * 4);
  float* er    = (float*)alloc((size_t)n * 4 * 4);
  float* feat4 = (float*)alloc((size_t)n * 8 * 4);
  float* res4  = (float*)alloc((size_t)n * 8 * 4);
  float* el4   = (float*)alloc((size_t)n * 4 * 4);
  float* er4   = (float*)alloc((size_t)n * 4 * 4);
  int* deg     = (int*)alloc((size_t)2 * n * 4);  // deg | cur contiguous
  int* cur     = deg + n;
  int* rowp    = (int*)alloc((size_t)(n + 1) * 4);
  int* csrc    = (int*)alloc((size_t)e * 4);
  int nb_scan  = (n + 1023) / 1024;
  int* bsum    = (int*)alloc((size_t)(nb_scan + 1) * 4);

  // zero deg+cur in one shot
  (void)hipMemsetAsync(deg, 0, (size_t)2 * n * 4, stream);

  // prep (cvt + histogram fused)
  int nx = n * 128;
  cvthist_k<<<(nx + 167936 + 255) / 256, 256, 0, stream>>>(x, W1, W2, W3, W4, rW4, xb, W1b,
                                                           W2b, W3b, Wcatb, nx, dst, deg, e);
  // CSR
  scan1_k<<<nb_scan, 1024, 0, stream>>>(deg, rowp, bsum, n);
  scan23_k<<<(n + 256) / 256, 256, 0, stream>>>(bsum, rowp, n, nb_scan);
  scatter_k<<<(e + 255) / 256, 256, 0, stream>>>(src, dst, rowp, cur, csrc, e);

  dim3 ggrid((n + 127) / 128, 2);
  int nb4 = (n + 3) / 4;

  // layer 1
  gemm_mfma<128><<<ggrid, 256, 0, stream>>>(xb, W1b, featb, al1, ar1, el, er, n);
  agg64_k<0><<<nb4, 256, 0, stream>>>(featb, el, er, rowp, csrc, nullptr, b1, h1b, n);
  // layer 2
  gemm_mfma<256><<<ggrid, 256, 0, stream>>>(h1b, W2b, featb, al2, ar2, el, er, n);
  agg64_k<1><<<nb4, 256, 0, stream>>>(featb, el, er, rowp, csrc, h1b, b2, h2b, n);
  // layer 3
  gemm_mfma<256><<<ggrid, 256, 0, stream>>>(h2b, W3b, featb, al3, ar3, el, er, n);
  agg64_k<1><<<nb4, 256, 0, stream>>>(featb, el, er, rowp, csrc, h2b, b3, h3b, n);
  // layer 4
  int n16 = (n + 15) / 16;
  l4mfma_k<<<(n16 + 3) / 4, 256, 0, stream>>>(h3b, Wcatb, al4, ar4, feat4, res4, el4, er4, n);
  agg4_k<<<nb4, 256, 0, stream>>>(feat4, el4, er4, rowp, csrc, res4, b4, out, n);
}

// Round 10
// 496.861 us; speedup vs baseline: 2.4548x; 1.0040x over previous
//
#include <hip/hip_runtime.h>
#include <hip/hip_bf16.h>
#include <math.h>

// GAT, 4 layers: N=50000, E=800000, IN=128, HID=64, H=4, C=2.
// R10: MLP attack. agg64 gathers 2 edges/wave (32-lane x 16B halves; 2x
// outstanding misses, no readlane); agg4 gathers one edge per lane (full
// parallel, 8 DPP wave-sums). gemm/CSR/prep unchanged from R9.

#define LEAKY_SLOPE 0.2f

typedef __bf16 bf16x8_t __attribute__((ext_vector_type(8)));
typedef float f32x4_t __attribute__((ext_vector_type(4)));
typedef float f32x2_t __attribute__((ext_vector_type(2)));

__device__ __forceinline__ float leaky(float x) { return x > 0.f ? x : LEAKY_SLOPE * x; }
__device__ __forceinline__ float eluf(float x)  { return x > 0.f ? x : expm1f(x); }
__device__ __forceinline__ float bflo(unsigned u) { return __uint_as_float(u << 16); }
__device__ __forceinline__ float bfhi(unsigned u) { return __uint_as_float(u & 0xffff0000u); }

__device__ __forceinline__ float rlf(float v, int l) {
  return __uint_as_float((unsigned)__builtin_amdgcn_readlane((int)__float_as_uint(v), l));
}
template <int CTRL>
__device__ __forceinline__ float dpp_add(float x) {
  int t = __builtin_amdgcn_update_dpp(0, (int)__float_as_uint(x), CTRL, 0xf, 0xf, false);
  return x + __uint_as_float((unsigned)t);
}
__device__ __forceinline__ float wsum_dpp(float x) {
  x = dpp_add<0x111>(x);
  x = dpp_add<0x112>(x);
  x = dpp_add<0x114>(x);
  x = dpp_add<0x118>(x);
  x = dpp_add<0x142>(x);
  x = dpp_add<0x143>(x);
  return rlf(x, 63);
}
__device__ __forceinline__ float rowsum_dpp(float x) {
  x = dpp_add<0x111>(x);
  x = dpp_add<0x112>(x);
  x = dpp_add<0x114>(x);
  x = dpp_add<0x118>(x);
  return x;
}
__device__ __forceinline__ float wmax(float v) {
#pragma unroll
  for (int o = 32; o; o >>= 1) v = fmaxf(v, __shfl_xor(v, o));
  return v;
}
__device__ __forceinline__ float wsum_sh(float v) {
#pragma unroll
  for (int o = 32; o; o >>= 1) v += __shfl_xor(v, o);
  return v;
}

// one 2-edge step: u = 8 bf16 (cols 2s,2s+1 x heads 0..3), w = 4 head weights
__device__ __forceinline__ void pair_fma(f32x2_t& c001, f32x2_t& c023, f32x2_t& c101,
                                         f32x2_t& c123, uint4 u, float4 w) {
  f32x2_t w01 = {w.x, w.y}, w23 = {w.z, w.w};
  f32x2_t f;
  f[0] = bflo(u.x); f[1] = bfhi(u.x); c001 = __builtin_elementwise_fma(w01, f, c001);
  f[0] = bflo(u.y); f[1] = bfhi(u.y); c023 = __builtin_elementwise_fma(w23, f, c023);
  f[0] = bflo(u.z); f[1] = bfhi(u.z); c101 = __builtin_elementwise_fma(w01, f, c101);
  f[0] = bflo(u.w); f[1] = bfhi(u.w); c123 = __builtin_elementwise_fma(w23, f, c123);
}

__device__ __forceinline__ void edge_fma(f32x2_t& a01, f32x2_t& a23, uint2 u, float4 w) {
  f32x2_t f01, f23, w01 = {w.x, w.y}, w23 = {w.z, w.w};
  f01[0] = bflo(u.x); f01[1] = bfhi(u.x);
  f23[0] = bflo(u.y); f23[1] = bfhi(u.y);
  a01 = __builtin_elementwise_fma(w01, f01, a01);
  a23 = __builtin_elementwise_fma(w23, f23, a23);
}

// async global->LDS, 16B per lane
__device__ __forceinline__ void gl_lds16(const __hip_bfloat16* g, __bf16* l) {
  __builtin_amdgcn_global_load_lds((const __attribute__((address_space(1))) void*)g,
                                   (__attribute__((address_space(3))) void*)l, 16, 0, 0);
}

// ---------------- CSR build ----------------
__global__ __launch_bounds__(1024) void scan1_k(const int* __restrict__ deg,
                                                int* __restrict__ rowp,
                                                int* __restrict__ bsum, int n) {
  __shared__ int sd[1024];
  int tid = threadIdx.x;
  int i = blockIdx.x * 1024 + tid;
  int v = (i < n) ? deg[i] : 0;
  int x = v;
  sd[tid] = x;
  __syncthreads();
  for (int off = 1; off < 1024; off <<= 1) {
    int t = (tid >= off) ? sd[tid - off] : 0;
    __syncthreads();
    x += t;
    sd[tid] = x;
    __syncthreads();
  }
  if (i < n) rowp[i] = x - v;
  if (tid == 1023) bsum[blockIdx.x] = x;
}

__global__ void scan23_k(const int* __restrict__ bsum, int* __restrict__ rowp, int n, int nb) {
  __shared__ int pref[65];
  int tid = threadIdx.x;
  if (tid < 64) {
    int v = (tid < nb) ? bsum[tid] : 0;
    int x = v;
#pragma unroll
    for (int off = 1; off < 64; off <<= 1) {
      int t = __shfl_up(x, off);
      if (tid >= off) x += t;
    }
    pref[tid] = x - v;
    if (tid == 63) pref[64] = x;
  }
  __syncthreads();
  int i = blockIdx.x * 256 + tid;
  if (i < n) rowp[i] += pref[i >> 10];
  if (i == n) rowp[n] = pref[64];
}

__global__ void scatter_k(const int* __restrict__ src, const int* __restrict__ dst,
                          const int* __restrict__ rowp, int* __restrict__ cur,
                          int* __restrict__ csrc, int e) {
  int i = blockIdx.x * 256 + threadIdx.x;
  if (i < e) {
    int d = dst[i];
    int p = atomicAdd(&cur[d], 1);
    csrc[rowp[d] + p] = src[i];
  }
}

// ---------------- prep: cvt fused with dst histogram ----------------
__global__ void cvthist_k(const float* __restrict__ x, const float* __restrict__ W1,
                          const float* __restrict__ W2, const float* __restrict__ W3,
                          const float* __restrict__ W4, const float* __restrict__ rW4,
                          __hip_bfloat16* __restrict__ xb, __hip_bfloat16* __restrict__ W1b,
                          __hip_bfloat16* __restrict__ W2b, __hip_bfloat16* __restrict__ W3b,
                          __hip_bfloat16* __restrict__ Wcatb, int nx,
                          const int* __restrict__ dst, int* __restrict__ deg, int e) {
  int i = blockIdx.x * 256 + threadIdx.x;
  if (i < e) atomicAdd(&deg[dst[i]], 1);
  if (i < nx) { xb[i] = __float2bfloat16(x[i]); return; }
  int j = i - nx;
  if (j < 32768) W1b[j] = __float2bfloat16(W1[j]);
  else if (j < 98304)  { int k = j - 32768;  W2b[k] = __float2bfloat16(W2[k]); }
  else if (j < 163840) { int k = j - 98304;  W3b[k] = __float2bfloat16(W3[k]); }
  else if (j < 165888) { int k = j - 163840; Wcatb[k] = __float2bfloat16(W4[k]); }
  else if (j < 167936) { int k = j - 165888; Wcatb[2048 + k] = __float2bfloat16(rW4[k]); }
}

// ---------------- MFMA GEMM + el/er epilogue (unchanged from R9) ----------------
template <int K>
__global__ __launch_bounds__(256) void gemm_mfma(const __hip_bfloat16* __restrict__ A,
                                                 const __hip_bfloat16* __restrict__ B,
                                                 __hip_bfloat16* __restrict__ featb,
                                                 const float* __restrict__ al,
                                                 const float* __restrict__ ar,
                                                 float* __restrict__ el,
                                                 float* __restrict__ er, int n) {
  __shared__ __bf16 As[128 * 32];
  __shared__ __bf16 Bs[128 * 32];
  const int tid = threadIdx.x;
  const int lane = tid & 63, w = tid >> 6;
  const int tm = lane & 15, tq = lane >> 4;
  const int wm = (w & 1) * 64, wn = (w >> 1) * 64;
  const int r0 = blockIdx.x * 128, c0 = blockIdx.y * 128;

  f32x4_t acc[4][4];
#pragma unroll
  for (int i = 0; i < 4; ++i)
#pragma unroll
    for (int j = 0; j < 4; ++j) acc[i][j] = 0.f;

  const bool interior = (r0 + 128 <= n);
  if (interior) {
    const int srow = w * 32 + (lane >> 2);
    const int scol = (lane & 3) * 8;
    for (int kk = 0; kk < K; kk += 32) {
      __syncthreads();
      const __hip_bfloat16* ga = A + (size_t)(r0 + srow) * K + kk + scol;
      const __hip_bfloat16* gb = B + (size_t)(c0 + srow) * K + kk + scol;
      gl_lds16(ga, As + w * 1024);
      gl_lds16(ga + (size_t)16 * K, As + w * 1024 + 512);
      gl_lds16(gb, Bs + w * 1024);
      gl_lds16(gb + (size_t)16 * K, Bs + w * 1024 + 512);
      __syncthreads();
      bf16x8_t af[4], bfr[4];
#pragma unroll
      for (int i = 0; i < 4; ++i) af[i] = *(const bf16x8_t*)&As[(wm + i * 16 + tm) * 32 + tq * 8];
#pragma unroll
      for (int j = 0; j < 4; ++j) bfr[j] = *(const bf16x8_t*)&Bs[(wn + j * 16 + tm) * 32 + tq * 8];
#pragma unroll
      for (int i = 0; i < 4; ++i)
#pragma unroll
        for (int j = 0; j < 4; ++j)
          acc[i][j] = __builtin_amdgcn_mfma_f32_16x16x32_bf16(af[i], bfr[j], acc[i][j], 0, 0, 0);
    }
  } else {
    const int srow = tid >> 1, sko = (tid & 1) * 16;
    for (int kk = 0; kk < K; kk += 32) {
      uint4 av0 = {0, 0, 0, 0}, av1 = {0, 0, 0, 0};
      int arw = r0 + srow;
      if (arw < n) {
        const uint4* p = (const uint4*)(A + (size_t)arw * K + kk + sko);
        av0 = p[0];
        av1 = p[1];
      }
      const uint4* q = (const uint4*)(B + (size_t)(c0 + srow) * K + kk + sko);
      uint4 bv0 = q[0], bv1 = q[1];
      __syncthreads();
      *(uint4*)&As[srow * 32 + sko] = av0;
      *(uint4*)&As[srow * 32 + sko + 8] = av1;
      *(uint4*)&Bs[srow * 32 + sko] = bv0;
      *(uint4*)&Bs[srow * 32 + sko + 8] = bv1;
      __syncthreads();
      bf16x8_t af[4], bfr[4];
#pragma unroll
      for (int i = 0; i < 4; ++i) af[i] = *(const bf16x8_t*)&As[(wm + i * 16 + tm) * 32 + tq * 8];
#pragma unroll
      for (int j = 0; j < 4; ++j) bfr[j] = *(const bf16x8_t*)&Bs[(wn + j * 16 + tm) * 32 + tq * 8];
#pragma unroll
      for (int i = 0; i < 4; ++i)
#pragma unroll
        for (int j = 0; j < 4; ++j)
          acc[i][j] = __builtin_amdgcn_mfma_f32_16x16x32_bf16(af[i], bfr[j], acc[i][j], 0, 0, 0);
    }
  }

#pragma unroll
  for (int i = 0; i < 4; ++i) {
#pragma unroll
    for (int j = 0; j < 4; ++j) {
      int col = c0 + wn + j * 16 + tm;
      int hh = col >> 6, oo = col & 63;
#pragma unroll
      for (int rr = 0; rr < 4; ++rr) {
        int row = r0 + wm + i * 16 + tq * 4 + rr;
        if (row < n) featb[(size_t)row * 256 + oo * 4 + hh] = __float2bfloat16(acc[i][j][rr]);
      }
    }
  }

  {
    const int hd = (c0 + wn) >> 6;
    float alv[4], arv[4];
#pragma unroll
    for (int j = 0; j < 4; ++j) {
      alv[j] = al[hd * 64 + j * 16 + tm];
      arv[j] = ar[hd * 64 + j * 16 + tm];
    }
#pragma unroll
    for (int i = 0; i < 4; ++i) {
#pragma unroll
      for (int rr = 0; rr < 4; ++rr) {
        float se = acc[i][0][rr] * alv[0] + acc[i][1][rr] * alv[1] +
                   acc[i][2][rr] * alv[2] + acc[i][3][rr] * alv[3];
        float sr2 = acc[i][0][rr] * arv[0] + acc[i][1][rr] * arv[1] +
                    acc[i][2][rr] * arv[2] + acc[i][3][rr] * arv[3];
        se = rowsum_dpp(se);
        sr2 = rowsum_dpp(sr2);
        if (tm == 15) {
          int row = r0 + wm + i * 16 + tq * 4 + rr;
          if (row < n) {
            el[(size_t)row * 4 + hd] = se;
            er[(size_t)row * 4 + hd] = sr2;
          }
        }
      }
    }
  }
}

// ---------------- aggregate layers 1-3: one wave per dst node, 2 edges/step ----------------
template <int RES>
__global__ __launch_bounds__(256) void agg64_k(const __hip_bfloat16* __restrict__ featb,
                                               const float* __restrict__ el,
                                               const float* __restrict__ er,
                                               const int* __restrict__ rowp,
                                               const int* __restrict__ csrc,
                                               const __hip_bfloat16* __restrict__ hinb,
                                               const float* __restrict__ bias,
                                               __hip_bfloat16* __restrict__ houtb, int n) {
  __shared__ float wsh[4][256];
  __shared__ int ssh[4][64];
  int wv = threadIdx.x >> 6;
  int node = blockIdx.x * 4 + wv;
  int lane = threadIdx.x & 63;
  if (node >= n) return;
  int s0 = rowp[node], s1 = rowp[node + 1];
  int deg = s1 - s0;
  float4 erv = *(const float4*)(er + (size_t)node * 4);

  if (deg <= 64) {
    // lane owns edge `lane`: unnormalized exp (max-sub identity), normalize,
    // stash weights + src idx in LDS.
    int sown = 0;
    float x0 = 0.f, x1 = 0.f, x2 = 0.f, x3 = 0.f;
    if (lane < deg) {
      sown = csrc[s0 + lane];
      float4 e = *(const float4*)(el + (size_t)sown * 4);
      x0 = __expf(leaky(e.x + erv.x));
      x1 = __expf(leaky(e.y + erv.y));
      x2 = __expf(leaky(e.z + erv.z));
      x3 = __expf(leaky(e.w + erv.w));
    }
    float d0 = wsum_dpp(x0), d1 = wsum_dpp(x1), d2 = wsum_dpp(x2), d3 = wsum_dpp(x3);
    float i0 = d0 > 0.f ? 1.f / d0 : 0.f;
    float i1 = d1 > 0.f ? 1.f / d1 : 0.f;
    float i2 = d2 > 0.f ? 1.f / d2 : 0.f;
    float i3 = d3 > 0.f ? 1.f / d3 : 0.f;
    float4 wq = {x0 * i0, x1 * i1, x2 * i2, x3 * i3};
    *(float4*)&wsh[wv][lane * 4] = wq;
    ssh[wv][lane] = sown;

    // 2 edges per step: half h handles edge k+h; 32 lanes x 16B per edge row.
    const int half = lane >> 5, sub = lane & 31;
    f32x2_t c001 = {0.f, 0.f}, c023 = {0.f, 0.f};  // col 2sub   (h01, h23)
    f32x2_t c101 = {0.f, 0.f}, c123 = {0.f, 0.f};  // col 2sub+1 (h01, h23)
    int k = 0;
    for (; k + 8 <= deg; k += 8) {
      int ke = k + half;
      int sk0 = ssh[wv][ke], sk1 = ssh[wv][ke + 2];
      int sk2 = ssh[wv][ke + 4], sk3 = ssh[wv][ke + 6];
      uint4 u0 = ((const uint4*)(featb + ((size_t)sk0 << 8)))[sub];
      uint4 u1 = ((const uint4*)(featb + ((size_t)sk1 << 8)))[sub];
      uint4 u2 = ((const uint4*)(featb + ((size_t)sk2 << 8)))[sub];
      uint4 u3 = ((const uint4*)(featb + ((size_t)sk3 << 8)))[sub];
      float4 w0 = *(const float4*)&wsh[wv][(ke)*4];
      float4 w1 = *(const float4*)&wsh[wv][(ke + 2) * 4];
      float4 w2 = *(const float4*)&wsh[wv][(ke + 4) * 4];
      float4 w3 = *(const float4*)&wsh[wv][(ke + 6) * 4];
      pair_fma(c001, c023, c101, c123, u0, w0);
      pair_fma(c001, c023, c101, c123, u1, w1);
      pair_fma(c001, c023, c101, c123, u2, w2);
      pair_fma(c001, c023, c101, c123, u3, w3);
    }
    for (; k < deg; k += 2) {
      int ke = k + half;  // ke <= 63 always; OOB edges have weight 0, src 0
      int sk = ssh[wv][ke];
      uint4 u = ((const uint4*)(featb + ((size_t)sk << 8)))[sub];
      float4 w = *(const float4*)&wsh[wv][ke * 4];
      pair_fma(c001, c023, c101, c123, u, w);
    }
    // combine halves
    c001[0] += __shfl_xor(c001[0], 32); c001[1] += __shfl_xor(c001[1], 32);
    c023[0] += __shfl_xor(c023[0], 32); c023[1] += __shfl_xor(c023[1], 32);
    c101[0] += __shfl_xor(c101[0], 32); c101[1] += __shfl_xor(c101[1], 32);
    c123[0] += __shfl_xor(c123[0], 32); c123[1] += __shfl_xor(c123[1], 32);

    // epilogue: half H writes heads 2H,2H+1 for cols 2sub,2sub+1
    size_t base = (size_t)node * 256;
    int hA = half * 2, hB = hA + 1;
    int colo = sub * 2;
    float pa0 = half ? c023[0] : c001[0];  // (col 2s, hA)
    float pa1 = half ? c123[0] : c101[0];  // (col 2s+1, hA)
    float pb0 = half ? c023[1] : c001[1];  // (col 2s, hB)
    float pb1 = half ? c123[1] : c101[1];
    float vA0 = pa0 + bias[hA * 64 + colo];
    float vA1 = pa1 + bias[hA * 64 + colo + 1];
    float vB0 = pb0 + bias[hB * 64 + colo];
    float vB1 = pb1 + bias[hB * 64 + colo + 1];
    if (RES) {
      unsigned rA = *(const unsigned*)(hinb + base + hA * 64 + colo);
      unsigned rB = *(const unsigned*)(hinb + base + hB * 64 + colo);
      vA0 += bflo(rA); vA1 += bfhi(rA);
      vB0 += bflo(rB); vB1 += bfhi(rB);
    }
    __hip_bfloat162 oA, oB;
    oA.x = __float2bfloat16(eluf(vA0)); oA.y = __float2bfloat16(eluf(vA1));
    oB.x = __float2bfloat16(eluf(vB0)); oB.y = __float2bfloat16(eluf(vB1));
    *(__hip_bfloat162*)(houtb + base + hA * 64 + colo) = oA;
    *(__hip_bfloat162*)(houtb + base + hB * 64 + colo) = oB;
  } else {
    // fallback (rare): 3-pass with max, col-per-lane layout
    f32x2_t a01 = {0.f, 0.f}, a23 = {0.f, 0.f};
    float m0 = -INFINITY, m1 = -INFINITY, m2 = -INFINITY, m3 = -INFINITY;
    for (int k = s0 + lane; k < s1; k += 64) {
      int s = csrc[k];
      float4 e = *(const float4*)(el + (size_t)s * 4);
      m0 = fmaxf(m0, leaky(e.x + erv.x));
      m1 = fmaxf(m1, leaky(e.y + erv.y));
      m2 = fmaxf(m2, leaky(e.z + erv.z));
      m3 = fmaxf(m3, leaky(e.w + erv.w));
    }
    m0 = wmax(m0); m1 = wmax(m1); m2 = wmax(m2); m3 = wmax(m3);
    float d0 = 0, d1 = 0, d2 = 0, d3 = 0;
    for (int k = s0 + lane; k < s1; k += 64) {
      int s = csrc[k];
      float4 e = *(const float4*)(el + (size_t)s * 4);
      d0 += __expf(leaky(e.x + erv.x) - m0);
      d1 += __expf(leaky(e.y + erv.y) - m1);
      d2 += __expf(leaky(e.z + erv.z) - m2);
      d3 += __expf(leaky(e.w + erv.w) - m3);
    }
    d0 = wsum_sh(d0); d1 = wsum_sh(d1); d2 = wsum_sh(d2); d3 = wsum_sh(d3);
    float j0 = d0 > 0.f ? 1.f / d0 : 0.f;
    float j1 = d1 > 0.f ? 1.f / d1 : 0.f;
    float j2 = d2 > 0.f ? 1.f / d2 : 0.f;
    float j3 = d3 > 0.f ? 1.f / d3 : 0.f;
    for (int k = s0; k < s1; ++k) {
      int s = csrc[k];
      float4 e = *(const float4*)(el + (size_t)s * 4);
      float4 wk;
      wk.x = __expf(leaky(e.x + erv.x) - m0) * j0;
      wk.y = __expf(leaky(e.y + erv.y) - m1) * j1;
      wk.z = __expf(leaky(e.z + erv.z) - m2) * j2;
      wk.w = __expf(leaky(e.w + erv.w) - m3) * j3;
      uint2 u = ((const uint2*)(featb + ((size_t)s << 8)))[lane];
      edge_fma(a01, a23, u, wk);
    }
    size_t base = (size_t)node * 256;
    float v0 = a01[0] + bias[lane];
    float v1 = a01[1] + bias[64 + lane];
    float v2 = a23[0] + bias[128 + lane];
    float v3 = a23[1] + bias[192 + lane];
    if (RES) {
      v0 += __bfloat162float(hinb[base + lane]);
      v1 += __bfloat162float(hinb[base + 64 + lane]);
      v2 += __bfloat162float(hinb[base + 128 + lane]);
      v3 += __bfloat162float(hinb[base + 192 + lane]);
    }
    houtb[base + lane]       = __float2bfloat16(eluf(v0));
    houtb[base + 64 + lane]  = __float2bfloat16(eluf(v1));
    houtb[base + 128 + lane] = __float2bfloat16(eluf(v2));
    houtb[base + 192 + lane] = __float2bfloat16(eluf(v3));
  }
}

// ---------------- layer 4 projection (MFMA) + el4/er4 epilogue ----------------
__global__ __launch_bounds__(256) void l4mfma_k(const __hip_bfloat16* __restrict__ hb,
                                                const __hip_bfloat16* __restrict__ Wcat,
                                                const float* __restrict__ al4,
                                                const float* __restrict__ ar4,
                                                float* __restrict__ feat4,
                                                float* __restrict__ res4,
                                                float* __restrict__ el4,
                                                float* __restrict__ er4, int n) {
  int wid = blockIdx.x * 4 + (threadIdx.x >> 6);
  int n16 = (n + 15) >> 4;
  if (wid >= n16) return;
  int lane = threadIdx.x & 63;
  int tm = lane & 15, tq = lane >> 4;
  int row = wid * 16 + tm;
  int rowc = row < n ? row : n - 1;
  const __hip_bfloat16* ap = hb + (size_t)rowc * 256 + tq * 8;
  const __hip_bfloat16* bp = Wcat + (size_t)tm * 256 + tq * 8;
  f32x4_t acc = {0.f, 0.f, 0.f, 0.f};
#pragma unroll
  for (int k = 0; k < 8; ++k) {
    bf16x8_t af = *(const bf16x8_t*)(ap + k * 32);
    bf16x8_t bf = *(const bf16x8_t*)(bp + k * 32);
    acc = __builtin_amdgcn_mfma_f32_16x16x32_bf16(af, bf, acc, 0, 0, 0);
  }
  float* dstp = (tm < 8) ? feat4 : res4;
  int cc = tm & 7;
  float a4 = (tm < 8) ? al4[tm] : 0.f;
  float r4 = (tm < 8) ? ar4[tm] : 0.f;
#pragma unroll
  for (int r = 0; r < 4; ++r) {
    int node = wid * 16 + tq * 4 + r;
    float te = acc[r] * a4;
    float tr = acc[r] * r4;
    te += __shfl_xor(te, 1);
    tr += __shfl_xor(tr, 1);
    if (node < n) {
      dstp[(size_t)node * 8 + cc] = acc[r];
      if (tm < 8 && (tm & 1) == 0) {
        el4[(size_t)node * 4 + (tm >> 1)] = te;
        er4[(size_t)node * 4 + (tm >> 1)] = tr;
      }
    }
  }
}

// ---------------- layer 4 aggregate: one edge per lane, fully parallel ----------------
__global__ __launch_bounds__(256) void agg4_k(const float* __restrict__ feat4,
                                              const float* __restrict__ el4,
                                              const float* __restrict__ er4,
                                              const int* __restrict__ rowp,
                                              const int* __restrict__ csrc,
                                              const float* __restrict__ res4,
                                              const float* __restrict__ b4,
                                              float* __restrict__ out, int n) {
  int wv = threadIdx.x >> 6;
  int node = blockIdx.x * 4 + wv;
  int lane = threadIdx.x & 63;
  if (node >= n) return;
  int s0 = rowp[node], s1 = rowp[node + 1];
  int deg = s1 - s0;
  float4 erv = *(const float4*)(er4 + (size_t)node * 4);
  float v = 0.f;

  if (deg <= 64) {
    int sown = 0;
    float x0 = 0.f, x1 = 0.f, x2 = 0.f, x3 = 0.f;
    if (lane < deg) {
      sown = csrc[s0 + lane];
      float4 e = *(const float4*)(el4 + (size_t)sown * 4);
      x0 = __expf(leaky(e.x + erv.x));
      x1 = __expf(leaky(e.y + erv.y));
      x2 = __expf(leaky(e.z + erv.z));
      x3 = __expf(leaky(e.w + erv.w));
    }
    float d0 = wsum_dpp(x0), d1 = wsum_dpp(x1), d2 = wsum_dpp(x2), d3 = wsum_dpp(x3);
    float w0 = x0 * (d0 > 0.f ? 1.f / d0 : 0.f);
    float w1 = x1 * (d1 > 0.f ? 1.f / d1 : 0.f);
    float w2 = x2 * (d2 > 0.f ? 1.f / d2 : 0.f);
    float w3 = x3 * (d3 > 0.f ? 1.f / d3 : 0.f);
    // lane loads its own edge's full feat4 row (32B) — all edges in parallel
    float4 f0 = {0, 0, 0, 0}, f1 = {0, 0, 0, 0};
    if (lane < deg) {
      const float4* fp = (const float4*)(feat4 + (size_t)sown * 8);
      f0 = fp[0];
      f1 = fp[1];
    }
    float t0 = w0 * f0.x, t1 = w0 * f0.y;
    float t2 = w1 * f0.z, t3 = w1 * f0.w;
    float t4 = w2 * f1.x, t5 = w2 * f1.y;
    float t6 = w3 * f1.z, t7 = w3 * f1.w;
    t0 = wsum_dpp(t0); t1 = wsum_dpp(t1); t2 = wsum_dpp(t2); t3 = wsum_dpp(t3);
    t4 = wsum_dpp(t4); t5 = wsum_dpp(t5); t6 = wsum_dpp(t6); t7 = wsum_dpp(t7);
    int p = lane & 7;
    float s = t0;
    s = (p == 1) ? t1 : s; s = (p == 2) ? t2 : s; s = (p == 3) ? t3 : s;
    s = (p == 4) ? t4 : s; s = (p == 5) ? t5 : s; s = (p == 6) ? t6 : s;
    s = (p == 7) ? t7 : s;
    if (lane < 8) v = s + res4[(size_t)node * 8 + lane] + b4[lane];
  } else {
    int p = lane & 7, hh = p >> 1;
    float acc = 0.f;
    float m0 = -INFINITY, m1 = -INFINITY, m2 = -INFINITY, m3 = -INFINITY;
    for (int k = s0 + lane; k < s1; k += 64) {
      int s = csrc[k];
      float4 e = *(const float4*)(el4 + (size_t)s * 4);
      m0 = fmaxf(m0, leaky(e.x + erv.x));
      m1 = fmaxf(m1, leaky(e.y + erv.y));
      m2 = fmaxf(m2, leaky(e.z + erv.z));
      m3 = fmaxf(m3, leaky(e.w + erv.w));
    }
    m0 = wmax(m0); m1 = wmax(m1); m2 = wmax(m2); m3 = wmax(m3);
    float d0 = 0, d1 = 0, d2 = 0, d3 = 0;
    for (int k = s0 + lane; k < s1; k += 64) {
      int s = csrc[k];
      float4 e = *(const float4*)(el4 + (size_t)s * 4);
      d0 += __expf(leaky(e.x + erv.x) - m0);
      d1 += __expf(leaky(e.y + erv.y) - m1);
      d2 += __expf(leaky(e.z + erv.z) - m2);
      d3 += __expf(leaky(e.w + erv.w) - m3);
    }
    d0 = wsum_sh(d0); d1 = wsum_sh(d1); d2 = wsum_sh(d2); d3 = wsum_sh(d3);
    float i0 = d0 > 0.f ? 1.f / d0 : 0.f;
    float i1 = d1 > 0.f ? 1.f / d1 : 0.f;
    float i2 = d2 > 0.f ? 1.f / d2 : 0.f;
    float i3 = d3 > 0.f ? 1.f / d3 : 0.f;
    for (int k = s0; k < s1; ++k) {
      int s = csrc[k];
      float4 e = *(const float4*)(el4 + (size_t)s * 4);
      float w0 = __expf(leaky(e.x + erv.x) - m0) * i0;
      float w1 = __expf(leaky(e.y + erv.y) - m1) * i1;
      float w2 = __expf(leaky(e.z + erv.z) - m2) * i2;
      float w3 = __expf(leaky(e.w + erv.w) - m3) * i3;
      float wk = (hh == 0) ? w0 : (hh == 1) ? w1 : (hh == 2) ? w2 : w3;
      if (lane < 8) acc = fmaf(wk, feat4[(size_t)s * 8 + p], acc);
    }
    if (lane < 8) v = acc + res4[(size_t)node * 8 + lane] + b4[lane];
  }

  float pv = __shfl_xor(v, 1);
  float mx = fmaxf(v, pv);
  float ex = __expf(v - mx);
  float sm = ex + __shfl_xor(ex, 1);
  float pr = ex / sm;
  float t = pr + __shfl_xor(pr, 2);
  t += __shfl_xor(t, 4);
  if (lane < 2) out[(size_t)node * 2 + lane] = t * 0.25f;
}

extern "C" void kernel_launch(void* const* d_in, const int* in_sizes, int n_in,
                              void* d_out, int out_size, void* d_ws, size_t ws_size,
                              hipStream_t stream) {
  const float* x   = (const float*)d_in[0];
  const int* src   = (const int*)d_in[1];
  const int* dst   = (const int*)d_in[2];
  const float* W1  = (const float*)d_in[3];
  const float* al1 = (const float*)d_in[4];
  const float* ar1 = (const float*)d_in[5];
  const float* b1  = (const float*)d_in[6];
  const float* W2  = (const float*)d_in[7];
  const float* al2 = (const float*)d_in[8];
  const float* ar2 = (const float*)d_in[9];
  const float* b2  = (const float*)d_in[10];
  const float* W3  = (const float*)d_in[11];
  const float* al3 = (const float*)d_in[12];
  const float* ar3 = (const float*)d_in[13];
  const float* b3  = (const float*)d_in[14];
  const float* W4  = (const float*)d_in[15];
  const float* al4 = (const float*)d_in[16];
  const float* ar4 = (const float*)d_in[17];
  const float* b4  = (const float*)d_in[18];
  const float* rW4 = (const float*)d_in[19];
  float* out = (float*)d_out;

  const int n = in_sizes[0] / 128;  // 50000
  const int e = in_sizes[1];        // 800000

  char* ws = (char*)d_ws;
  auto alloc = [&](size_t bytes) -> char* {
    char* p = ws;
    ws += (bytes + 255) & ~(size_t)255;
    return p;
  };
  __hip_bfloat16* featb = (__hip_bfloat16*)alloc((size_t)n * 256 * 2);
  __hip_bfloat16* h1b   = (__hip_bfloat16*)alloc((size_t)n * 256 * 2);
  __hip_bfloat16* h2b   = (__hip_bfloat16*)alloc((size_t)n * 256 * 2);
  __hip_bfloat16* h3b   = (__hip_bfloat16*)alloc((size_t)n * 256 * 2);
  __hip_bfloat16* xb    = (__hip_bfloat16*)alloc((size_t)n * 128 * 2);
  __hip_bfloat16* W1b   = (__hip_bfloat16*)alloc((size_t)256 * 128 * 2);
  __hip_bfloat16* W2b   = (__hip_bfloat16*)alloc((size_t)256 * 256 * 2);
  __hip_bfloat16* W3b   = (__hip_bfloat16*)alloc((size_t)256 * 256 * 2);
  __hip_bfloat16* Wcatb = (__hip_bfloat16*)alloc((size_t)16 * 256 * 2);
  float* el    = (float*)alloc((size_t)n * 4 * 4);
  float* er    = (float*)alloc((size_t)n * 4 * 4);
  float* feat4 = (float*)alloc((size_t)n * 8 * 4);
  float* res4  = (float*)alloc((size_t)n * 8 * 4);
  float* el4   = (float*)alloc((size_t)n * 4 * 4);
  float* er4   = (float*)alloc((size_t)n * 4 * 4);
  int* deg     = (int*)alloc((size_t)2 * n * 4);
  int* cur     = deg + n;
  int* rowp    = (int*)alloc((size_t)(n + 1) * 4);
  int* csrc    = (int*)alloc((size_t)e * 4);
  int nb_scan  = (n + 1023) / 1024;
  int* bsum    = (int*)alloc((size_t)(nb_scan + 1) * 4);

  (void)hipMemsetAsync(deg, 0, (size_t)2 * n * 4, stream);

  int nx = n * 128;
  cvthist_k<<<(nx + 167936 + 255) / 256, 256, 0, stream>>>(x, W1, W2, W3, W4, rW4, xb, W1b,
                                                           W2b, W3b, Wcatb, nx, dst, deg, e);
  scan1_k<<<nb_scan, 1024, 0, stream>>>(deg, rowp, bsum, n);
  scan23_k<<<(n + 256) / 256, 256, 0, stream>>>(bsum, rowp, n, nb_scan);
  scatter_k<<<(e + 255) / 256, 256, 0, stream>>>(src, dst, rowp, cur, csrc, e);

  dim3 ggrid((n + 127) / 128, 2);
  int nb4 = (n + 3) / 4;

  // layer 1
  gemm_mfma<128><<<ggrid, 256, 0, stream>>>(xb, W1b, featb, al1, ar1, el, er, n);
  agg64_k<0><<<nb4, 256, 0, stream>>>(featb, el, er, rowp, csrc, nullptr, b1, h1b, n);
  // layer 2
  gemm_mfma<256><<<ggrid, 256, 0, stream>>>(h1b, W2b, featb, al2, ar2, el, er, n);
  agg64_k<1><<<nb4, 256, 0, stream>>>(featb, el, er, rowp, csrc, h1b, b2, h2b, n);
  // layer 3
  gemm_mfma<256><<<ggrid, 256, 0, stream>>>(h2b, W3b, featb, al3, ar3, el, er, n);
  agg64_k<1><<<nb4, 256, 0, stream>>>(featb, el, er, rowp, csrc, h2b, b3, h3b, n);
  // layer 4
  int n16 = (n + 15) / 16;
  l4mfma_k<<<(n16 + 3) / 4, 256, 0, stream>>>(h3b, Wcatb, al4, ar4, feat4, res4, el4, er4, n);
  agg4_k<<<nb4, 256, 0, stream>>>(feat4, el4, er4, rowp, csrc, res4, b4, out, n);
}

// Round 11
// 488.765 us; speedup vs baseline: 2.4955x; 1.0166x over previous
//
#include <hip/hip_runtime.h>
#include <hip/hip_bf16.h>
#include <math.h>

// GAT, 4 layers: N=50000, E=800000, IN=128, HID=64, H=4, C=2.
// R11: featb goes row-major [n][h*64+o] (same layout as h buffers).
// gemm featb-store: 2B-stride-8 scatter -> 32B contiguous runs.
// agg64 gather: 2 edges/wave, sub-lane owns 8 cols of one head (scalar
// weight, 4 pk_fma/edge), contiguous 16B/lane epilogue stores.

#define LEAKY_SLOPE 0.2f

typedef __bf16 bf16x8_t __attribute__((ext_vector_type(8)));
typedef float f32x4_t __attribute__((ext_vector_type(4)));
typedef float f32x2_t __attribute__((ext_vector_type(2)));

__device__ __forceinline__ float leaky(float x) { return x > 0.f ? x : LEAKY_SLOPE * x; }
__device__ __forceinline__ float eluf(float x)  { return x > 0.f ? x : expm1f(x); }
__device__ __forceinline__ float bflo(unsigned u) { return __uint_as_float(u << 16); }
__device__ __forceinline__ float bfhi(unsigned u) { return __uint_as_float(u & 0xffff0000u); }
__device__ __forceinline__ unsigned pk2(float a, float b) {
  __hip_bfloat162 t;
  t.x = __float2bfloat16(a);
  t.y = __float2bfloat16(b);
  return *(unsigned*)&t;
}

__device__ __forceinline__ float rlf(float v, int l) {
  return __uint_as_float((unsigned)__builtin_amdgcn_readlane((int)__float_as_uint(v), l));
}
template <int CTRL>
__device__ __forceinline__ float dpp_add(float x) {
  int t = __builtin_amdgcn_update_dpp(0, (int)__float_as_uint(x), CTRL, 0xf, 0xf, false);
  return x + __uint_as_float((unsigned)t);
}
__device__ __forceinline__ float wsum_dpp(float x) {
  x = dpp_add<0x111>(x);
  x = dpp_add<0x112>(x);
  x = dpp_add<0x114>(x);
  x = dpp_add<0x118>(x);
  x = dpp_add<0x142>(x);
  x = dpp_add<0x143>(x);
  return rlf(x, 63);
}
__device__ __forceinline__ float rowsum_dpp(float x) {
  x = dpp_add<0x111>(x);
  x = dpp_add<0x112>(x);
  x = dpp_add<0x114>(x);
  x = dpp_add<0x118>(x);
  return x;
}
__device__ __forceinline__ float wmax(float v) {
#pragma unroll
  for (int o = 32; o; o >>= 1) v = fmaxf(v, __shfl_xor(v, o));
  return v;
}
__device__ __forceinline__ float wsum_sh(float v) {
#pragma unroll
  for (int o = 32; o; o >>= 1) v += __shfl_xor(v, o);
  return v;
}

// 8-col fma: u = 8 consecutive bf16 of one head, scalar weight w
__device__ __forceinline__ void quad_fma(f32x2_t& a0, f32x2_t& a1, f32x2_t& a2, f32x2_t& a3,
                                         uint4 u, float w) {
  f32x2_t wv = {w, w};
  f32x2_t f;
  f[0] = bflo(u.x); f[1] = bfhi(u.x); a0 = __builtin_elementwise_fma(wv, f, a0);
  f[0] = bflo(u.y); f[1] = bfhi(u.y); a1 = __builtin_elementwise_fma(wv, f, a1);
  f[0] = bflo(u.z); f[1] = bfhi(u.z); a2 = __builtin_elementwise_fma(wv, f, a2);
  f[0] = bflo(u.w); f[1] = bfhi(u.w); a3 = __builtin_elementwise_fma(wv, f, a3);
}

// async global->LDS, 16B per lane
__device__ __forceinline__ void gl_lds16(const __hip_bfloat16* g, __bf16* l) {
  __builtin_amdgcn_global_load_lds((const __attribute__((address_space(1))) void*)g,
                                   (__attribute__((address_space(3))) void*)l, 16, 0, 0);
}

// ---------------- CSR build ----------------
__global__ __launch_bounds__(1024) void scan1_k(const int* __restrict__ deg,
                                                int* __restrict__ rowp,
                                                int* __restrict__ bsum, int n) {
  __shared__ int sd[1024];
  int tid = threadIdx.x;
  int i = blockIdx.x * 1024 + tid;
  int v = (i < n) ? deg[i] : 0;
  int x = v;
  sd[tid] = x;
  __syncthreads();
  for (int off = 1; off < 1024; off <<= 1) {
    int t = (tid >= off) ? sd[tid - off] : 0;
    __syncthreads();
    x += t;
    sd[tid] = x;
    __syncthreads();
  }
  if (i < n) rowp[i] = x - v;
  if (tid == 1023) bsum[blockIdx.x] = x;
}

__global__ void scan23_k(const int* __restrict__ bsum, int* __restrict__ rowp, int n, int nb) {
  __shared__ int pref[65];
  int tid = threadIdx.x;
  if (tid < 64) {
    int v = (tid < nb) ? bsum[tid] : 0;
    int x = v;
#pragma unroll
    for (int off = 1; off < 64; off <<= 1) {
      int t = __shfl_up(x, off);
      if (tid >= off) x += t;
    }
    pref[tid] = x - v;
    if (tid == 63) pref[64] = x;
  }
  __syncthreads();
  int i = blockIdx.x * 256 + tid;
  if (i < n) rowp[i] += pref[i >> 10];
  if (i == n) rowp[n] = pref[64];
}

__global__ void scatter_k(const int* __restrict__ src, const int* __restrict__ dst,
                          const int* __restrict__ rowp, int* __restrict__ cur,
                          int* __restrict__ csrc, int e) {
  int i = blockIdx.x * 256 + threadIdx.x;
  if (i < e) {
    int d = dst[i];
    int p = atomicAdd(&cur[d], 1);
    csrc[rowp[d] + p] = src[i];
  }
}

// ---------------- prep: cvt fused with dst histogram ----------------
__global__ void cvthist_k(const float* __restrict__ x, const float* __restrict__ W1,
                          const float* __restrict__ W2, const float* __restrict__ W3,
                          const float* __restrict__ W4, const float* __restrict__ rW4,
                          __hip_bfloat16* __restrict__ xb, __hip_bfloat16* __restrict__ W1b,
                          __hip_bfloat16* __restrict__ W2b, __hip_bfloat16* __restrict__ W3b,
                          __hip_bfloat16* __restrict__ Wcatb, int nx,
                          const int* __restrict__ dst, int* __restrict__ deg, int e) {
  int i = blockIdx.x * 256 + threadIdx.x;
  if (i < e) atomicAdd(&deg[dst[i]], 1);
  if (i < nx) { xb[i] = __float2bfloat16(x[i]); return; }
  int j = i - nx;
  if (j < 32768) W1b[j] = __float2bfloat16(W1[j]);
  else if (j < 98304)  { int k = j - 32768;  W2b[k] = __float2bfloat16(W2[k]); }
  else if (j < 163840) { int k = j - 98304;  W3b[k] = __float2bfloat16(W3[k]); }
  else if (j < 165888) { int k = j - 163840; Wcatb[k] = __float2bfloat16(W4[k]); }
  else if (j < 167936) { int k = j - 165888; Wcatb[2048 + k] = __float2bfloat16(rW4[k]); }
}

// ---------------- MFMA GEMM + el/er epilogue; featb row-major [n][256] ----------------
template <int K>
__global__ __launch_bounds__(256) void gemm_mfma(const __hip_bfloat16* __restrict__ A,
                                                 const __hip_bfloat16* __restrict__ B,
                                                 __hip_bfloat16* __restrict__ featb,
                                                 const float* __restrict__ al,
                                                 const float* __restrict__ ar,
                                                 float* __restrict__ el,
                                                 float* __restrict__ er, int n) {
  __shared__ __bf16 As[128 * 32];
  __shared__ __bf16 Bs[128 * 32];
  const int tid = threadIdx.x;
  const int lane = tid & 63, w = tid >> 6;
  const int tm = lane & 15, tq = lane >> 4;
  const int wm = (w & 1) * 64, wn = (w >> 1) * 64;
  const int r0 = blockIdx.x * 128, c0 = blockIdx.y * 128;

  f32x4_t acc[4][4];
#pragma unroll
  for (int i = 0; i < 4; ++i)
#pragma unroll
    for (int j = 0; j < 4; ++j) acc[i][j] = 0.f;

  const bool interior = (r0 + 128 <= n);
  if (interior) {
    const int srow = w * 32 + (lane >> 2);
    const int scol = (lane & 3) * 8;
    for (int kk = 0; kk < K; kk += 32) {
      __syncthreads();
      const __hip_bfloat16* ga = A + (size_t)(r0 + srow) * K + kk + scol;
      const __hip_bfloat16* gb = B + (size_t)(c0 + srow) * K + kk + scol;
      gl_lds16(ga, As + w * 1024);
      gl_lds16(ga + (size_t)16 * K, As + w * 1024 + 512);
      gl_lds16(gb, Bs + w * 1024);
      gl_lds16(gb + (size_t)16 * K, Bs + w * 1024 + 512);
      __syncthreads();
      bf16x8_t af[4], bfr[4];
#pragma unroll
      for (int i = 0; i < 4; ++i) af[i] = *(const bf16x8_t*)&As[(wm + i * 16 + tm) * 32 + tq * 8];
#pragma unroll
      for (int j = 0; j < 4; ++j) bfr[j] = *(const bf16x8_t*)&Bs[(wn + j * 16 + tm) * 32 + tq * 8];
#pragma unroll
      for (int i = 0; i < 4; ++i)
#pragma unroll
        for (int j = 0; j < 4; ++j)
          acc[i][j] = __builtin_amdgcn_mfma_f32_16x16x32_bf16(af[i], bfr[j], acc[i][j], 0, 0, 0);
    }
  } else {
    const int srow = tid >> 1, sko = (tid & 1) * 16;
    for (int kk = 0; kk < K; kk += 32) {
      uint4 av0 = {0, 0, 0, 0}, av1 = {0, 0, 0, 0};
      int arw = r0 + srow;
      if (arw < n) {
        const uint4* p = (const uint4*)(A + (size_t)arw * K + kk + sko);
        av0 = p[0];
        av1 = p[1];
      }
      const uint4* q = (const uint4*)(B + (size_t)(c0 + srow) * K + kk + sko);
      uint4 bv0 = q[0], bv1 = q[1];
      __syncthreads();
      *(uint4*)&As[srow * 32 + sko] = av0;
      *(uint4*)&As[srow * 32 + sko + 8] = av1;
      *(uint4*)&Bs[srow * 32 + sko] = bv0;
      *(uint4*)&Bs[srow * 32 + sko + 8] = bv1;
      __syncthreads();
      bf16x8_t af[4], bfr[4];
#pragma unroll
      for (int i = 0; i < 4; ++i) af[i] = *(const bf16x8_t*)&As[(wm + i * 16 + tm) * 32 + tq * 8];
#pragma unroll
      for (int j = 0; j < 4; ++j) bfr[j] = *(const bf16x8_t*)&Bs[(wn + j * 16 + tm) * 32 + tq * 8];
#pragma unroll
      for (int i = 0; i < 4; ++i)
#pragma unroll
        for (int j = 0; j < 4; ++j)
          acc[i][j] = __builtin_amdgcn_mfma_f32_16x16x32_bf16(af[i], bfr[j], acc[i][j], 0, 0, 0);
    }
  }

  // featb store, row-major: col = c0+wn+j*16+tm; 16 consecutive lanes -> 32B runs
#pragma unroll
  for (int i = 0; i < 4; ++i) {
#pragma unroll
    for (int j = 0; j < 4; ++j) {
      int col = c0 + wn + j * 16 + tm;
#pragma unroll
      for (int rr = 0; rr < 4; ++rr) {
        int row = r0 + wm + i * 16 + tq * 4 + rr;
        if (row < n) featb[(size_t)row * 256 + col] = __float2bfloat16(acc[i][j][rr]);
      }
    }
  }

  // el/er epilogue: wave owns head hd entirely; row sums via DPP (lane tm==15)
  {
    const int hd = (c0 + wn) >> 6;
    float alv[4], arv[4];
#pragma unroll
    for (int j = 0; j < 4; ++j) {
      alv[j] = al[hd * 64 + j * 16 + tm];
      arv[j] = ar[hd * 64 + j * 16 + tm];
    }
#pragma unroll
    for (int i = 0; i < 4; ++i) {
#pragma unroll
      for (int rr = 0; rr < 4; ++rr) {
        float se = acc[i][0][rr] * alv[0] + acc[i][1][rr] * alv[1] +
                   acc[i][2][rr] * alv[2] + acc[i][3][rr] * alv[3];
        float sr2 = acc[i][0][rr] * arv[0] + acc[i][1][rr] * arv[1] +
                    acc[i][2][rr] * arv[2] + acc[i][3][rr] * arv[3];
        se = rowsum_dpp(se);
        sr2 = rowsum_dpp(sr2);
        if (tm == 15) {
          int row = r0 + wm + i * 16 + tq * 4 + rr;
          if (row < n) {
            el[(size_t)row * 4 + hd] = se;
            er[(size_t)row * 4 + hd] = sr2;
          }
        }
      }
    }
  }
}

// ---------------- aggregate layers 1-3: one wave per dst node, 2 edges/step ----------------
// featb row-major: sub-lane s owns cols 8s..8s+7 (head s>>3), scalar weight.
template <int RES>
__global__ __launch_bounds__(256) void agg64_k(const __hip_bfloat16* __restrict__ featb,
                                               const float* __restrict__ el,
                                               const float* __restrict__ er,
                                               const int* __restrict__ rowp,
                                               const int* __restrict__ csrc,
                                               const __hip_bfloat16* __restrict__ hinb,
                                               const float* __restrict__ bias,
                                               __hip_bfloat16* __restrict__ houtb, int n) {
  __shared__ float wsh[4][256];
  __shared__ int ssh[4][64];
  int wv = threadIdx.x >> 6;
  int node = blockIdx.x * 4 + wv;
  int lane = threadIdx.x & 63;
  if (node >= n) return;
  int s0 = rowp[node], s1 = rowp[node + 1];
  int deg = s1 - s0;
  float4 erv = *(const float4*)(er + (size_t)node * 4);

  if (deg <= 64) {
    // lane owns edge `lane`: unnormalized exp (max-sub identity), normalize,
    // stash weights + src idx in LDS.
    int sown = 0;
    float x0 = 0.f, x1 = 0.f, x2 = 0.f, x3 = 0.f;
    if (lane < deg) {
      sown = csrc[s0 + lane];
      float4 e = *(const float4*)(el + (size_t)sown * 4);
      x0 = __expf(leaky(e.x + erv.x));
      x1 = __expf(leaky(e.y + erv.y));
      x2 = __expf(leaky(e.z + erv.z));
      x3 = __expf(leaky(e.w + erv.w));
    }
    float d0 = wsum_dpp(x0), d1 = wsum_dpp(x1), d2 = wsum_dpp(x2), d3 = wsum_dpp(x3);
    float i0 = d0 > 0.f ? 1.f / d0 : 0.f;
    float i1 = d1 > 0.f ? 1.f / d1 : 0.f;
    float i2 = d2 > 0.f ? 1.f / d2 : 0.f;
    float i3 = d3 > 0.f ? 1.f / d3 : 0.f;
    float4 wq = {x0 * i0, x1 * i1, x2 * i2, x3 * i3};
    *(float4*)&wsh[wv][lane * 4] = wq;
    ssh[wv][lane] = sown;

    // 2 edges/step: half h -> edge k+h; sub-lane s -> bytes 16s..16s+15 of row
    const int half = lane >> 5, sub = lane & 31;
    const int hh = sub >> 3;
    f32x2_t a0 = {0.f, 0.f}, a1 = {0.f, 0.f}, a2 = {0.f, 0.f}, a3 = {0.f, 0.f};
    int k = 0;
    for (; k + 8 <= deg; k += 8) {
      int ke = k + half;
      int sk0 = ssh[wv][ke], sk1 = ssh[wv][ke + 2];
      int sk2 = ssh[wv][ke + 4], sk3 = ssh[wv][ke + 6];
      uint4 u0 = ((const uint4*)(featb + ((size_t)sk0 << 8)))[sub];
      uint4 u1 = ((const uint4*)(featb + ((size_t)sk1 << 8)))[sub];
      uint4 u2 = ((const uint4*)(featb + ((size_t)sk2 << 8)))[sub];
      uint4 u3 = ((const uint4*)(featb + ((size_t)sk3 << 8)))[sub];
      float w0 = wsh[wv][ke * 4 + hh];
      float w1 = wsh[wv][(ke + 2) * 4 + hh];
      float w2 = wsh[wv][(ke + 4) * 4 + hh];
      float w3 = wsh[wv][(ke + 6) * 4 + hh];
      quad_fma(a0, a1, a2, a3, u0, w0);
      quad_fma(a0, a1, a2, a3, u1, w1);
      quad_fma(a0, a1, a2, a3, u2, w2);
      quad_fma(a0, a1, a2, a3, u3, w3);
    }
    for (; k < deg; k += 2) {
      int ke = k + half;  // OOB edges: weight 0, src 0
      int sk = ssh[wv][ke];
      uint4 u = ((const uint4*)(featb + ((size_t)sk << 8)))[sub];
      float wk = wsh[wv][ke * 4 + hh];
      quad_fma(a0, a1, a2, a3, u, wk);
    }
    // combine halves
    a0[0] += __shfl_xor(a0[0], 32); a0[1] += __shfl_xor(a0[1], 32);
    a1[0] += __shfl_xor(a1[0], 32); a1[1] += __shfl_xor(a1[1], 32);
    a2[0] += __shfl_xor(a2[0], 32); a2[1] += __shfl_xor(a2[1], 32);
    a3[0] += __shfl_xor(a3[0], 32); a3[1] += __shfl_xor(a3[1], 32);

    // epilogue: lanes 0-31 write cols 8s..8s+7 (16B contiguous per lane)
    if (half == 0) {
      size_t base = (size_t)node * 256 + sub * 8;
      float v0 = a0[0], v1 = a0[1], v2 = a1[0], v3 = a1[1];
      float v4 = a2[0], v5 = a2[1], v6 = a3[0], v7 = a3[1];
      float4 b0 = *(const float4*)(bias + sub * 8);
      float4 b1 = *(const float4*)(bias + sub * 8 + 4);
      v0 += b0.x; v1 += b0.y; v2 += b0.z; v3 += b0.w;
      v4 += b1.x; v5 += b1.y; v6 += b1.z; v7 += b1.w;
      if (RES) {
        uint4 r = *(const uint4*)(hinb + base);
        v0 += bflo(r.x); v1 += bfhi(r.x);
        v2 += bflo(r.y); v3 += bfhi(r.y);
        v4 += bflo(r.z); v5 += bfhi(r.z);
        v6 += bflo(r.w); v7 += bfhi(r.w);
      }
      uint4 o;
      o.x = pk2(eluf(v0), eluf(v1));
      o.y = pk2(eluf(v2), eluf(v3));
      o.z = pk2(eluf(v4), eluf(v5));
      o.w = pk2(eluf(v6), eluf(v7));
      *(uint4*)(houtb + base) = o;
    }
  } else {
    // fallback (rare): 3-pass with max; lane owns cols 4l..4l+3 (head l>>4)
    int hsel = lane >> 4;
    f32x2_t a01 = {0.f, 0.f}, a23 = {0.f, 0.f};
    float m0 = -INFINITY, m1 = -INFINITY, m2 = -INFINITY, m3 = -INFINITY;
    for (int k = s0 + lane; k < s1; k += 64) {
      int s = csrc[k];
      float4 e = *(const float4*)(el + (size_t)s * 4);
      m0 = fmaxf(m0, leaky(e.x + erv.x));
      m1 = fmaxf(m1, leaky(e.y + erv.y));
      m2 = fmaxf(m2, leaky(e.z + erv.z));
      m3 = fmaxf(m3, leaky(e.w + erv.w));
    }
    m0 = wmax(m0); m1 = wmax(m1); m2 = wmax(m2); m3 = wmax(m3);
    float d0 = 0, d1 = 0, d2 = 0, d3 = 0;
    for (int k = s0 + lane; k < s1; k += 64) {
      int s = csrc[k];
      float4 e = *(const float4*)(el + (size_t)s * 4);
      d0 += __expf(leaky(e.x + erv.x) - m0);
      d1 += __expf(leaky(e.y + erv.y) - m1);
      d2 += __expf(leaky(e.z + erv.z) - m2);
      d3 += __expf(leaky(e.w + erv.w) - m3);
    }
    d0 = wsum_sh(d0); d1 = wsum_sh(d1); d2 = wsum_sh(d2); d3 = wsum_sh(d3);
    float j0 = d0 > 0.f ? 1.f / d0 : 0.f;
    float j1 = d1 > 0.f ? 1.f / d1 : 0.f;
    float j2 = d2 > 0.f ? 1.f / d2 : 0.f;
    float j3 = d3 > 0.f ? 1.f / d3 : 0.f;
    for (int k = s0; k < s1; ++k) {
      int s = csrc[k];
      float4 e = *(const float4*)(el + (size_t)s * 4);
      float w0 = __expf(leaky(e.x + erv.x) - m0) * j0;
      float w1 = __expf(leaky(e.y + erv.y) - m1) * j1;
      float w2 = __expf(leaky(e.z + erv.z) - m2) * j2;
      float w3 = __expf(leaky(e.w + erv.w) - m3) * j3;
      float wk = (hsel == 0) ? w0 : (hsel == 1) ? w1 : (hsel == 2) ? w2 : w3;
      uint2 u = ((const uint2*)(featb + ((size_t)s << 8)))[lane];
      f32x2_t wv2 = {wk, wk};
      f32x2_t f;
      f[0] = bflo(u.x); f[1] = bfhi(u.x); a01 = __builtin_elementwise_fma(wv2, f, a01);
      f[0] = bflo(u.y); f[1] = bfhi(u.y); a23 = __builtin_elementwise_fma(wv2, f, a23);
    }
    size_t base = (size_t)node * 256 + lane * 4;
    float4 bv = *(const float4*)(bias + lane * 4);
    float v0 = a01[0] + bv.x, v1 = a01[1] + bv.y;
    float v2 = a23[0] + bv.z, v3 = a23[1] + bv.w;
    if (RES) {
      uint2 r = *(const uint2*)(hinb + base);
      v0 += bflo(r.x); v1 += bfhi(r.x);
      v2 += bflo(r.y); v3 += bfhi(r.y);
    }
    uint2 o;
    o.x = pk2(eluf(v0), eluf(v1));
    o.y = pk2(eluf(v2), eluf(v3));
    *(uint2*)(houtb + base) = o;
  }
}

// ---------------- layer 4 projection (MFMA) + el4/er4 epilogue ----------------
__global__ __launch_bounds__(256) void l4mfma_k(const __hip_bfloat16* __restrict__ hb,
                                                const __hip_bfloat16* __restrict__ Wcat,
                                                const float* __restrict__ al4,
                                                const float* __restrict__ ar4,
                                                float* __restrict__ feat4,
                                                float* __restrict__ res4,
                                                float* __restrict__ el4,
                                                float* __restrict__ er4, int n) {
  int wid = blockIdx.x * 4 + (threadIdx.x >> 6);
  int n16 = (n + 15) >> 4;
  if (wid >= n16) return;
  int lane = threadIdx.x & 63;
  int tm = lane & 15, tq = lane >> 4;
  int row = wid * 16 + tm;
  int rowc = row < n ? row : n - 1;
  const __hip_bfloat16* ap = hb + (size_t)rowc * 256 + tq * 8;
  const __hip_bfloat16* bp = Wcat + (size_t)tm * 256 + tq * 8;
  f32x4_t acc = {0.f, 0.f, 0.f, 0.f};
#pragma unroll
  for (int k = 0; k < 8; ++k) {
    bf16x8_t af = *(const bf16x8_t*)(ap + k * 32);
    bf16x8_t bf = *(const bf16x8_t*)(bp + k * 32);
    acc = __builtin_amdgcn_mfma_f32_16x16x32_bf16(af, bf, acc, 0, 0, 0);
  }
  float* dstp = (tm < 8) ? feat4 : res4;
  int cc = tm & 7;
  float a4 = (tm < 8) ? al4[tm] : 0.f;
  float r4 = (tm < 8) ? ar4[tm] : 0.f;
#pragma unroll
  for (int r = 0; r < 4; ++r) {
    int node = wid * 16 + tq * 4 + r;
    float te = acc[r] * a4;
    float tr = acc[r] * r4;
    te += __shfl_xor(te, 1);
    tr += __shfl_xor(tr, 1);
    if (node < n) {
      dstp[(size_t)node * 8 + cc] = acc[r];
      if (tm < 8 && (tm & 1) == 0) {
        el4[(size_t)node * 4 + (tm >> 1)] = te;
        er4[(size_t)node * 4 + (tm >> 1)] = tr;
      }
    }
  }
}

// ---------------- layer 4 aggregate: one edge per lane, fully parallel ----------------
__global__ __launch_bounds__(256) void agg4_k(const float* __restrict__ feat4,
                                              const float* __restrict__ el4,
                                              const float* __restrict__ er4,
                                              const int* __restrict__ rowp,
                                              const int* __restrict__ csrc,
                                              const float* __restrict__ res4,
                                              const float* __restrict__ b4,
                                              float* __restrict__ out, int n) {
  int wv = threadIdx.x >> 6;
  int node = blockIdx.x * 4 + wv;
  int lane = threadIdx.x & 63;
  if (node >= n) return;
  int s0 = rowp[node], s1 = rowp[node + 1];
  int deg = s1 - s0;
  float4 erv = *(const float4*)(er4 + (size_t)node * 4);
  float v = 0.f;

  if (deg <= 64) {
    int sown = 0;
    float x0 = 0.f, x1 = 0.f, x2 = 0.f, x3 = 0.f;
    if (lane < deg) {
      sown = csrc[s0 + lane];
      float4 e = *(const float4*)(el4 + (size_t)sown * 4);
      x0 = __expf(leaky(e.x + erv.x));
      x1 = __expf(leaky(e.y + erv.y));
      x2 = __expf(leaky(e.z + erv.z));
      x3 = __expf(leaky(e.w + erv.w));
    }
    float d0 = wsum_dpp(x0), d1 = wsum_dpp(x1), d2 = wsum_dpp(x2), d3 = wsum_dpp(x3);
    float w0 = x0 * (d0 > 0.f ? 1.f / d0 : 0.f);
    float w1 = x1 * (d1 > 0.f ? 1.f / d1 : 0.f);
    float w2 = x2 * (d2 > 0.f ? 1.f / d2 : 0.f);
    float w3 = x3 * (d3 > 0.f ? 1.f / d3 : 0.f);
    float4 f0 = {0, 0, 0, 0}, f1 = {0, 0, 0, 0};
    if (lane < deg) {
      const float4* fp = (const float4*)(feat4 + (size_t)sown * 8);
      f0 = fp[0];
      f1 = fp[1];
    }
    float t0 = w0 * f0.x, t1 = w0 * f0.y;
    float t2 = w1 * f0.z, t3 = w1 * f0.w;
    float t4 = w2 * f1.x, t5 = w2 * f1.y;
    float t6 = w3 * f1.z, t7 = w3 * f1.w;
    t0 = wsum_dpp(t0); t1 = wsum_dpp(t1); t2 = wsum_dpp(t2); t3 = wsum_dpp(t3);
    t4 = wsum_dpp(t4); t5 = wsum_dpp(t5); t6 = wsum_dpp(t6); t7 = wsum_dpp(t7);
    int p = lane & 7;
    float s = t0;
    s = (p == 1) ? t1 : s; s = (p == 2) ? t2 : s; s = (p == 3) ? t3 : s;
    s = (p == 4) ? t4 : s; s = (p == 5) ? t5 : s; s = (p == 6) ? t6 : s;
    s = (p == 7) ? t7 : s;
    if (lane < 8) v = s + res4[(size_t)node * 8 + lane] + b4[lane];
  } else {
    int p = lane & 7, hh = p >> 1;
    float acc = 0.f;
    float m0 = -INFINITY, m1 = -INFINITY, m2 = -INFINITY, m3 = -INFINITY;
    for (int k = s0 + lane; k < s1; k += 64) {
      int s = csrc[k];
      float4 e = *(const float4*)(el4 + (size_t)s * 4);
      m0 = fmaxf(m0, leaky(e.x + erv.x));
      m1 = fmaxf(m1, leaky(e.y + erv.y));
      m2 = fmaxf(m2, leaky(e.z + erv.z));
      m3 = fmaxf(m3, leaky(e.w + erv.w));
    }
    m0 = wmax(m0); m1 = wmax(m1); m2 = wmax(m2); m3 = wmax(m3);
    float d0 = 0, d1 = 0, d2 = 0, d3 = 0;
    for (int k = s0 + lane; k < s1; k += 64) {
      int s = csrc[k];
      float4 e = *(const float4*)(el4 + (size_t)s * 4);
      d0 += __expf(leaky(e.x + erv.x) - m0);
      d1 += __expf(leaky(e.y + erv.y) - m1);
      d2 += __expf(leaky(e.z + erv.z) - m2);
      d3 += __expf(leaky(e.w + erv.w) - m3);
    }
    d0 = wsum_sh(d0); d1 = wsum_sh(d1); d2 = wsum_sh(d2); d3 = wsum_sh(d3);
    float i0 = d0 > 0.f ? 1.f / d0 : 0.f;
    float i1 = d1 > 0.f ? 1.f / d1 : 0.f;
    float i2 = d2 > 0.f ? 1.f / d2 : 0.f;
    float i3 = d3 > 0.f ? 1.f / d3 : 0.f;
    for (int k = s0; k < s1; ++k) {
      int s = csrc[k];
      float4 e = *(const float4*)(el4 + (size_t)s * 4);
      float w0 = __expf(leaky(e.x + erv.x) - m0) * i0;
      float w1 = __expf(leaky(e.y + erv.y) - m1) * i1;
      float w2 = __expf(leaky(e.z + erv.z) - m2) * i2;
      float w3 = __expf(leaky(e.w + erv.w) - m3) * i3;
      float wk = (hh == 0) ? w0 : (hh == 1) ? w1 : (hh == 2) ? w2 : w3;
      if (lane < 8) acc = fmaf(wk, feat4[(size_t)s * 8 + p], acc);
    }
    if (lane < 8) v = acc + res4[(size_t)node * 8 + lane] + b4[lane];
  }

  float pv = __shfl_xor(v, 1);
  float mx = fmaxf(v, pv);
  float ex = __expf(v - mx);
  float sm = ex + __shfl_xor(ex, 1);
  float pr = ex / sm;
  float t = pr + __shfl_xor(pr, 2);
  t += __shfl_xor(t, 4);
  if (lane < 2) out[(size_t)node * 2 + lane] = t * 0.25f;
}

extern "C" void kernel_launch(void* const* d_in, const int* in_sizes, int n_in,
                              void* d_out, int out_size, void* d_ws, size_t ws_size,
                              hipStream_t stream) {
  const float* x   = (const float*)d_in[0];
  const int* src   = (const int*)d_in[1];
  const int* dst   = (const int*)d_in[2];
  const float* W1  = (const float*)d_in[3];
  const float* al1 = (const float*)d_in[4];
  const float* ar1 = (const float*)d_in[5];
  const float* b1  = (const float*)d_in[6];
  const float* W2  = (const float*)d_in[7];
  const float* al2 = (const float*)d_in[8];
  const float* ar2 = (const float*)d_in[9];
  const float* b2  = (const float*)d_in[10];
  const float* W3  = (const float*)d_in[11];
  const float* al3 = (const float*)d_in[12];
  const float* ar3 = (const float*)d_in[13];
  const float* b3  = (const float*)d_in[14];
  const float* W4  = (const float*)d_in[15];
  const float* al4 = (const float*)d_in[16];
  const float* ar4 = (const float*)d_in[17];
  const float* b4  = (const float*)d_in[18];
  const float* rW4 = (const float*)d_in[19];
  float* out = (float*)d_out;

  const int n = in_sizes[0] / 128;  // 50000
  const int e = in_sizes[1];        // 800000

  char* ws = (char*)d_ws;
  auto alloc = [&](size_t bytes) -> char* {
    char* p = ws;
    ws += (bytes + 255) & ~(size_t)255;
    return p;
  };
  __hip_bfloat16* featb = (__hip_bfloat16*)alloc((size_t)n * 256 * 2);
  __hip_bfloat16* h1b   = (__hip_bfloat16*)alloc((size_t)n * 256 * 2);
  __hip_bfloat16* h2b   = (__hip_bfloat16*)alloc((size_t)n * 256 * 2);
  __hip_bfloat16* h3b   = (__hip_bfloat16*)alloc((size_t)n * 256 * 2);
  __hip_bfloat16* xb    = (__hip_bfloat16*)alloc((size_t)n * 128 * 2);
  __hip_bfloat16* W1b   = (__hip_bfloat16*)alloc((size_t)256 * 128 * 2);
  __hip_bfloat16* W2b   = (__hip_bfloat16*)alloc((size_t)256 * 256 * 2);
  __hip_bfloat16* W3b   = (__hip_bfloat16*)alloc((size_t)256 * 256 * 2);
  __hip_bfloat16* Wcatb = (__hip_bfloat16*)alloc((size_t)16 * 256 * 2);
  float* el    = (float*)alloc((size_t)n * 4 * 4);
  float* er    = (float*)alloc((size_t)n * 4 * 4);
  float* feat4 = (float*)alloc((size_t)n * 8 * 4);
  float* res4  = (float*)alloc((size_t)n * 8 * 4);
  float* el4   = (float*)alloc((size_t)n * 4 * 4);
  float* er4   = (float*)alloc((size_t)n * 4 * 4);
  int* deg     = (int*)alloc((size_t)2 * n * 4);
  int* cur     = deg + n;
  int* rowp    = (int*)alloc((size_t)(n + 1) * 4);
  int* csrc    = (int*)alloc((size_t)e * 4);
  int nb_scan  = (n + 1023) / 1024;
  int* bsum    = (int*)alloc((size_t)(nb_scan + 1) * 4);

  (void)hipMemsetAsync(deg, 0, (size_t)2 * n * 4, stream);

  int nx = n * 128;
  cvthist_k<<<(nx + 167936 + 255) / 256, 256, 0, stream>>>(x, W1, W2, W3, W4, rW4, xb, W1b,
                                                           W2b, W3b, Wcatb, nx, dst, deg, e);
  scan1_k<<<nb_scan, 1024, 0, stream>>>(deg, rowp, bsum, n);
  scan23_k<<<(n + 256) / 256, 256, 0, stream>>>(bsum, rowp, n, nb_scan);
  scatter_k<<<(e + 255) / 256, 256, 0, stream>>>(src, dst, rowp, cur, csrc, e);

  dim3 ggrid((n + 127) / 128, 2);
  int nb4 = (n + 3) / 4;

  // layer 1
  gemm_mfma<128><<<ggrid, 256, 0, stream>>>(xb, W1b, featb, al1, ar1, el, er, n);
  agg64_k<0><<<nb4, 256, 0, stream>>>(featb, el, er, rowp, csrc, nullptr, b1, h1b, n);
  // layer 2
  gemm_mfma<256><<<ggrid, 256, 0, stream>>>(h1b, W2b, featb, al2, ar2, el, er, n);
  agg64_k<1><<<nb4, 256, 0, stream>>>(featb, el, er, rowp, csrc, h1b, b2, h2b, n);
  // layer 3
  gemm_mfma<256><<<ggrid, 256, 0, stream>>>(h2b, W3b, featb, al3, ar3, el, er, n);
  agg64_k<1><<<nb4, 256, 0, stream>>>(featb, el, er, rowp, csrc, h2b, b3, h3b, n);
  // layer 4
  int n16 = (n + 15) / 16;
  l4mfma_k<<<(n16 + 3) / 4, 256, 0, stream>>>(h3b, Wcatb, al4, ar4, feat4, res4, el4, er4, n);
  agg4_k<<<nb4, 256, 0, stream>>>(feat4, el4, er4, rowp, csrc, res4, b4, out, n);
}

// Round 12
// 480.372 us; speedup vs baseline: 2.5391x; 1.0175x over previous
//
#include <hip/hip_runtime.h>
#include <hip/hip_bf16.h>
#include <math.h>

// GAT, 4 layers: N=50000, E=800000, IN=128, HID=64, H=4, C=2.
// R12: scan1 -> wave-shuffle scan (2 barriers, was 10); cvthist vectorized x4.
// agg64/gemm unchanged from R11 (agg64 proven at random-gather memory wall
// across 5 variants: 65-68us, FETCH 210MB, both pipes <70%).

#define LEAKY_SLOPE 0.2f

typedef __bf16 bf16x8_t __attribute__((ext_vector_type(8)));
typedef float f32x4_t __attribute__((ext_vector_type(4)));
typedef float f32x2_t __attribute__((ext_vector_type(2)));

__device__ __forceinline__ float leaky(float x) { return x > 0.f ? x : LEAKY_SLOPE * x; }
__device__ __forceinline__ float eluf(float x)  { return x > 0.f ? x : expm1f(x); }
__device__ __forceinline__ float bflo(unsigned u) { return __uint_as_float(u << 16); }
__device__ __forceinline__ float bfhi(unsigned u) { return __uint_as_float(u & 0xffff0000u); }
__device__ __forceinline__ unsigned pk2(float a, float b) {
  __hip_bfloat162 t;
  t.x = __float2bfloat16(a);
  t.y = __float2bfloat16(b);
  return *(unsigned*)&t;
}

__device__ __forceinline__ float rlf(float v, int l) {
  return __uint_as_float((unsigned)__builtin_amdgcn_readlane((int)__float_as_uint(v), l));
}
template <int CTRL>
__device__ __forceinline__ float dpp_add(float x) {
  int t = __builtin_amdgcn_update_dpp(0, (int)__float_as_uint(x), CTRL, 0xf, 0xf, false);
  return x + __uint_as_float((unsigned)t);
}
__device__ __forceinline__ float wsum_dpp(float x) {
  x = dpp_add<0x111>(x);
  x = dpp_add<0x112>(x);
  x = dpp_add<0x114>(x);
  x = dpp_add<0x118>(x);
  x = dpp_add<0x142>(x);
  x = dpp_add<0x143>(x);
  return rlf(x, 63);
}
__device__ __forceinline__ float rowsum_dpp(float x) {
  x = dpp_add<0x111>(x);
  x = dpp_add<0x112>(x);
  x = dpp_add<0x114>(x);
  x = dpp_add<0x118>(x);
  return x;
}
__device__ __forceinline__ float wmax(float v) {
#pragma unroll
  for (int o = 32; o; o >>= 1) v = fmaxf(v, __shfl_xor(v, o));
  return v;
}
__device__ __forceinline__ float wsum_sh(float v) {
#pragma unroll
  for (int o = 32; o; o >>= 1) v += __shfl_xor(v, o);
  return v;
}

// 8-col fma: u = 8 consecutive bf16 of one head, scalar weight w
__device__ __forceinline__ void quad_fma(f32x2_t& a0, f32x2_t& a1, f32x2_t& a2, f32x2_t& a3,
                                         uint4 u, float w) {
  f32x2_t wv = {w, w};
  f32x2_t f;
  f[0] = bflo(u.x); f[1] = bfhi(u.x); a0 = __builtin_elementwise_fma(wv, f, a0);
  f[0] = bflo(u.y); f[1] = bfhi(u.y); a1 = __builtin_elementwise_fma(wv, f, a1);
  f[0] = bflo(u.z); f[1] = bfhi(u.z); a2 = __builtin_elementwise_fma(wv, f, a2);
  f[0] = bflo(u.w); f[1] = bfhi(u.w); a3 = __builtin_elementwise_fma(wv, f, a3);
}

// async global->LDS, 16B per lane
__device__ __forceinline__ void gl_lds16(const __hip_bfloat16* g, __bf16* l) {
  __builtin_amdgcn_global_load_lds((const __attribute__((address_space(1))) void*)g,
                                   (__attribute__((address_space(3))) void*)l, 16, 0, 0);
}

// ---------------- CSR build ----------------
// wave-shuffle scan: 2 barriers instead of 10
__global__ __launch_bounds__(1024) void scan1_k(const int* __restrict__ deg,
                                                int* __restrict__ rowp,
                                                int* __restrict__ bsum, int n) {
  __shared__ int wtot[16];
  __shared__ int wpre[16];
  int tid = threadIdx.x, lane = tid & 63, wid = tid >> 6;
  int i = blockIdx.x * 1024 + tid;
  int v = (i < n) ? deg[i] : 0;
  int x = v;
#pragma unroll
  for (int off = 1; off < 64; off <<= 1) {
    int t = __shfl_up(x, off);
    if (lane >= off) x += t;
  }
  if (lane == 63) wtot[wid] = x;
  __syncthreads();
  if (wid == 0 && lane < 16) {
    int s = wtot[lane];
    int y = s;
#pragma unroll
    for (int off = 1; off < 16; off <<= 1) {
      int t = __shfl_up(y, off);
      if (lane >= off) y += t;
    }
    wpre[lane] = y - s;
    if (lane == 15) bsum[blockIdx.x] = y;
  }
  __syncthreads();
  if (i < n) rowp[i] = wpre[wid] + x - v;
}

__global__ void scan23_k(const int* __restrict__ bsum, int* __restrict__ rowp, int n, int nb) {
  __shared__ int pref[65];
  int tid = threadIdx.x;
  if (tid < 64) {
    int v = (tid < nb) ? bsum[tid] : 0;
    int x = v;
#pragma unroll
    for (int off = 1; off < 64; off <<= 1) {
      int t = __shfl_up(x, off);
      if (tid >= off) x += t;
    }
    pref[tid] = x - v;
    if (tid == 63) pref[64] = x;
  }
  __syncthreads();
  int i = blockIdx.x * 256 + tid;
  if (i < n) rowp[i] += pref[i >> 10];
  if (i == n) rowp[n] = pref[64];
}

__global__ void scatter_k(const int* __restrict__ src, const int* __restrict__ dst,
                          const int* __restrict__ rowp, int* __restrict__ cur,
                          int* __restrict__ csrc, int e) {
  int i = blockIdx.x * 256 + threadIdx.x;
  if (i < e) {
    int d = dst[i];
    int p = atomicAdd(&cur[d], 1);
    csrc[rowp[d] + p] = src[i];
  }
}

// ---------------- prep: vectorized cvt (x4) fused with dst histogram ----------------
// thread i: hist for i<e; x-convert float4 for i<nx/4; weights float4 after.
__global__ void cvthist_k(const float* __restrict__ x, const float* __restrict__ W1,
                          const float* __restrict__ W2, const float* __restrict__ W3,
                          const float* __restrict__ W4, const float* __restrict__ rW4,
                          __hip_bfloat16* __restrict__ xb, __hip_bfloat16* __restrict__ W1b,
                          __hip_bfloat16* __restrict__ W2b, __hip_bfloat16* __restrict__ W3b,
                          __hip_bfloat16* __restrict__ Wcatb, int nx4,
                          const int* __restrict__ dst, int* __restrict__ deg, int e) {
  int i = blockIdx.x * 256 + threadIdx.x;
  if (i < e) atomicAdd(&deg[dst[i]], 1);
  if (i < nx4) {
    float4 xv = ((const float4*)x)[i];
    uint2 o = {pk2(xv.x, xv.y), pk2(xv.z, xv.w)};
    ((uint2*)xb)[i] = o;
    return;
  }
  int j = i - nx4;
  const float* sp = nullptr;
  __hip_bfloat16* dp = nullptr;
  int idx = 0;
  if (j < 8192)       { sp = W1;  dp = W1b;          idx = j; }
  else if (j < 24576) { sp = W2;  dp = W2b;          idx = j - 8192; }
  else if (j < 40960) { sp = W3;  dp = W3b;          idx = j - 24576; }
  else if (j < 41472) { sp = W4;  dp = Wcatb;        idx = j - 40960; }
  else if (j < 41984) { sp = rW4; dp = Wcatb + 2048; idx = j - 41472; }
  else return;
  float4 wv = ((const float4*)sp)[idx];
  uint2 o = {pk2(wv.x, wv.y), pk2(wv.z, wv.w)};
  ((uint2*)dp)[idx] = o;
}

// ---------------- MFMA GEMM + el/er epilogue; featb row-major [n][256] ----------------
template <int K>
__global__ __launch_bounds__(256) void gemm_mfma(const __hip_bfloat16* __restrict__ A,
                                                 const __hip_bfloat16* __restrict__ B,
                                                 __hip_bfloat16* __restrict__ featb,
                                                 const float* __restrict__ al,
                                                 const float* __restrict__ ar,
                                                 float* __restrict__ el,
                                                 float* __restrict__ er, int n) {
  __shared__ __bf16 As[128 * 32];
  __shared__ __bf16 Bs[128 * 32];
  const int tid = threadIdx.x;
  const int lane = tid & 63, w = tid >> 6;
  const int tm = lane & 15, tq = lane >> 4;
  const int wm = (w & 1) * 64, wn = (w >> 1) * 64;
  const int r0 = blockIdx.x * 128, c0 = blockIdx.y * 128;

  f32x4_t acc[4][4];
#pragma unroll
  for (int i = 0; i < 4; ++i)
#pragma unroll
    for (int j = 0; j < 4; ++j) acc[i][j] = 0.f;

  const bool interior = (r0 + 128 <= n);
  if (interior) {
    const int srow = w * 32 + (lane >> 2);
    const int scol = (lane & 3) * 8;
    for (int kk = 0; kk < K; kk += 32) {
      __syncthreads();
      const __hip_bfloat16* ga = A + (size_t)(r0 + srow) * K + kk + scol;
      const __hip_bfloat16* gb = B + (size_t)(c0 + srow) * K + kk + scol;
      gl_lds16(ga, As + w * 1024);
      gl_lds16(ga + (size_t)16 * K, As + w * 1024 + 512);
      gl_lds16(gb, Bs + w * 1024);
      gl_lds16(gb + (size_t)16 * K, Bs + w * 1024 + 512);
      __syncthreads();
      bf16x8_t af[4], bfr[4];
#pragma unroll
      for (int i = 0; i < 4; ++i) af[i] = *(const bf16x8_t*)&As[(wm + i * 16 + tm) * 32 + tq * 8];
#pragma unroll
      for (int j = 0; j < 4; ++j) bfr[j] = *(const bf16x8_t*)&Bs[(wn + j * 16 + tm) * 32 + tq * 8];
#pragma unroll
      for (int i = 0; i < 4; ++i)
#pragma unroll
        for (int j = 0; j < 4; ++j)
          acc[i][j] = __builtin_amdgcn_mfma_f32_16x16x32_bf16(af[i], bfr[j], acc[i][j], 0, 0, 0);
    }
  } else {
    const int srow = tid >> 1, sko = (tid & 1) * 16;
    for (int kk = 0; kk < K; kk += 32) {
      uint4 av0 = {0, 0, 0, 0}, av1 = {0, 0, 0, 0};
      int arw = r0 + srow;
      if (arw < n) {
        const uint4* p = (const uint4*)(A + (size_t)arw * K + kk + sko);
        av0 = p[0];
        av1 = p[1];
      }
      const uint4* q = (const uint4*)(B + (size_t)(c0 + srow) * K + kk + sko);
      uint4 bv0 = q[0], bv1 = q[1];
      __syncthreads();
      *(uint4*)&As[srow * 32 + sko] = av0;
      *(uint4*)&As[srow * 32 + sko + 8] = av1;
      *(uint4*)&Bs[srow * 32 + sko] = bv0;
      *(uint4*)&Bs[srow * 32 + sko + 8] = bv1;
      __syncthreads();
      bf16x8_t af[4], bfr[4];
#pragma unroll
      for (int i = 0; i < 4; ++i) af[i] = *(const bf16x8_t*)&As[(wm + i * 16 + tm) * 32 + tq * 8];
#pragma unroll
      for (int j = 0; j < 4; ++j) bfr[j] = *(const bf16x8_t*)&Bs[(wn + j * 16 + tm) * 32 + tq * 8];
#pragma unroll
      for (int i = 0; i < 4; ++i)
#pragma unroll
        for (int j = 0; j < 4; ++j)
          acc[i][j] = __builtin_amdgcn_mfma_f32_16x16x32_bf16(af[i], bfr[j], acc[i][j], 0, 0, 0);
    }
  }

  // featb store, row-major
#pragma unroll
  for (int i = 0; i < 4; ++i) {
#pragma unroll
    for (int j = 0; j < 4; ++j) {
      int col = c0 + wn + j * 16 + tm;
#pragma unroll
      for (int rr = 0; rr < 4; ++rr) {
        int row = r0 + wm + i * 16 + tq * 4 + rr;
        if (row < n) featb[(size_t)row * 256 + col] = __float2bfloat16(acc[i][j][rr]);
      }
    }
  }

  // el/er epilogue
  {
    const int hd = (c0 + wn) >> 6;
    float alv[4], arv[4];
#pragma unroll
    for (int j = 0; j < 4; ++j) {
      alv[j] = al[hd * 64 + j * 16 + tm];
      arv[j] = ar[hd * 64 + j * 16 + tm];
    }
#pragma unroll
    for (int i = 0; i < 4; ++i) {
#pragma unroll
      for (int rr = 0; rr < 4; ++rr) {
        float se = acc[i][0][rr] * alv[0] + acc[i][1][rr] * alv[1] +
                   acc[i][2][rr] * alv[2] + acc[i][3][rr] * alv[3];
        float sr2 = acc[i][0][rr] * arv[0] + acc[i][1][rr] * arv[1] +
                    acc[i][2][rr] * arv[2] + acc[i][3][rr] * arv[3];
        se = rowsum_dpp(se);
        sr2 = rowsum_dpp(sr2);
        if (tm == 15) {
          int row = r0 + wm + i * 16 + tq * 4 + rr;
          if (row < n) {
            el[(size_t)row * 4 + hd] = se;
            er[(size_t)row * 4 + hd] = sr2;
          }
        }
      }
    }
  }
}

// ---------------- aggregate layers 1-3 (unchanged from R11) ----------------
template <int RES>
__global__ __launch_bounds__(256) void agg64_k(const __hip_bfloat16* __restrict__ featb,
                                               const float* __restrict__ el,
                                               const float* __restrict__ er,
                                               const int* __restrict__ rowp,
                                               const int* __restrict__ csrc,
                                               const __hip_bfloat16* __restrict__ hinb,
                                               const float* __restrict__ bias,
                                               __hip_bfloat16* __restrict__ houtb, int n) {
  __shared__ float wsh[4][256];
  __shared__ int ssh[4][64];
  int wv = threadIdx.x >> 6;
  int node = blockIdx.x * 4 + wv;
  int lane = threadIdx.x & 63;
  if (node >= n) return;
  int s0 = rowp[node], s1 = rowp[node + 1];
  int deg = s1 - s0;
  float4 erv = *(const float4*)(er + (size_t)node * 4);

  if (deg <= 64) {
    int sown = 0;
    float x0 = 0.f, x1 = 0.f, x2 = 0.f, x3 = 0.f;
    if (lane < deg) {
      sown = csrc[s0 + lane];
      float4 e = *(const float4*)(el + (size_t)sown * 4);
      x0 = __expf(leaky(e.x + erv.x));
      x1 = __expf(leaky(e.y + erv.y));
      x2 = __expf(leaky(e.z + erv.z));
      x3 = __expf(leaky(e.w + erv.w));
    }
    float d0 = wsum_dpp(x0), d1 = wsum_dpp(x1), d2 = wsum_dpp(x2), d3 = wsum_dpp(x3);
    float i0 = d0 > 0.f ? 1.f / d0 : 0.f;
    float i1 = d1 > 0.f ? 1.f / d1 : 0.f;
    float i2 = d2 > 0.f ? 1.f / d2 : 0.f;
    float i3 = d3 > 0.f ? 1.f / d3 : 0.f;
    float4 wq = {x0 * i0, x1 * i1, x2 * i2, x3 * i3};
    *(float4*)&wsh[wv][lane * 4] = wq;
    ssh[wv][lane] = sown;

    const int half = lane >> 5, sub = lane & 31;
    const int hh = sub >> 3;
    f32x2_t a0 = {0.f, 0.f}, a1 = {0.f, 0.f}, a2 = {0.f, 0.f}, a3 = {0.f, 0.f};
    int k = 0;
    for (; k + 8 <= deg; k += 8) {
      int ke = k + half;
      int sk0 = ssh[wv][ke], sk1 = ssh[wv][ke + 2];
      int sk2 = ssh[wv][ke + 4], sk3 = ssh[wv][ke + 6];
      uint4 u0 = ((const uint4*)(featb + ((size_t)sk0 << 8)))[sub];
      uint4 u1 = ((const uint4*)(featb + ((size_t)sk1 << 8)))[sub];
      uint4 u2 = ((const uint4*)(featb + ((size_t)sk2 << 8)))[sub];
      uint4 u3 = ((const uint4*)(featb + ((size_t)sk3 << 8)))[sub];
      float w0 = wsh[wv][ke * 4 + hh];
      float w1 = wsh[wv][(ke + 2) * 4 + hh];
      float w2 = wsh[wv][(ke + 4) * 4 + hh];
      float w3 = wsh[wv][(ke + 6) * 4 + hh];
      quad_fma(a0, a1, a2, a3, u0, w0);
      quad_fma(a0, a1, a2, a3, u1, w1);
      quad_fma(a0, a1, a2, a3, u2, w2);
      quad_fma(a0, a1, a2, a3, u3, w3);
    }
    for (; k < deg; k += 2) {
      int ke = k + half;
      int sk = ssh[wv][ke];
      uint4 u = ((const uint4*)(featb + ((size_t)sk << 8)))[sub];
      float wk = wsh[wv][ke * 4 + hh];
      quad_fma(a0, a1, a2, a3, u, wk);
    }
    a0[0] += __shfl_xor(a0[0], 32); a0[1] += __shfl_xor(a0[1], 32);
    a1[0] += __shfl_xor(a1[0], 32); a1[1] += __shfl_xor(a1[1], 32);
    a2[0] += __shfl_xor(a2[0], 32); a2[1] += __shfl_xor(a2[1], 32);
    a3[0] += __shfl_xor(a3[0], 32); a3[1] += __shfl_xor(a3[1], 32);

    if (half == 0) {
      size_t base = (size_t)node * 256 + sub * 8;
      float v0 = a0[0], v1 = a0[1], v2 = a1[0], v3 = a1[1];
      float v4 = a2[0], v5 = a2[1], v6 = a3[0], v7 = a3[1];
      float4 b0 = *(const float4*)(bias + sub * 8);
      float4 b1 = *(const float4*)(bias + sub * 8 + 4);
      v0 += b0.x; v1 += b0.y; v2 += b0.z; v3 += b0.w;
      v4 += b1.x; v5 += b1.y; v6 += b1.z; v7 += b1.w;
      if (RES) {
        uint4 r = *(const uint4*)(hinb + base);
        v0 += bflo(r.x); v1 += bfhi(r.x);
        v2 += bflo(r.y); v3 += bfhi(r.y);
        v4 += bflo(r.z); v5 += bfhi(r.z);
        v6 += bflo(r.w); v7 += bfhi(r.w);
      }
      uint4 o;
      o.x = pk2(eluf(v0), eluf(v1));
      o.y = pk2(eluf(v2), eluf(v3));
      o.z = pk2(eluf(v4), eluf(v5));
      o.w = pk2(eluf(v6), eluf(v7));
      *(uint4*)(houtb + base) = o;
    }
  } else {
    int hsel = lane >> 4;
    f32x2_t a01 = {0.f, 0.f}, a23 = {0.f, 0.f};
    float m0 = -INFINITY, m1 = -INFINITY, m2 = -INFINITY, m3 = -INFINITY;
    for (int k = s0 + lane; k < s1; k += 64) {
      int s = csrc[k];
      float4 e = *(const float4*)(el + (size_t)s * 4);
      m0 = fmaxf(m0, leaky(e.x + erv.x));
      m1 = fmaxf(m1, leaky(e.y + erv.y));
      m2 = fmaxf(m2, leaky(e.z + erv.z));
      m3 = fmaxf(m3, leaky(e.w + erv.w));
    }
    m0 = wmax(m0); m1 = wmax(m1); m2 = wmax(m2); m3 = wmax(m3);
    float d0 = 0, d1 = 0, d2 = 0, d3 = 0;
    for (int k = s0 + lane; k < s1; k += 64) {
      int s = csrc[k];
      float4 e = *(const float4*)(el + (size_t)s * 4);
      d0 += __expf(leaky(e.x + erv.x) - m0);
      d1 += __expf(leaky(e.y + erv.y) - m1);
      d2 += __expf(leaky(e.z + erv.z) - m2);
      d3 += __expf(leaky(e.w + erv.w) - m3);
    }
    d0 = wsum_sh(d0); d1 = wsum_sh(d1); d2 = wsum_sh(d2); d3 = wsum_sh(d3);
    float j0 = d0 > 0.f ? 1.f / d0 : 0.f;
    float j1 = d1 > 0.f ? 1.f / d1 : 0.f;
    float j2 = d2 > 0.f ? 1.f / d2 : 0.f;
    float j3 = d3 > 0.f ? 1.f / d3 : 0.f;
    for (int k = s0; k < s1; ++k) {
      int s = csrc[k];
      float4 e = *(const float4*)(el + (size_t)s * 4);
      float w0 = __expf(leaky(e.x + erv.x) - m0) * j0;
      float w1 = __expf(leaky(e.y + erv.y) - m1) * j1;
      float w2 = __expf(leaky(e.z + erv.z) - m2) * j2;
      float w3 = __expf(leaky(e.w + erv.w) - m3) * j3;
      float wk = (hsel == 0) ? w0 : (hsel == 1) ? w1 : (hsel == 2) ? w2 : w3;
      uint2 u = ((const uint2*)(featb + ((size_t)s << 8)))[lane];
      f32x2_t wv2 = {wk, wk};
      f32x2_t f;
      f[0] = bflo(u.x); f[1] = bfhi(u.x); a01 = __builtin_elementwise_fma(wv2, f, a01);
      f[0] = bflo(u.y); f[1] = bfhi(u.y); a23 = __builtin_elementwise_fma(wv2, f, a23);
    }
    size_t base = (size_t)node * 256 + lane * 4;
    float4 bv = *(const float4*)(bias + lane * 4);
    float v0 = a01[0] + bv.x, v1 = a01[1] + bv.y;
    float v2 = a23[0] + bv.z, v3 = a23[1] + bv.w;
    if (RES) {
      uint2 r = *(const uint2*)(hinb + base);
      v0 += bflo(r.x); v1 += bfhi(r.x);
      v2 += bflo(r.y); v3 += bfhi(r.y);
    }
    uint2 o;
    o.x = pk2(eluf(v0), eluf(v1));
    o.y = pk2(eluf(v2), eluf(v3));
    *(uint2*)(houtb + base) = o;
  }
}

// ---------------- layer 4 projection (MFMA) + el4/er4 epilogue ----------------
__global__ __launch_bounds__(256) void l4mfma_k(const __hip_bfloat16* __restrict__ hb,
                                                const __hip_bfloat16* __restrict__ Wcat,
                                                const float* __restrict__ al4,
                                                const float* __restrict__ ar4,
                                                float* __restrict__ feat4,
                                                float* __restrict__ res4,
                                                float* __restrict__ el4,
                                                float* __restrict__ er4, int n) {
  int wid = blockIdx.x * 4 + (threadIdx.x >> 6);
  int n16 = (n + 15) >> 4;
  if (wid >= n16) return;
  int lane = threadIdx.x & 63;
  int tm = lane & 15, tq = lane >> 4;
  int row = wid * 16 + tm;
  int rowc = row < n ? row : n - 1;
  const __hip_bfloat16* ap = hb + (size_t)rowc * 256 + tq * 8;
  const __hip_bfloat16* bp = Wcat + (size_t)tm * 256 + tq * 8;
  f32x4_t acc = {0.f, 0.f, 0.f, 0.f};
#pragma unroll
  for (int k = 0; k < 8; ++k) {
    bf16x8_t af = *(const bf16x8_t*)(ap + k * 32);
    bf16x8_t bf = *(const bf16x8_t*)(bp + k * 32);
    acc = __builtin_amdgcn_mfma_f32_16x16x32_bf16(af, bf, acc, 0, 0, 0);
  }
  float* dstp = (tm < 8) ? feat4 : res4;
  int cc = tm & 7;
  float a4 = (tm < 8) ? al4[tm] : 0.f;
  float r4 = (tm < 8) ? ar4[tm] : 0.f;
#pragma unroll
  for (int r = 0; r < 4; ++r) {
    int node = wid * 16 + tq * 4 + r;
    float te = acc[r] * a4;
    float tr = acc[r] * r4;
    te += __shfl_xor(te, 1);
    tr += __shfl_xor(tr, 1);
    if (node < n) {
      dstp[(size_t)node * 8 + cc] = acc[r];
      if (tm < 8 && (tm & 1) == 0) {
        el4[(size_t)node * 4 + (tm >> 1)] = te;
        er4[(size_t)node * 4 + (tm >> 1)] = tr;
      }
    }
  }
}

// ---------------- layer 4 aggregate: one edge per lane, fully parallel ----------------
__global__ __launch_bounds__(256) void agg4_k(const float* __restrict__ feat4,
                                              const float* __restrict__ el4,
                                              const float* __restrict__ er4,
                                              const int* __restrict__ rowp,
                                              const int* __restrict__ csrc,
                                              const float* __restrict__ res4,
                                              const float* __restrict__ b4,
                                              float* __restrict__ out, int n) {
  int wv = threadIdx.x >> 6;
  int node = blockIdx.x * 4 + wv;
  int lane = threadIdx.x & 63;
  if (node >= n) return;
  int s0 = rowp[node], s1 = rowp[node + 1];
  int deg = s1 - s0;
  float4 erv = *(const float4*)(er4 + (size_t)node * 4);
  float v = 0.f;

  if (deg <= 64) {
    int sown = 0;
    float x0 = 0.f, x1 = 0.f, x2 = 0.f, x3 = 0.f;
    if (lane < deg) {
      sown = csrc[s0 + lane];
      float4 e = *(const float4*)(el4 + (size_t)sown * 4);
      x0 = __expf(leaky(e.x + erv.x));
      x1 = __expf(leaky(e.y + erv.y));
      x2 = __expf(leaky(e.z + erv.z));
      x3 = __expf(leaky(e.w + erv.w));
    }
    float d0 = wsum_dpp(x0), d1 = wsum_dpp(x1), d2 = wsum_dpp(x2), d3 = wsum_dpp(x3);
    float w0 = x0 * (d0 > 0.f ? 1.f / d0 : 0.f);
    float w1 = x1 * (d1 > 0.f ? 1.f / d1 : 0.f);
    float w2 = x2 * (d2 > 0.f ? 1.f / d2 : 0.f);
    float w3 = x3 * (d3 > 0.f ? 1.f / d3 : 0.f);
    float4 f0 = {0, 0, 0, 0}, f1 = {0, 0, 0, 0};
    if (lane < deg) {
      const float4* fp = (const float4*)(feat4 + (size_t)sown * 8);
      f0 = fp[0];
      f1 = fp[1];
    }
    float t0 = w0 * f0.x, t1 = w0 * f0.y;
    float t2 = w1 * f0.z, t3 = w1 * f0.w;
    float t4 = w2 * f1.x, t5 = w2 * f1.y;
    float t6 = w3 * f1.z, t7 = w3 * f1.w;
    t0 = wsum_dpp(t0); t1 = wsum_dpp(t1); t2 = wsum_dpp(t2); t3 = wsum_dpp(t3);
    t4 = wsum_dpp(t4); t5 = wsum_dpp(t5); t6 = wsum_dpp(t6); t7 = wsum_dpp(t7);
    int p = lane & 7;
    float s = t0;
    s = (p == 1) ? t1 : s; s = (p == 2) ? t2 : s; s = (p == 3) ? t3 : s;
    s = (p == 4) ? t4 : s; s = (p == 5) ? t5 : s; s = (p == 6) ? t6 : s;
    s = (p == 7) ? t7 : s;
    if (lane < 8) v = s + res4[(size_t)node * 8 + lane] + b4[lane];
  } else {
    int p = lane & 7, hh = p >> 1;
    float acc = 0.f;
    float m0 = -INFINITY, m1 = -INFINITY, m2 = -INFINITY, m3 = -INFINITY;
    for (int k = s0 + lane; k < s1; k += 64) {
      int s = csrc[k];
      float4 e = *(const float4*)(el4 + (size_t)s * 4);
      m0 = fmaxf(m0, leaky(e.x + erv.x));
      m1 = fmaxf(m1, leaky(e.y + erv.y));
      m2 = fmaxf(m2, leaky(e.z + erv.z));
      m3 = fmaxf(m3, leaky(e.w + erv.w));
    }
    m0 = wmax(m0); m1 = wmax(m1); m2 = wmax(m2); m3 = wmax(m3);
    float d0 = 0, d1 = 0, d2 = 0, d3 = 0;
    for (int k = s0 + lane; k < s1; k += 64) {
      int s = csrc[k];
      float4 e = *(const float4*)(el4 + (size_t)s * 4);
      d0 += __expf(leaky(e.x + erv.x) - m0);
      d1 += __expf(leaky(e.y + erv.y) - m1);
      d2 += __expf(leaky(e.z + erv.z) - m2);
      d3 += __expf(leaky(e.w + erv.w) - m3);
    }
    d0 = wsum_sh(d0); d1 = wsum_sh(d1); d2 = wsum_sh(d2); d3 = wsum_sh(d3);
    float i0 = d0 > 0.f ? 1.f / d0 : 0.f;
    float i1 = d1 > 0.f ? 1.f / d1 : 0.f;
    float i2 = d2 > 0.f ? 1.f / d2 : 0.f;
    float i3 = d3 > 0.f ? 1.f / d3 : 0.f;
    for (int k = s0; k < s1; ++k) {
      int s = csrc[k];
      float4 e = *(const float4*)(el4 + (size_t)s * 4);
      float w0 = __expf(leaky(e.x + erv.x) - m0) * i0;
      float w1 = __expf(leaky(e.y + erv.y) - m1) * i1;
      float w2 = __expf(leaky(e.z + erv.z) - m2) * i2;
      float w3 = __expf(leaky(e.w + erv.w) - m3) * i3;
      float wk = (hh == 0) ? w0 : (hh == 1) ? w1 : (hh == 2) ? w2 : w3;
      if (lane < 8) acc = fmaf(wk, feat4[(size_t)s * 8 + p], acc);
    }
    if (lane < 8) v = acc + res4[(size_t)node * 8 + lane] + b4[lane];
  }

  float pv = __shfl_xor(v, 1);
  float mx = fmaxf(v, pv);
  float ex = __expf(v - mx);
  float sm = ex + __shfl_xor(ex, 1);
  float pr = ex / sm;
  float t = pr + __shfl_xor(pr, 2);
  t += __shfl_xor(t, 4);
  if (lane < 2) out[(size_t)node * 2 + lane] = t * 0.25f;
}

extern "C" void kernel_launch(void* const* d_in, const int* in_sizes, int n_in,
                              void* d_out, int out_size, void* d_ws, size_t ws_size,
                              hipStream_t stream) {
  const float* x   = (const float*)d_in[0];
  const int* src   = (const int*)d_in[1];
  const int* dst   = (const int*)d_in[2];
  const float* W1  = (const float*)d_in[3];
  const float* al1 = (const float*)d_in[4];
  const float* ar1 = (const float*)d_in[5];
  const float* b1  = (const float*)d_in[6];
  const float* W2  = (const float*)d_in[7];
  const float* al2 = (const float*)d_in[8];
  const float* ar2 = (const float*)d_in[9];
  const float* b2  = (const float*)d_in[10];
  const float* W3  = (const float*)d_in[11];
  const float* al3 = (const float*)d_in[12];
  const float* ar3 = (const float*)d_in[13];
  const float* b3  = (const float*)d_in[14];
  const float* W4  = (const float*)d_in[15];
  const float* al4 = (const float*)d_in[16];
  const float* ar4 = (const float*)d_in[17];
  const float* b4  = (const float*)d_in[18];
  const float* rW4 = (const float*)d_in[19];
  float* out = (float*)d_out;

  const int n = in_sizes[0] / 128;  // 50000
  const int e = in_sizes[1];        // 800000

  char* ws = (char*)d_ws;
  auto alloc = [&](size_t bytes) -> char* {
    char* p = ws;
    ws += (bytes + 255) & ~(size_t)255;
    return p;
  };
  __hip_bfloat16* featb = (__hip_bfloat16*)alloc((size_t)n * 256 * 2);
  __hip_bfloat16* h1b   = (__hip_bfloat16*)alloc((size_t)n * 256 * 2);
  __hip_bfloat16* h2b   = (__hip_bfloat16*)alloc((size_t)n * 256 * 2);
  __hip_bfloat16* h3b   = (__hip_bfloat16*)alloc((size_t)n * 256 * 2);
  __hip_bfloat16* xb    = (__hip_bfloat16*)alloc((size_t)n * 128 * 2);
  __hip_bfloat16* W1b   = (__hip_bfloat16*)alloc((size_t)256 * 128 * 2);
  __hip_bfloat16* W2b   = (__hip_bfloat16*)alloc((size_t)256 * 256 * 2);
  __hip_bfloat16* W3b   = (__hip_bfloat16*)alloc((size_t)256 * 256 * 2);
  __hip_bfloat16* Wcatb = (__hip_bfloat16*)alloc((size_t)16 * 256 * 2);
  float* el    = (float*)alloc((size_t)n * 4 * 4);
  float* er    = (float*)alloc((size_t)n * 4 * 4);
  float* feat4 = (float*)alloc((size_t)n * 8 * 4);
  float* res4  = (float*)alloc((size_t)n * 8 * 4);
  float* el4   = (float*)alloc((size_t)n * 4 * 4);
  float* er4   = (float*)alloc((size_t)n * 4 * 4);
  int* deg     = (int*)alloc((size_t)2 * n * 4);
  int* cur     = deg + n;
  int* rowp    = (int*)alloc((size_t)(n + 1) * 4);
  int* csrc    = (int*)alloc((size_t)e * 4);
  int nb_scan  = (n + 1023) / 1024;
  int* bsum    = (int*)alloc((size_t)(nb_scan + 1) * 4);

  (void)hipMemsetAsync(deg, 0, (size_t)2 * n * 4, stream);

  int nx4 = n * 128 / 4;
  int nwork = nx4 + 41984;
  if (nwork < e) nwork = e;
  cvthist_k<<<(nwork + 255) / 256, 256, 0, stream>>>(x, W1, W2, W3, W4, rW4, xb, W1b,
                                                     W2b, W3b, Wcatb, nx4, dst, deg, e);
  scan1_k<<<nb_scan, 1024, 0, stream>>>(deg, rowp, bsum, n);
  scan23_k<<<(n + 256) / 256, 256, 0, stream>>>(bsum, rowp, n, nb_scan);
  scatter_k<<<(e + 255) / 256, 256, 0, stream>>>(src, dst, rowp, cur, csrc, e);

  dim3 ggrid((n + 127) / 128, 2);
  int nb4 = (n + 3) / 4;

  // layer 1
  gemm_mfma<128><<<ggrid, 256, 0, stream>>>(xb, W1b, featb, al1, ar1, el, er, n);
  agg64_k<0><<<nb4, 256, 0, stream>>>(featb, el, er, rowp, csrc, nullptr, b1, h1b, n);
  // layer 2
  gemm_mfma<256><<<ggrid, 256, 0, stream>>>(h1b, W2b, featb, al2, ar2, el, er, n);
  agg64_k<1><<<nb4, 256, 0, stream>>>(featb, el, er, rowp, csrc, h1b, b2, h2b, n);
  // layer 3
  gemm_mfma<256><<<ggrid, 256, 0, stream>>>(h2b, W3b, featb, al3, ar3, el, er, n);
  agg64_k<1><<<nb4, 256, 0, stream>>>(featb, el, er, rowp, csrc, h2b, b3, h3b, n);
  // layer 4
  int n16 = (n + 15) / 16;
  l4mfma_k<<<(n16 + 3) / 4, 256, 0, stream>>>(h3b, Wcatb, al4, ar4, feat4, res4, el4, er4, n);
  agg4_k<<<nb4, 256, 0, stream>>>(feat4, el4, er4, rowp, csrc, res4, b4, out, n);
}